// Round 2
// baseline (1827.581 us; speedup 1.0000x reference)
//
#include <hip/hip_runtime.h>

#define BATCH 256
#define SEQ   128
#define EDIM  300
#define PDIM  200
#define BSTOK (BATCH * SEQ)

#define F_RELU  1
#define F_ACCUM 2

typedef unsigned short u16;
typedef __attribute__((ext_vector_type(8))) short bf16x8;   // 8 bf16 in 4 VGPRs
typedef __attribute__((ext_vector_type(4))) float f32x4;

__device__ __forceinline__ u16 f2bf(float x) {
    unsigned u = __float_as_uint(x);
    unsigned r = u + 0x7fffu + ((u >> 16) & 1u);   // round-to-nearest-even
    return (u16)(r >> 16);
}
__device__ __forceinline__ float bf2f(u16 h) {
    return __uint_as_float(((unsigned)h) << 16);
}

// ---------------------------------------------------------------------------
// fp32 tiled GEMM (kept for batched S x S attention GEMMs + fallback path).
// Optionally writes split-bf16 hi/lo of the result (Hh/Hl, leading dim hld,
// batch stride sH) instead of / in addition to fp32 C.
// ---------------------------------------------------------------------------
template <bool BT>
__global__ __launch_bounds__(256) void gemm_kernel(
    const float* __restrict__ A, const float* __restrict__ Bm,
    float* __restrict__ C, int M, int N, int K, int lda, int ldb, int ldc,
    long long sA, long long sB, long long sC, int flags,
    u16* __restrict__ Hh, u16* __restrict__ Hl, int hld, long long sH)
{
    __shared__ float As[16][68];
    __shared__ float Bs[16][68];

    const int bz = blockIdx.z;
    A  += (long long)bz * sA;
    Bm += (long long)bz * sB;
    if (C)  C  += (long long)bz * sC;
    if (Hh) { Hh += (long long)bz * sH; Hl += (long long)bz * sH; }

    const int tid = threadIdx.x;
    const int bn = blockIdx.x * 64;
    const int bm = blockIdx.y * 64;
    const int tx = tid & 15;
    const int ty = tid >> 4;

    float acc[4][4] = {};

    for (int k0 = 0; k0 < K; k0 += 16) {
        {
            const int lk = tid & 15;
            const int m0 = tid >> 4;
            const int gk = k0 + lk;
            #pragma unroll
            for (int i = 0; i < 4; i++) {
                const int m = m0 + i * 16;
                const int gm = bm + m;
                float v = 0.f;
                if (gm < M && gk < K) v = A[(long long)gm * lda + gk];
                As[lk][m] = v;
            }
        }
        if (!BT) {
            const int ln = tid & 63;
            const int kb = tid >> 6;
            const int gn = bn + ln;
            #pragma unroll
            for (int i = 0; i < 4; i++) {
                const int k = kb + i * 4;
                const int gk = k0 + k;
                float v = 0.f;
                if (gk < K && gn < N) v = Bm[(long long)gk * ldb + gn];
                Bs[k][ln] = v;
            }
        } else {
            const int lk = tid & 15;
            const int n0 = tid >> 4;
            const int gk = k0 + lk;
            #pragma unroll
            for (int i = 0; i < 4; i++) {
                const int n = n0 + i * 16;
                const int gn = bn + n;
                float v = 0.f;
                if (gn < N && gk < K) v = Bm[(long long)gn * ldb + gk];
                Bs[lk][n] = v;
            }
        }
        __syncthreads();

        #pragma unroll
        for (int k = 0; k < 16; k++) {
            const float4 av = *reinterpret_cast<const float4*>(&As[k][ty * 4]);
            const float4 bv = *reinterpret_cast<const float4*>(&Bs[k][tx * 4]);
            const float a[4] = {av.x, av.y, av.z, av.w};
            const float b[4] = {bv.x, bv.y, bv.z, bv.w};
            #pragma unroll
            for (int i = 0; i < 4; i++)
                #pragma unroll
                for (int j = 0; j < 4; j++)
                    acc[i][j] = fmaf(a[i], b[j], acc[i][j]);
        }
        __syncthreads();
    }

    #pragma unroll
    for (int i = 0; i < 4; i++) {
        const int gm = bm + ty * 4 + i;
        if (gm >= M) continue;
        #pragma unroll
        for (int j = 0; j < 4; j++) {
            const int gn = bn + tx * 4 + j;
            if (gn >= N) continue;
            float v = acc[i][j];
            if (flags & F_ACCUM) v += C[(long long)gm * ldc + gn];
            if (flags & F_RELU)  v = fmaxf(v, 0.f);
            if (C) C[(long long)gm * ldc + gn] = v;
            if (Hh) {
                const long long oi = (long long)gm * hld + gn;
                const u16 h = f2bf(v);
                Hh[oi] = h;
                Hl[oi] = f2bf(v - bf2f(h));
            }
        }
    }
}

// ---------------------------------------------------------------------------
// Split-bf16 MFMA GEMM: C[M,N] = (Ah+Al)[M,Kp] * (Bh+Bl)^T[N,Kp]
// via 3 MFMAs per fragment pair (Ah*Bh + Ah*Bl + Al*Bh), rel err ~2^-18.
// A: [M][lda] bf16 hi/lo (K-major). B: [N][ldb] bf16 hi/lo (K-major,
// i.e. pre-transposed weights). Kp multiple of 32. M multiple of 128.
// 128x128 tile, BK=32, 4 waves, each wave 4x4 grid of 16x16x32 MFMAs.
// Optional second output: split-bf16 hi/lo (Oh/Ol, leading dim ldo), with
// zero-padding of columns [N, opad) for the next GEMM's K-padding.
// ---------------------------------------------------------------------------
__global__ __launch_bounds__(256) void gemm_mfma(
    const u16* __restrict__ Ah, const u16* __restrict__ Al,
    const u16* __restrict__ Bh, const u16* __restrict__ Bl,
    float* __restrict__ C, u16* __restrict__ Oh, u16* __restrict__ Ol,
    int M, int N, int Kp, int lda, int ldb, int ldc, int ldo, int opad, int flags)
{
    // rows padded to 40 bf16 (80 B = 20 banks) -> ~2-way conflicts (free)
    __shared__ u16 AsH[128][40];
    __shared__ u16 AsL[128][40];
    __shared__ u16 BsH[128][40];
    __shared__ u16 BsL[128][40];

    const int tid  = threadIdx.x;
    const int bm   = blockIdx.y * 128;
    const int bn   = blockIdx.x * 128;
    const int wave = tid >> 6;
    const int lane = tid & 63;
    const int wm   = (wave >> 1) * 64;   // wave quadrant
    const int wn   = (wave & 1) * 64;
    const int lr   = lane & 15;          // fragment row/col
    const int quad = lane >> 4;          // k-offset = quad*8 ; C-row = quad*4+r

    // staging: thread t covers row sr = t>>1, 16 bf16 at col sc = (t&1)*16
    const int sr = tid >> 1;
    const int sc = (tid & 1) * 16;

    f32x4 acc[4][4];
    #pragma unroll
    for (int i = 0; i < 4; i++)
        #pragma unroll
        for (int j = 0; j < 4; j++)
            acc[i][j] = (f32x4)(0.0f);

    for (int k0 = 0; k0 < Kp; k0 += 32) {
        {
            const long long ar = (long long)(bm + sr) * lda + k0 + sc;
            const uint4 vh = *(const uint4*)(Ah + ar);
            const uint4 vl = *(const uint4*)(Al + ar);
            *(uint4*)&AsH[sr][sc] = vh;
            *(uint4*)&AsL[sr][sc] = vl;
            uint4 wh = make_uint4(0, 0, 0, 0), wl = make_uint4(0, 0, 0, 0);
            const int gn = bn + sr;
            if (gn < N) {
                const long long br = (long long)gn * ldb + k0 + sc;
                wh = *(const uint4*)(Bh + br);
                wl = *(const uint4*)(Bl + br);
            }
            *(uint4*)&BsH[sr][sc] = wh;
            *(uint4*)&BsL[sr][sc] = wl;
        }
        __syncthreads();

        bf16x8 fah[4], fal[4], fbh[4], fbl[4];
        #pragma unroll
        for (int i = 0; i < 4; i++) {
            fah[i] = *(const bf16x8*)&AsH[wm + i * 16 + lr][quad * 8];
            fal[i] = *(const bf16x8*)&AsL[wm + i * 16 + lr][quad * 8];
            fbh[i] = *(const bf16x8*)&BsH[wn + i * 16 + lr][quad * 8];
            fbl[i] = *(const bf16x8*)&BsL[wn + i * 16 + lr][quad * 8];
        }
        #pragma unroll
        for (int i = 0; i < 4; i++)
            #pragma unroll
            for (int j = 0; j < 4; j++) {
                acc[i][j] = __builtin_amdgcn_mfma_f32_16x16x32_bf16(fah[i], fbh[j], acc[i][j], 0, 0, 0);
                acc[i][j] = __builtin_amdgcn_mfma_f32_16x16x32_bf16(fah[i], fbl[j], acc[i][j], 0, 0, 0);
                acc[i][j] = __builtin_amdgcn_mfma_f32_16x16x32_bf16(fal[i], fbh[j], acc[i][j], 0, 0, 0);
            }
        __syncthreads();
    }

    // C/D layout: col = lane&15, row = quad*4 + r  [verified m89/m91]
    #pragma unroll
    for (int i = 0; i < 4; i++) {
        #pragma unroll
        for (int j = 0; j < 4; j++) {
            const int gn = bn + wn + j * 16 + lr;
            #pragma unroll
            for (int r = 0; r < 4; r++) {
                const int gm = bm + wm + i * 16 + quad * 4 + r;
                float v = acc[i][j][r];
                if (flags & F_RELU) v = fmaxf(v, 0.f);
                if (gn < N) {
                    if (C) C[(long long)gm * ldc + gn] = v;
                    if (Oh) {
                        const long long oi = (long long)gm * ldo + gn;
                        const u16 h = f2bf(v);
                        Oh[oi] = h;
                        Ol[oi] = f2bf(v - bf2f(h));
                    }
                } else if (Oh && gn < opad) {
                    const long long oi = (long long)gm * ldo + gn;
                    Oh[oi] = 0; Ol[oi] = 0;
                }
            }
        }
    }
}

// fp32 [rows][sld] (cols >= scols treated as 0) -> hi/lo bf16 [rows][dld]
__global__ void convert_hilo_kernel(const float* __restrict__ src, int sld, int scols,
                                    u16* __restrict__ H, u16* __restrict__ L, int dld, int dcols)
{
    const int row = blockIdx.y;
    const int c = blockIdx.x * 256 + threadIdx.x;
    if (c >= dcols) return;
    const float v = (c < scols) ? src[(long long)row * sld + c] : 0.f;
    const u16 h = f2bf(v);
    const long long di = (long long)row * dld + c;
    H[di] = h;
    L[di] = f2bf(v - bf2f(h));
}

// weight [K][N] fp32 -> transposed hi/lo bf16 [N][Kp], zero-padded k in [K,Kp)
__global__ void convert_wt_kernel(const float* __restrict__ src, int K, int N,
                                  u16* __restrict__ H, u16* __restrict__ L, int Kp)
{
    const int n = blockIdx.y;
    const int k = blockIdx.x * 256 + threadIdx.x;
    if (k >= Kp) return;
    const float v = (k < K) ? src[(long long)k * N + n] : 0.f;
    const u16 h = f2bf(v);
    const long long di = (long long)n * Kp + k;
    H[di] = h;
    L[di] = f2bf(v - bf2f(h));
}

// sizes[side*256 + b] = count_nonzero(x_side[b, :])
__global__ void sizes_kernel(const int* __restrict__ x1, const int* __restrict__ x2,
                             int* __restrict__ sizes)
{
    const int b = blockIdx.x;
    const int side = blockIdx.y;
    const int* x = (side ? x2 : x1) + b * SEQ;
    const int nz = (x[threadIdx.x] != 0) ? 1 : 0;
    const unsigned long long bal = __ballot(nz);
    __shared__ int part[2];
    if ((threadIdx.x & 63) == 0) part[threadIdx.x >> 6] = __popcll(bal);
    __syncthreads();
    if (threadIdx.x == 0) sizes[side * BATCH + b] = part[0] + part[1];
}

// out[t,:] = l2norm(emb[x[t],:]); optionally also hi/lo into [t][608] cols 0:300,
// zeroing pad cols 600:608 (cols 300:600 are filled later by the xp GEMM).
__global__ void gather_norm_kernel(const int* __restrict__ x, const float* __restrict__ emb,
                                   float* __restrict__ out,
                                   u16* __restrict__ H, u16* __restrict__ L)
{
    const int t = blockIdx.x;
    const int lane = threadIdx.x;
    const int tok = x[t];
    const float* row = emb + (long long)tok * EDIM;
    float v[5];
    float ss = 0.f;
    #pragma unroll
    for (int i = 0; i < 5; i++) {
        const int c = lane + i * 64;
        const float f = (c < EDIM) ? row[c] : 0.f;
        v[i] = f;
        ss += f * f;
    }
    #pragma unroll
    for (int o = 32; o > 0; o >>= 1) ss += __shfl_xor(ss, o);
    const float inv = rsqrtf(fmaxf(ss, 1e-12f));
    float* orow = out + (long long)t * EDIM;
    u16* hrow = H ? H + (long long)t * 608 : nullptr;
    u16* lrow = L ? L + (long long)t * 608 : nullptr;
    #pragma unroll
    for (int i = 0; i < 5; i++) {
        const int c = lane + i * 64;
        if (c < EDIM) {
            const float val = v[i] * inv;
            orow[c] = val;
            if (hrow) {
                const u16 h = f2bf(val);
                hrow[c] = h;
                lrow[c] = f2bf(val - bf2f(h));
            }
        }
    }
    if (hrow && lane < 8) { hrow[600 + lane] = 0; lrow[600 + lane] = 0; }
}

__global__ void softmax_row_kernel(float* __restrict__ att, const float* __restrict__ bias_ptr,
                                   int use_bias)
{
    const int row = blockIdx.x;
    const int i = row & (SEQ - 1);
    const int lane = threadIdx.x;
    float* p = att + (long long)row * SEQ;
    float b0 = 0.f, b1 = 0.f;
    if (use_bias) {
        const float bias = bias_ptr[0];
        int d0 = i - lane;        d0 = d0 < 0 ? -d0 : d0;
        int d1 = i - (lane + 64); d1 = d1 < 0 ? -d1 : d1;
        b0 = (d0 >= 10) ? bias : 0.f;
        b1 = (d1 >= 10) ? bias : 0.f;
    }
    const float v0 = p[lane] + b0;
    const float v1 = p[lane + 64] + b1;
    float m = fmaxf(v0, v1);
    #pragma unroll
    for (int o = 32; o > 0; o >>= 1) m = fmaxf(m, __shfl_xor(m, o));
    const float e0 = __expf(v0 - m);
    const float e1 = __expf(v1 - m);
    float s = e0 + e1;
    #pragma unroll
    for (int o = 32; o > 0; o >>= 1) s += __shfl_xor(s, o);
    const float inv = 1.f / s;
    p[lane] = e0 * inv;
    p[lane + 64] = e1 * inv;
}

__global__ void softmax_col_kernel(const float* __restrict__ sim, float* __restrict__ smt)
{
    const int cid = blockIdx.x;
    const int b = cid >> 7;
    const int j = cid & 127;
    const int lane = threadIdx.x;
    const float* p = sim + (long long)b * (SEQ * SEQ) + j;
    const float v0 = p[lane * SEQ];
    const float v1 = p[(lane + 64) * SEQ];
    float m = fmaxf(v0, v1);
    #pragma unroll
    for (int o = 32; o > 0; o >>= 1) m = fmaxf(m, __shfl_xor(m, o));
    const float e0 = __expf(v0 - m);
    const float e1 = __expf(v1 - m);
    float s = e0 + e1;
    #pragma unroll
    for (int o = 32; o > 0; o >>= 1) s += __shfl_xor(s, o);
    const float inv = 1.f / s;
    float* q = smt + (long long)b * (SEQ * SEQ) + (long long)j * SEQ;
    q[lane] = e0 * inv;
    q[lane + 64] = e1 * inv;
}

__global__ void mask_sim_kernel(float* __restrict__ sim, const int* __restrict__ sizes)
{
    const int idx = blockIdx.x * 256 + threadIdx.x;
    const int b = idx >> 14;
    const int i = (idx >> 7) & 127;
    const int j = idx & 127;
    if (i >= sizes[b] || j >= sizes[BATCH + b]) sim[idx] = 0.f;
}

__global__ void pool_kernel(const float* __restrict__ v, const int* __restrict__ sizes,
                            float* __restrict__ out)
{
    const int b = blockIdx.x;
    const int sz = sizes[b];
    const float* p = v + (long long)b * SEQ * 400;
    for (int n = threadIdx.x; n < 400; n += blockDim.x) {
        float acc = 0.f;
        for (int s = 0; s < sz; s++) acc += p[s * 400 + n];
        out[b * 400 + n] = acc;
    }
}

__global__ void agg_kernel(const float* __restrict__ v1s, const float* __restrict__ v2s,
                           const float* __restrict__ w_agg, float* __restrict__ y)
{
    const int b = blockIdx.x;
    const int lane = threadIdx.x;
    float a0 = 0.f, a1 = 0.f, a2 = 0.f;
    for (int k = lane; k < 800; k += 64) {
        const float v = (k < 400) ? v1s[b * 400 + k] : v2s[b * 400 + k - 400];
        a0 = fmaf(v, w_agg[k * 3 + 0], a0);
        a1 = fmaf(v, w_agg[k * 3 + 1], a1);
        a2 = fmaf(v, w_agg[k * 3 + 2], a2);
    }
    #pragma unroll
    for (int o = 32; o > 0; o >>= 1) {
        a0 += __shfl_xor(a0, o);
        a1 += __shfl_xor(a1, o);
        a2 += __shfl_xor(a2, o);
    }
    if (lane == 0) {
        y[b * 3 + 0] = fmaxf(a0, 0.f);
        y[b * 3 + 1] = fmaxf(a1, 0.f);
        y[b * 3 + 2] = fmaxf(a2, 0.f);
    }
}

static inline void launch_gemm(hipStream_t st, bool bt, const float* A, const float* B,
                               float* C, int M, int N, int K, int lda, int ldb, int ldc,
                               long long sA, long long sB, long long sC, int batch, int flags,
                               u16* Hh = nullptr, u16* Hl = nullptr, int hld = 0, long long sH = 0)
{
    dim3 grid((N + 63) / 64, (M + 63) / 64, batch);
    if (bt)
        gemm_kernel<true><<<grid, 256, 0, st>>>(A, B, C, M, N, K, lda, ldb, ldc, sA, sB, sC,
                                                flags, Hh, Hl, hld, sH);
    else
        gemm_kernel<false><<<grid, 256, 0, st>>>(A, B, C, M, N, K, lda, ldb, ldc, sA, sB, sC,
                                                 flags, Hh, Hl, hld, sH);
}

extern "C" void kernel_launch(void* const* d_in, const int* in_sizes, int n_in,
                              void* d_out, int out_size, void* d_ws, size_t ws_size,
                              hipStream_t stream)
{
    (void)in_sizes; (void)n_in; (void)out_size;
    const int*   x1         = (const int*)d_in[0];
    const int*   x2         = (const int*)d_in[1];
    const float* emb        = (const float*)d_in[2];
    const float* w_intra    = (const float*)d_in[3];
    const float* bias_intra = (const float*)d_in[4];
    const float* w_proj1    = (const float*)d_in[5];
    const float* w_proj2    = (const float*)d_in[6];
    const float* w_att      = (const float*)d_in[7];
    const float* w_cmp1     = (const float*)d_in[8];
    const float* w_cmp2     = (const float*)d_in[9];
    const float* w_agg      = (const float*)d_in[10];
    float* y  = (float*)d_out;
    float* ws = (float*)d_ws;

    const size_t NEED_MFMA = 359155712ull;   // bytes for the split-bf16 path

    if (ws_size >= NEED_MFMA) {
        // ---------------- split-bf16 MFMA path ----------------
        float* X1CAT = ws;                        // [32768,400]: x1p | beta
        float* X2CAT = X1CAT + 13107200;          // [32768,400]: x2p | alpha
        float* EBUF  = X2CAT + 13107200;          // [32768,300] e fp32 (V overlays later)
        float* FBUF  = EBUF  + 9830400;           // [32768,300] f fp32 / F2
        float* ATT   = FBUF  + 9830400;           // [256,128,128] att / sim
        float* SMT   = ATT   + 4194304;           // [256,128,128] col-softmax^T
        float* V1S   = SMT   + 4194304;           // [256,400]
        float* V2S   = V1S + 102400;              // [256,400]
        int*   SIZES = (int*)(V2S + 102400);      // [2,256] + pad to 512
        u16* EH   = (u16*)(V2S + 102400 + 512);   // [32768][608] hi  (CH overlays)
        u16* EL   = EH + 19922944;                // [32768][608] lo  (CL overlays)
        u16* CH   = EH;                           // [32768][416] compare-A hi
        u16* CL   = EL;
        u16* P1H  = EL + 19922944;                // [32768][224] x1p hi
        u16* P1L  = P1H + 7340032;
        u16* P2H  = P1L + 7340032;
        u16* P2L  = P2H + 7340032;
        u16* WIH  = P2L + 7340032;                // w_intra^T  [300][320]
        u16* WIL  = WIH + 96000;
        u16* WP1H = WIL + 96000;                  // w_proj1^T  [200][608]
        u16* WP1L = WP1H + 121600;
        u16* WP2H = WP1L + 121600;
        u16* WP2L = WP2H + 121600;
        u16* WAH  = WP2L + 121600;                // w_att^T    [200][224]
        u16* WAL  = WAH + 44800;
        u16* WC1H = WAL + 44800;                  // w_cmp1^T   [400][416]
        u16* WC1L = WC1H + 166400;
        u16* WC2H = WC1L + 166400;
        u16* WC2L = WC2H + 166400;

        sizes_kernel<<<dim3(BATCH, 2), 128, 0, stream>>>(x1, x2, SIZES);

        // weight transpose + hi/lo split (tiny)
        convert_wt_kernel<<<dim3(2, 300), 256, 0, stream>>>(w_intra, 300, 300, WIH, WIL, 320);
        convert_wt_kernel<<<dim3(3, 200), 256, 0, stream>>>(w_proj1, 600, 200, WP1H, WP1L, 608);
        convert_wt_kernel<<<dim3(3, 200), 256, 0, stream>>>(w_proj2, 600, 200, WP2H, WP2L, 608);
        convert_wt_kernel<<<dim3(1, 200), 256, 0, stream>>>(w_att,  200, 200, WAH,  WAL,  224);
        convert_wt_kernel<<<dim3(2, 400), 256, 0, stream>>>(w_cmp1, 400, 400, WC1H, WC1L, 416);
        convert_wt_kernel<<<dim3(2, 400), 256, 0, stream>>>(w_cmp2, 400, 400, WC2H, WC2L, 416);

        for (int side = 0; side < 2; side++) {
            const int* x  = side ? x2 : x1;
            float* XCAT   = side ? X2CAT : X1CAT;
            u16* PH  = side ? P2H : P1H;
            u16* PL  = side ? P2L : P1L;
            u16* WPH = side ? WP2H : WP1H;
            u16* WPL = side ? WP2L : WP1L;

            // e (fp32 + hi/lo cols 0:300 of [.,608], pad 600:608 zeroed)
            gather_norm_kernel<<<BSTOK, 64, 0, stream>>>(x, emb, EBUF, EH, EL);
            // f = relu(e @ w_intra)   (Kp=320; cols 300:320 of EH are garbage x B-zero = 0)
            gemm_mfma<<<dim3(3, 256), 256, 0, stream>>>(EH, EL, WIH, WIL, FBUF, nullptr, nullptr,
                BSTOK, EDIM, 320, 608, 320, EDIM, 0, 0, F_RELU);
            // att[b] = f f^T  (fp32 batched NT)
            launch_gemm(stream, true, FBUF, FBUF, ATT, SEQ, SEQ, EDIM, EDIM, EDIM, SEQ,
                        (long long)SEQ * EDIM, (long long)SEQ * EDIM, (long long)SEQ * SEQ,
                        BATCH, 0);
            softmax_row_kernel<<<BSTOK, 64, 0, stream>>>(ATT, bias_intra, 1);
            // xp = sm @ e  -> hi/lo directly into EH/EL cols 300:600 (no fp32 xp needed)
            launch_gemm(stream, false, ATT, EBUF, nullptr, SEQ, EDIM, SEQ, SEQ, EDIM, 0,
                        (long long)SEQ * SEQ, (long long)SEQ * EDIM, 0, BATCH, 0,
                        EH + 300, EL + 300, 608, (long long)SEQ * 608);
            // x_proj = relu([e|xp] @ wp) -> fp32 XCAT cols 0:200 + hi/lo P (padded to 224)
            gemm_mfma<<<dim3(2, 256), 256, 0, stream>>>(EH, EL, WPH, WPL, XCAT, PH, PL,
                BSTOK, PDIM, 608, 608, 608, 400, 224, 224, F_RELU);
        }

        float* F1  = EBUF;
        float* F2  = FBUF;
        float* SIM = ATT;
        float* V   = EBUF;   // [32768,400], overlays EBUF+part of FBUF (F1/F2 dead by then)

        // f1/f2 = relu(x_proj @ w_att)
        gemm_mfma<<<dim3(2, 256), 256, 0, stream>>>(P1H, P1L, WAH, WAL, F1, nullptr, nullptr,
            BSTOK, PDIM, 224, 224, 224, PDIM, 0, 0, F_RELU);
        gemm_mfma<<<dim3(2, 256), 256, 0, stream>>>(P2H, P2L, WAH, WAL, F2, nullptr, nullptr,
            BSTOK, PDIM, 224, 224, 224, PDIM, 0, 0, F_RELU);
        // sim[b] = f1 f2^T
        launch_gemm(stream, true, F1, F2, SIM, SEQ, SEQ, PDIM, PDIM, PDIM, SEQ,
                    (long long)SEQ * PDIM, (long long)SEQ * PDIM, (long long)SEQ * SEQ,
                    BATCH, 0);
        mask_sim_kernel<<<(BATCH * SEQ * SEQ) / 256, 256, 0, stream>>>(SIM, SIZES);
        softmax_col_kernel<<<BSTOK, 64, 0, stream>>>(SIM, SMT);
        softmax_row_kernel<<<BSTOK, 64, 0, stream>>>(SIM, bias_intra, 0);
        // beta -> X1CAT cols 200:400 ; alpha -> X2CAT cols 200:400
        launch_gemm(stream, false, SIM, X2CAT, X1CAT + 200, SEQ, PDIM, SEQ, SEQ, 400, 400,
                    (long long)SEQ * SEQ, (long long)SEQ * 400, (long long)SEQ * 400, BATCH, 0);
        launch_gemm(stream, false, SMT, X1CAT, X2CAT + 200, SEQ, PDIM, SEQ, SEQ, 400, 400,
                    (long long)SEQ * SEQ, (long long)SEQ * 400, (long long)SEQ * 400, BATCH, 0);

        // compare + pool (EH/EL region is free -> reuse as CH/CL)
        convert_hilo_kernel<<<dim3(2, BSTOK), 256, 0, stream>>>(X1CAT, 400, 400, CH, CL, 416, 416);
        gemm_mfma<<<dim3(4, 256), 256, 0, stream>>>(CH, CL, WC1H, WC1L, V, nullptr, nullptr,
            BSTOK, 400, 416, 416, 416, 400, 0, 0, F_RELU);
        pool_kernel<<<BATCH, 256, 0, stream>>>(V, SIZES, V1S);
        convert_hilo_kernel<<<dim3(2, BSTOK), 256, 0, stream>>>(X2CAT, 400, 400, CH, CL, 416, 416);
        gemm_mfma<<<dim3(4, 256), 256, 0, stream>>>(CH, CL, WC2H, WC2L, V, nullptr, nullptr,
            BSTOK, 400, 416, 416, 416, 400, 0, 0, F_RELU);
        pool_kernel<<<BATCH, 256, 0, stream>>>(V, SIZES + BATCH, V2S);

        agg_kernel<<<BATCH, 64, 0, stream>>>(V1S, V2S, w_agg, y);
    } else {
        // ---------------- fp32 fallback (round-1 proven path) ----------------
        float* X1CAT = ws;
        float* X2CAT = X1CAT + 13107200;
        float* EBUF  = X2CAT + 13107200;
        float* FBUF  = EBUF + 9830400;
        float* ATT   = FBUF + 9830400;
        float* XPB   = ATT + 4194304;
        float* V1S   = XPB + 9830400;
        float* V2S   = V1S + 102400;
        int*   SIZES = (int*)(V2S + 102400);

        sizes_kernel<<<dim3(BATCH, 2), 128, 0, stream>>>(x1, x2, SIZES);

        for (int side = 0; side < 2; side++) {
            const int*   x    = side ? x2 : x1;
            const float* wp   = side ? w_proj2 : w_proj1;
            float*       XCAT = side ? X2CAT : X1CAT;

            gather_norm_kernel<<<BSTOK, 64, 0, stream>>>(x, emb, EBUF, nullptr, nullptr);
            launch_gemm(stream, false, EBUF, w_intra, FBUF, BSTOK, EDIM, EDIM,
                        EDIM, EDIM, EDIM, 0, 0, 0, 1, F_RELU);
            launch_gemm(stream, true, FBUF, FBUF, ATT, SEQ, SEQ, EDIM,
                        EDIM, EDIM, SEQ, (long long)SEQ * EDIM, (long long)SEQ * EDIM,
                        (long long)SEQ * SEQ, BATCH, 0);
            softmax_row_kernel<<<BSTOK, 64, 0, stream>>>(ATT, bias_intra, 1);
            launch_gemm(stream, false, ATT, EBUF, XPB, SEQ, EDIM, SEQ,
                        SEQ, EDIM, EDIM, (long long)SEQ * SEQ, (long long)SEQ * EDIM,
                        (long long)SEQ * EDIM, BATCH, 0);
            launch_gemm(stream, false, EBUF, wp, XCAT, BSTOK, PDIM, EDIM,
                        EDIM, PDIM, 400, 0, 0, 0, 1, 0);
            launch_gemm(stream, false, XPB, wp + EDIM * PDIM, XCAT, BSTOK, PDIM, EDIM,
                        EDIM, PDIM, 400, 0, 0, 0, 1, F_RELU | F_ACCUM);
        }

        float* F1  = EBUF;
        float* F2  = FBUF;
        float* SIM = ATT;
        float* SMT = XPB;

        launch_gemm(stream, false, X1CAT, w_att, F1, BSTOK, PDIM, PDIM,
                    400, PDIM, PDIM, 0, 0, 0, 1, F_RELU);
        launch_gemm(stream, false, X2CAT, w_att, F2, BSTOK, PDIM, PDIM,
                    400, PDIM, PDIM, 0, 0, 0, 1, F_RELU);
        launch_gemm(stream, true, F1, F2, SIM, SEQ, SEQ, PDIM,
                    PDIM, PDIM, SEQ, (long long)SEQ * PDIM, (long long)SEQ * PDIM,
                    (long long)SEQ * SEQ, BATCH, 0);
        mask_sim_kernel<<<(BATCH * SEQ * SEQ) / 256, 256, 0, stream>>>(SIM, SIZES);
        softmax_col_kernel<<<BSTOK, 64, 0, stream>>>(SIM, SMT);
        softmax_row_kernel<<<BSTOK, 64, 0, stream>>>(SIM, bias_intra, 0);
        launch_gemm(stream, false, SIM, X2CAT, X1CAT + 200, SEQ, PDIM, SEQ,
                    SEQ, 400, 400, (long long)SEQ * SEQ, (long long)SEQ * 400,
                    (long long)SEQ * 400, BATCH, 0);
        launch_gemm(stream, false, SMT, X1CAT, X2CAT + 200, SEQ, PDIM, SEQ,
                    SEQ, 400, 400, (long long)SEQ * SEQ, (long long)SEQ * 400,
                    (long long)SEQ * 400, BATCH, 0);

        float* V = EBUF;
        launch_gemm(stream, false, X1CAT, w_cmp1, V, BSTOK, 400, 400,
                    400, 400, 400, 0, 0, 0, 1, F_RELU);
        pool_kernel<<<BATCH, 256, 0, stream>>>(V, SIZES, V1S);
        launch_gemm(stream, false, X2CAT, w_cmp2, V, BSTOK, 400, 400,
                    400, 400, 400, 0, 0, 0, 1, F_RELU);
        pool_kernel<<<BATCH, 256, 0, stream>>>(V, SIZES + BATCH, V2S);

        agg_kernel<<<BATCH, 64, 0, stream>>>(V1S, V2S, w_agg, y);
    }
}

// Round 4
// 1051.808 us; speedup vs baseline: 1.7376x; 1.7376x over previous
//
#include <hip/hip_runtime.h>

#define BATCH 256
#define SEQ   128
#define EDIM  300
#define PDIM  200
#define BSTOK (BATCH * SEQ)

#define F_RELU  1

typedef unsigned short u16;
typedef __attribute__((ext_vector_type(8))) short bf16x8;   // 8 bf16 in 4 VGPRs
typedef __attribute__((ext_vector_type(4))) float f32x4;

__device__ __forceinline__ u16 f2bf(float x) {
    unsigned u = __float_as_uint(x);
    unsigned r = u + 0x7fffu + ((u >> 16) & 1u);   // round-to-nearest-even
    return (u16)(r >> 16);
}
__device__ __forceinline__ float bf2f(u16 h) {
    return __uint_as_float(((unsigned)h) << 16);
}

// ---------------------------------------------------------------------------
// fp32 tiled GEMM for the batched S x S attention GEMMs (round-1 proven).
// 64x64 tile, BK=16, 256 threads, 4x4 microtile. NT variant via template.
// ---------------------------------------------------------------------------
template <bool BT>
__global__ __launch_bounds__(256) void gemm_kernel(
    const float* __restrict__ A, const float* __restrict__ Bm,
    float* __restrict__ C, int M, int N, int K, int lda, int ldb, int ldc,
    long long sA, long long sB, long long sC, int flags)
{
    __shared__ float As[16][68];
    __shared__ float Bs[16][68];

    const int bz = blockIdx.z;
    A  += (long long)bz * sA;
    Bm += (long long)bz * sB;
    C  += (long long)bz * sC;

    const int tid = threadIdx.x;
    const int bn = blockIdx.x * 64;
    const int bm = blockIdx.y * 64;
    const int tx = tid & 15;
    const int ty = tid >> 4;

    float acc[4][4] = {};

    for (int k0 = 0; k0 < K; k0 += 16) {
        {
            const int lk = tid & 15;
            const int m0 = tid >> 4;
            const int gk = k0 + lk;
            #pragma unroll
            for (int i = 0; i < 4; i++) {
                const int m = m0 + i * 16;
                const int gm = bm + m;
                float v = 0.f;
                if (gm < M && gk < K) v = A[(long long)gm * lda + gk];
                As[lk][m] = v;
            }
        }
        if (!BT) {
            const int ln = tid & 63;
            const int kb = tid >> 6;
            const int gn = bn + ln;
            #pragma unroll
            for (int i = 0; i < 4; i++) {
                const int k = kb + i * 4;
                const int gk = k0 + k;
                float v = 0.f;
                if (gk < K && gn < N) v = Bm[(long long)gk * ldb + gn];
                Bs[k][ln] = v;
            }
        } else {
            const int lk = tid & 15;
            const int n0 = tid >> 4;
            const int gk = k0 + lk;
            #pragma unroll
            for (int i = 0; i < 4; i++) {
                const int n = n0 + i * 16;
                const int gn = bn + n;
                float v = 0.f;
                if (gn < N && gk < K) v = Bm[(long long)gn * ldb + gk];
                Bs[lk][n] = v;
            }
        }
        __syncthreads();

        #pragma unroll
        for (int k = 0; k < 16; k++) {
            const float4 av = *reinterpret_cast<const float4*>(&As[k][ty * 4]);
            const float4 bv = *reinterpret_cast<const float4*>(&Bs[k][tx * 4]);
            const float a[4] = {av.x, av.y, av.z, av.w};
            const float b[4] = {bv.x, bv.y, bv.z, bv.w};
            #pragma unroll
            for (int i = 0; i < 4; i++)
                #pragma unroll
                for (int j = 0; j < 4; j++)
                    acc[i][j] = fmaf(a[i], b[j], acc[i][j]);
        }
        __syncthreads();
    }

    #pragma unroll
    for (int i = 0; i < 4; i++) {
        const int gm = bm + ty * 4 + i;
        if (gm >= M) continue;
        #pragma unroll
        for (int j = 0; j < 4; j++) {
            const int gn = bn + tx * 4 + j;
            if (gn >= N) continue;
            float v = acc[i][j];
            if (flags & F_RELU) v = fmaxf(v, 0.f);
            C[(long long)gm * ldc + gn] = v;
        }
    }
}

// ---------------------------------------------------------------------------
// Split-bf16 MFMA GEMM, fp32 A operand converted during LDS staging.
//   C[M,N] = relu?( A[M,Kp]_fp32 * (Bh+Bl)^T )   B: [N][ldb] bf16 hi/lo K-major
// A split: hi = truncate-to-bf16(v), lo = truncate-to-bf16(v - hi).
// 3 MFMAs per fragment pair (Ah*Bh + Ah*Bl + Al*Bh), rel err ~2^-16.
// Kp multiple of 32 (B rows zero-padded in k >= K_true; A k-pad reads are
// finite garbage * 0). M multiple of 128. 128x128 tile, BK=32, 4 waves.
// Staging coverage: 256 threads x 16 elements (2 x uint4 per LDS array) =
// 4096 u16 = full 128x32 tile for BOTH A and B.   <-- round-3 bug: B staged
// only one uint4 (8 u16) per thread, leaving cols 8-15/24-31 stale.
// ---------------------------------------------------------------------------
__global__ __launch_bounds__(256) void gemm_mfma_af32(
    const float* __restrict__ A,
    const u16* __restrict__ Bh, const u16* __restrict__ Bl,
    float* __restrict__ C, int M, int N, int Kp, int lda, int ldb, int ldc,
    int flags)
{
    // rows padded to 40 u16 (80 B = 20 banks) -> ~2-way conflicts (free)
    __shared__ u16 AsH[128][40];
    __shared__ u16 AsL[128][40];
    __shared__ u16 BsH[128][40];
    __shared__ u16 BsL[128][40];

    const int tid  = threadIdx.x;
    const int bm   = blockIdx.y * 128;
    const int bn   = blockIdx.x * 128;
    const int wave = tid >> 6;
    const int lane = tid & 63;
    const int wm   = (wave >> 1) * 64;   // wave quadrant
    const int wn   = (wave & 1) * 64;
    const int lr   = lane & 15;          // fragment row/col
    const int quad = lane >> 4;          // k-offset = quad*8 ; C-row = quad*4+r

    // staging: thread t covers row sr = t>>1, 16 elements at col sc = (t&1)*16
    const int sr = tid >> 1;
    const int sc = (tid & 1) * 16;

    f32x4 acc[4][4];
    #pragma unroll
    for (int i = 0; i < 4; i++)
        #pragma unroll
        for (int j = 0; j < 4; j++)
            acc[i][j] = (f32x4)(0.0f);

    for (int k0 = 0; k0 < Kp; k0 += 32) {
        // ---- A: 16 fp32 -> 16 hi + 16 lo bf16 (packed u32 pairs) ----
        {
            const float* ap = A + (long long)(bm + sr) * lda + k0 + sc;
            float va[16];
            #pragma unroll
            for (int i = 0; i < 4; i++) {
                const float4 v = *(const float4*)(ap + i * 4);
                va[i * 4 + 0] = v.x; va[i * 4 + 1] = v.y;
                va[i * 4 + 2] = v.z; va[i * 4 + 3] = v.w;
            }
            unsigned hp[8], lp[8];
            #pragma unroll
            for (int i = 0; i < 8; i++) {
                const unsigned u0 = __float_as_uint(va[2 * i]);
                const unsigned u1 = __float_as_uint(va[2 * i + 1]);
                const unsigned h0 = u0 & 0xffff0000u;
                const unsigned h1 = u1 & 0xffff0000u;
                hp[i] = (u0 >> 16) | h1;
                const float r0 = va[2 * i]     - __uint_as_float(h0);
                const float r1 = va[2 * i + 1] - __uint_as_float(h1);
                lp[i] = (__float_as_uint(r0) >> 16) | (__float_as_uint(r1) & 0xffff0000u);
            }
            *(uint4*)&AsH[sr][sc]     = make_uint4(hp[0], hp[1], hp[2], hp[3]);
            *(uint4*)&AsH[sr][sc + 8] = make_uint4(hp[4], hp[5], hp[6], hp[7]);
            *(uint4*)&AsL[sr][sc]     = make_uint4(lp[0], lp[1], lp[2], lp[3]);
            *(uint4*)&AsL[sr][sc + 8] = make_uint4(lp[4], lp[5], lp[6], lp[7]);
        }
        // ---- B: pre-split weights, straight copy (16 u16 per thread) ----
        {
            uint4 wh0 = make_uint4(0, 0, 0, 0), wh1 = make_uint4(0, 0, 0, 0);
            uint4 wl0 = make_uint4(0, 0, 0, 0), wl1 = make_uint4(0, 0, 0, 0);
            const int gn = bn + sr;
            if (gn < N) {
                const long long br = (long long)gn * ldb + k0 + sc;
                wh0 = *(const uint4*)(Bh + br);
                wh1 = *(const uint4*)(Bh + br + 8);
                wl0 = *(const uint4*)(Bl + br);
                wl1 = *(const uint4*)(Bl + br + 8);
            }
            *(uint4*)&BsH[sr][sc]     = wh0;
            *(uint4*)&BsH[sr][sc + 8] = wh1;
            *(uint4*)&BsL[sr][sc]     = wl0;
            *(uint4*)&BsL[sr][sc + 8] = wl1;
        }
        __syncthreads();

        bf16x8 fah[4], fal[4], fbh[4], fbl[4];
        #pragma unroll
        for (int i = 0; i < 4; i++) {
            fah[i] = *(const bf16x8*)&AsH[wm + i * 16 + lr][quad * 8];
            fal[i] = *(const bf16x8*)&AsL[wm + i * 16 + lr][quad * 8];
            fbh[i] = *(const bf16x8*)&BsH[wn + i * 16 + lr][quad * 8];
            fbl[i] = *(const bf16x8*)&BsL[wn + i * 16 + lr][quad * 8];
        }
        #pragma unroll
        for (int i = 0; i < 4; i++)
            #pragma unroll
            for (int j = 0; j < 4; j++) {
                acc[i][j] = __builtin_amdgcn_mfma_f32_16x16x32_bf16(fah[i], fbh[j], acc[i][j], 0, 0, 0);
                acc[i][j] = __builtin_amdgcn_mfma_f32_16x16x32_bf16(fah[i], fbl[j], acc[i][j], 0, 0, 0);
                acc[i][j] = __builtin_amdgcn_mfma_f32_16x16x32_bf16(fal[i], fbh[j], acc[i][j], 0, 0, 0);
            }
        __syncthreads();
    }

    // C/D layout: col = lane&15, row = quad*4 + r  [verified m89/m91]
    #pragma unroll
    for (int i = 0; i < 4; i++) {
        #pragma unroll
        for (int j = 0; j < 4; j++) {
            const int gn = bn + wn + j * 16 + lr;
            if (gn >= N) continue;
            #pragma unroll
            for (int r = 0; r < 4; r++) {
                const int gm = bm + wm + i * 16 + quad * 4 + r;
                float v = acc[i][j][r];
                if (flags & F_RELU) v = fmaxf(v, 0.f);
                C[(long long)gm * ldc + gn] = v;
            }
        }
    }
}

// weight [K][N] fp32 -> transposed hi/lo bf16 [N][Kp], zero-padded k in [K,Kp)
__global__ void convert_wt_kernel(const float* __restrict__ src, int K, int N,
                                  u16* __restrict__ H, u16* __restrict__ L, int Kp)
{
    const int n = blockIdx.y;
    const int k = blockIdx.x * 256 + threadIdx.x;
    if (k >= Kp) return;
    const float v = (k < K) ? src[(long long)k * N + n] : 0.f;
    const u16 h = f2bf(v);
    const long long di = (long long)n * Kp + k;
    H[di] = h;
    L[di] = f2bf(v - bf2f(h));
}

// sizes[side*256 + b] = count_nonzero(x_side[b, :])
__global__ void sizes_kernel(const int* __restrict__ x1, const int* __restrict__ x2,
                             int* __restrict__ sizes)
{
    const int b = blockIdx.x;
    const int side = blockIdx.y;
    const int* x = (side ? x2 : x1) + b * SEQ;
    const int nz = (x[threadIdx.x] != 0) ? 1 : 0;
    const unsigned long long bal = __ballot(nz);
    __shared__ int part[2];
    if ((threadIdx.x & 63) == 0) part[threadIdx.x >> 6] = __popcll(bal);
    __syncthreads();
    if (threadIdx.x == 0) sizes[side * BATCH + b] = part[0] + part[1];
}

// out[t, 0:300] = emb[x[t], :] / ||emb[x[t], :]||_2  (row stride ld)
__global__ void gather_norm_kernel(const int* __restrict__ x, const float* __restrict__ emb,
                                   float* __restrict__ out, int ld)
{
    const int t = blockIdx.x;
    const int lane = threadIdx.x;
    const int tok = x[t];
    const float* row = emb + (long long)tok * EDIM;
    float v[5];
    float ss = 0.f;
    #pragma unroll
    for (int i = 0; i < 5; i++) {
        const int c = lane + i * 64;
        const float f = (c < EDIM) ? row[c] : 0.f;
        v[i] = f;
        ss += f * f;
    }
    #pragma unroll
    for (int o = 32; o > 0; o >>= 1) ss += __shfl_xor(ss, o);
    const float inv = rsqrtf(fmaxf(ss, 1e-12f));
    float* orow = out + (long long)t * ld;
    #pragma unroll
    for (int i = 0; i < 5; i++) {
        const int c = lane + i * 64;
        if (c < EDIM) orow[c] = v[i] * inv;
    }
}

// Row softmax over last dim (len 128), optional distance bias (|i-j| >= 10).
__global__ void softmax_row_kernel(float* __restrict__ att, const float* __restrict__ bias_ptr,
                                   int use_bias)
{
    const int row = blockIdx.x;
    const int i = row & (SEQ - 1);
    const int lane = threadIdx.x;
    float* p = att + (long long)row * SEQ;
    float b0 = 0.f, b1 = 0.f;
    if (use_bias) {
        const float bias = bias_ptr[0];
        int d0 = i - lane;        d0 = d0 < 0 ? -d0 : d0;
        int d1 = i - (lane + 64); d1 = d1 < 0 ? -d1 : d1;
        b0 = (d0 >= 10) ? bias : 0.f;
        b1 = (d1 >= 10) ? bias : 0.f;
    }
    const float v0 = p[lane] + b0;
    const float v1 = p[lane + 64] + b1;
    float m = fmaxf(v0, v1);
    #pragma unroll
    for (int o = 32; o > 0; o >>= 1) m = fmaxf(m, __shfl_xor(m, o));
    const float e0 = __expf(v0 - m);
    const float e1 = __expf(v1 - m);
    float s = e0 + e1;
    #pragma unroll
    for (int o = 32; o > 0; o >>= 1) s += __shfl_xor(s, o);
    const float inv = 1.f / s;
    p[lane] = e0 * inv;
    p[lane + 64] = e1 * inv;
}

// Column softmax of sim (axis=1), written TRANSPOSED: smt[b,j,i]
__global__ void softmax_col_kernel(const float* __restrict__ sim, float* __restrict__ smt)
{
    const int cid = blockIdx.x;
    const int b = cid >> 7;
    const int j = cid & 127;
    const int lane = threadIdx.x;
    const float* p = sim + (long long)b * (SEQ * SEQ) + j;
    const float v0 = p[lane * SEQ];
    const float v1 = p[(lane + 64) * SEQ];
    float m = fmaxf(v0, v1);
    #pragma unroll
    for (int o = 32; o > 0; o >>= 1) m = fmaxf(m, __shfl_xor(m, o));
    const float e0 = __expf(v0 - m);
    const float e1 = __expf(v1 - m);
    float s = e0 + e1;
    #pragma unroll
    for (int o = 32; o > 0; o >>= 1) s += __shfl_xor(s, o);
    const float inv = 1.f / s;
    float* q = smt + (long long)b * (SEQ * SEQ) + (long long)j * SEQ;
    q[lane] = e0 * inv;
    q[lane + 64] = e1 * inv;
}

// Multiplicative mask: sim[b,i,j] = 0 where i >= size1[b] or j >= size2[b]
__global__ void mask_sim_kernel(float* __restrict__ sim, const int* __restrict__ sizes)
{
    const int idx = blockIdx.x * 256 + threadIdx.x;
    const int b = idx >> 14;
    const int i = (idx >> 7) & 127;
    const int j = idx & 127;
    if (i >= sizes[b] || j >= sizes[BATCH + b]) sim[idx] = 0.f;
}

// out[b,n] = sum_{s < sizes[b]} v[b,s,n], n in [0,400)
__global__ void pool_kernel(const float* __restrict__ v, const int* __restrict__ sizes,
                            float* __restrict__ out)
{
    const int b = blockIdx.x;
    const int sz = sizes[b];
    const float* p = v + (long long)b * SEQ * 400;
    for (int n = threadIdx.x; n < 400; n += blockDim.x) {
        float acc = 0.f;
        for (int s = 0; s < sz; s++) acc += p[s * 400 + n];
        out[b * 400 + n] = acc;
    }
}

// y[b,c] = relu(sum_k concat(v1s,v2s)[b,k] * w_agg[k,c]), K=800, C=3
__global__ void agg_kernel(const float* __restrict__ v1s, const float* __restrict__ v2s,
                           const float* __restrict__ w_agg, float* __restrict__ y)
{
    const int b = blockIdx.x;
    const int lane = threadIdx.x;
    float a0 = 0.f, a1 = 0.f, a2 = 0.f;
    for (int k = lane; k < 800; k += 64) {
        const float v = (k < 400) ? v1s[b * 400 + k] : v2s[b * 400 + k - 400];
        a0 = fmaf(v, w_agg[k * 3 + 0], a0);
        a1 = fmaf(v, w_agg[k * 3 + 1], a1);
        a2 = fmaf(v, w_agg[k * 3 + 2], a2);
    }
    #pragma unroll
    for (int o = 32; o > 0; o >>= 1) {
        a0 += __shfl_xor(a0, o);
        a1 += __shfl_xor(a1, o);
        a2 += __shfl_xor(a2, o);
    }
    if (lane == 0) {
        y[b * 3 + 0] = fmaxf(a0, 0.f);
        y[b * 3 + 1] = fmaxf(a1, 0.f);
        y[b * 3 + 2] = fmaxf(a2, 0.f);
    }
}

static inline void launch_gemm(hipStream_t st, bool bt, const float* A, const float* B,
                               float* C, int M, int N, int K, int lda, int ldb, int ldc,
                               long long sA, long long sB, long long sC, int batch, int flags)
{
    dim3 grid((N + 63) / 64, (M + 63) / 64, batch);
    if (bt)
        gemm_kernel<true><<<grid, 256, 0, st>>>(A, B, C, M, N, K, lda, ldb, ldc, sA, sB, sC, flags);
    else
        gemm_kernel<false><<<grid, 256, 0, st>>>(A, B, C, M, N, K, lda, ldb, ldc, sA, sB, sC, flags);
}

static inline void launch_mfma(hipStream_t st, const float* A, const u16* Bh, const u16* Bl,
                               float* C, int M, int N, int Kp, int lda, int ldb, int ldc,
                               int flags)
{
    dim3 grid((N + 127) / 128, M / 128);
    gemm_mfma_af32<<<grid, 256, 0, st>>>(A, Bh, Bl, C, M, N, Kp, lda, ldb, ldc, flags);
}

extern "C" void kernel_launch(void* const* d_in, const int* in_sizes, int n_in,
                              void* d_out, int out_size, void* d_ws, size_t ws_size,
                              hipStream_t stream)
{
    (void)in_sizes; (void)n_in; (void)out_size; (void)ws_size;
    const int*   x1         = (const int*)d_in[0];
    const int*   x2         = (const int*)d_in[1];
    const float* emb        = (const float*)d_in[2];
    const float* w_intra    = (const float*)d_in[3];
    const float* bias_intra = (const float*)d_in[4];
    const float* w_proj1    = (const float*)d_in[5];
    const float* w_proj2    = (const float*)d_in[6];
    const float* w_att      = (const float*)d_in[7];
    const float* w_cmp1     = (const float*)d_in[8];
    const float* w_cmp2     = (const float*)d_in[9];
    const float* w_agg      = (const float*)d_in[10];
    float* y  = (float*)d_out;
    float* ws = (float*)d_ws;

    // ---- workspace layout (floats); total 51,253,760 fl = 205.0 MB ----
    float* X1CAT = ws;                        // [32768,400] fp32: x1p | beta
    float* X2CAT = X1CAT + 13107200;          // [32768,400] fp32: x2p | alpha
    float* FBUF  = X2CAT;                     //   alias: intra f [32768,300] (dead before X2CAT written)
    float* EXP   = X2CAT + 13107200;          // [32768,608] fp32: e | xp  (phase A)
    float* F1    = EXP;                       //   phase B alias: f1 [32768,200]
    float* F2    = EXP + 6553600;             //   phase B alias: f2 [32768,200]
    float* SMT   = EXP + 13107200;            //   phase B alias: col-softmax^T [256,128,128]
    float* V     = EXP;                       //   phase C alias: compare out [32768,400]
    float* ATT   = EXP + 19922944;            // [256,128,128] att / sim
    float* V1S   = ATT + 4194304;             // [256,400]
    float* V2S   = V1S + 102400;              // [256,400]
    int*   SIZES = (int*)(V2S + 102400);      // [2,256] + pad to 512 ints
    u16*   WIH   = (u16*)(V2S + 102400 + 512); // w_intra^T [300][320]
    u16*   WIL   = WIH + 96000;
    u16*   WP1H  = WIL + 96000;               // w_proj1^T [200][608]
    u16*   WP1L  = WP1H + 121600;
    u16*   WP2H  = WP1L + 121600;
    u16*   WP2L  = WP2H + 121600;
    u16*   WAH   = WP2L + 121600;             // w_att^T   [200][224]
    u16*   WAL   = WAH + 44800;
    u16*   WC1H  = WAL + 44800;               // w_cmp1^T  [400][416]
    u16*   WC1L  = WC1H + 166400;
    u16*   WC2H  = WC1L + 166400;
    u16*   WC2L  = WC2H + 166400;

    sizes_kernel<<<dim3(BATCH, 2), 128, 0, stream>>>(x1, x2, SIZES);

    // weight transpose + hi/lo split (tiny, 2.9 MB total)
    convert_wt_kernel<<<dim3(2, 300), 256, 0, stream>>>(w_intra, 300, 300, WIH, WIL, 320);
    convert_wt_kernel<<<dim3(3, 200), 256, 0, stream>>>(w_proj1, 600, 200, WP1H, WP1L, 608);
    convert_wt_kernel<<<dim3(3, 200), 256, 0, stream>>>(w_proj2, 600, 200, WP2H, WP2L, 608);
    convert_wt_kernel<<<dim3(1, 200), 256, 0, stream>>>(w_att,  200, 200, WAH,  WAL,  224);
    convert_wt_kernel<<<dim3(2, 400), 256, 0, stream>>>(w_cmp1, 400, 400, WC1H, WC1L, 416);
    convert_wt_kernel<<<dim3(2, 400), 256, 0, stream>>>(w_cmp2, 400, 400, WC2H, WC2L, 416);

    // -------- phase A: per-side intra attention + projection --------
    for (int side = 0; side < 2; side++) {
        const int* x  = side ? x2 : x1;
        float* XCAT   = side ? X2CAT : X1CAT;
        u16* WPH = side ? WP2H : WP1H;
        u16* WPL = side ? WP2L : WP1L;

        // e -> EXP cols 0:300 (ld 608)
        gather_norm_kernel<<<BSTOK, 64, 0, stream>>>(x, emb, EXP, 608);
        // f = relu(e @ w_intra)  [MFMA; Kp=320: A k-pad finite*0]
        launch_mfma(stream, EXP, WIH, WIL, FBUF, BSTOK, EDIM, 320, 608, 320, EDIM, F_RELU);
        // att[b] = f[b] f[b]^T  (fp32 batched NT)
        launch_gemm(stream, true, FBUF, FBUF, ATT, SEQ, SEQ, EDIM, EDIM, EDIM, SEQ,
                    (long long)SEQ * EDIM, (long long)SEQ * EDIM, (long long)SEQ * SEQ,
                    BATCH, 0);
        softmax_row_kernel<<<BSTOK, 64, 0, stream>>>(ATT, bias_intra, 1);
        // xp[b] = sm[b] @ e[b] -> EXP cols 300:600  (fp32 batched NN; B/C disjoint cols)
        launch_gemm(stream, false, ATT, EXP, EXP + 300, SEQ, EDIM, SEQ, SEQ, 608, 608,
                    (long long)SEQ * SEQ, (long long)SEQ * 608, (long long)SEQ * 608,
                    BATCH, 0);
        // x_proj = relu([e|xp] @ wp)  [MFMA; Kp=608] -> XCAT cols 0:200
        launch_mfma(stream, EXP, WPH, WPL, XCAT, BSTOK, PDIM, 608, 608, 608, 400, F_RELU);
    }

    // -------- phase B: cross attention --------
    float* SIM = ATT;

    // f1/f2 = relu(x_proj @ w_att)  [MFMA; Kp=224: A cols 200:224 finite*0]
    launch_mfma(stream, X1CAT, WAH, WAL, F1, BSTOK, PDIM, 224, 400, 224, PDIM, F_RELU);
    launch_mfma(stream, X2CAT, WAH, WAL, F2, BSTOK, PDIM, 224, 400, 224, PDIM, F_RELU);
    // sim[b] = f1[b] f2[b]^T  (fp32 batched NT)
    launch_gemm(stream, true, F1, F2, SIM, SEQ, SEQ, PDIM, PDIM, PDIM, SEQ,
                (long long)SEQ * PDIM, (long long)SEQ * PDIM, (long long)SEQ * SEQ,
                BATCH, 0);
    mask_sim_kernel<<<(BATCH * SEQ * SEQ) / 256, 256, 0, stream>>>(SIM, SIZES);
    softmax_col_kernel<<<BSTOK, 64, 0, stream>>>(SIM, SMT);
    softmax_row_kernel<<<BSTOK, 64, 0, stream>>>(SIM, bias_intra, 0);
    // beta -> X1CAT cols 200:400 ; alpha -> X2CAT cols 200:400  (fp32 batched)
    launch_gemm(stream, false, SIM, X2CAT, X1CAT + 200, SEQ, PDIM, SEQ, SEQ, 400, 400,
                (long long)SEQ * SEQ, (long long)SEQ * 400, (long long)SEQ * 400, BATCH, 0);
    launch_gemm(stream, false, SMT, X1CAT, X2CAT + 200, SEQ, PDIM, SEQ, SEQ, 400, 400,
                (long long)SEQ * SEQ, (long long)SEQ * 400, (long long)SEQ * 400, BATCH, 0);

    // -------- phase C: compare + pool + aggregate --------
    // v1 = relu([x1p|beta] @ w_cmp1)  [MFMA; Kp=416: last 16 k wrap into next
    // row / adjacent mapped buffer, finite * 0]
    launch_mfma(stream, X1CAT, WC1H, WC1L, V, BSTOK, 400, 416, 400, 416, 400, F_RELU);
    pool_kernel<<<BATCH, 256, 0, stream>>>(V, SIZES, V1S);
    launch_mfma(stream, X2CAT, WC2H, WC2L, V, BSTOK, 400, 416, 400, 416, 400, F_RELU);
    pool_kernel<<<BATCH, 256, 0, stream>>>(V, SIZES + BATCH, V2S);

    agg_kernel<<<BATCH, 64, 0, stream>>>(V1S, V2S, w_agg, y);
}

// Round 5
// 933.445 us; speedup vs baseline: 1.9579x; 1.1268x over previous
//
#include <hip/hip_runtime.h>

#define BATCH 256
#define SEQ   128
#define EDIM  300
#define PDIM  200
#define BSTOK (BATCH * SEQ)

#define F_RELU  1
#define F_ACCUM 2

typedef unsigned short u16;
typedef __attribute__((ext_vector_type(8))) short bf16x8;   // 8 bf16 in 4 VGPRs
typedef __attribute__((ext_vector_type(4))) float f32x4;

__device__ __forceinline__ u16 f2bf(float x) {
    unsigned u = __float_as_uint(x);
    unsigned r = u + 0x7fffu + ((u >> 16) & 1u);   // round-to-nearest-even
    return (u16)(r >> 16);
}
__device__ __forceinline__ float bf2f(u16 h) {
    return __uint_as_float(((unsigned)h) << 16);
}

// Load 16 fp32 (or 0 if !row_ok), zero k >= Kvalid, split hi/lo bf16,
// write 2 x uint4 to each LDS slot. 256 threads x 16 elems = full 128x32 tile.
__device__ __forceinline__ void stage16(const float* __restrict__ src, bool row_ok,
                                        int kbase, int Kvalid, u16* dH, u16* dL)
{
    float va[16];
    if (row_ok) {
        #pragma unroll
        for (int i = 0; i < 4; i++) {
            const float4 v = *(const float4*)(src + i * 4);
            va[i * 4 + 0] = v.x; va[i * 4 + 1] = v.y;
            va[i * 4 + 2] = v.z; va[i * 4 + 3] = v.w;
        }
        #pragma unroll
        for (int i = 0; i < 16; i++)
            va[i] = (kbase + i < Kvalid) ? va[i] : 0.f;
    } else {
        #pragma unroll
        for (int i = 0; i < 16; i++) va[i] = 0.f;
    }
    unsigned hp[8], lp[8];
    #pragma unroll
    for (int i = 0; i < 8; i++) {
        const unsigned u0 = __float_as_uint(va[2 * i]);
        const unsigned u1 = __float_as_uint(va[2 * i + 1]);
        const unsigned h0 = u0 & 0xffff0000u;
        const unsigned h1 = u1 & 0xffff0000u;
        hp[i] = (u0 >> 16) | h1;
        const float r0 = va[2 * i]     - __uint_as_float(h0);
        const float r1 = va[2 * i + 1] - __uint_as_float(h1);
        lp[i] = (__float_as_uint(r0) >> 16) | (__float_as_uint(r1) & 0xffff0000u);
    }
    ((uint4*)dH)[0] = make_uint4(hp[0], hp[1], hp[2], hp[3]);
    ((uint4*)dH)[1] = make_uint4(hp[4], hp[5], hp[6], hp[7]);
    ((uint4*)dL)[0] = make_uint4(lp[0], lp[1], lp[2], lp[3]);
    ((uint4*)dL)[1] = make_uint4(lp[4], lp[5], lp[6], lp[7]);
}

// ---------------------------------------------------------------------------
// Flat split-bf16 MFMA GEMM, fp32 A converted during staging, B = pre-split
// weights [N][ldb] bf16 hi/lo K-major (zero-padded k >= K_true).
// 3 MFMAs per fragment pair (AhBh + AhBl + AlBh), rel err ~2^-16.
// 128x128 tile, BK=32, 4 waves. M mult of 128. A k-pad reads: finite * 0.
// Optional: C row-major store (nullable) and/or CT batch-transposed store
// CT[bm/128][gn][gm&127] with batch stride sCT (for G = e @ wp_b).
// ---------------------------------------------------------------------------
__global__ __launch_bounds__(256) void gemm_mfma_af32(
    const float* __restrict__ A,
    const u16* __restrict__ Bh, const u16* __restrict__ Bl,
    float* __restrict__ C, float* __restrict__ CT,
    int M, int N, int Kp, int lda, int ldb, int ldc, long long sCT, int flags)
{
    __shared__ u16 AsH[128][40];
    __shared__ u16 AsL[128][40];
    __shared__ u16 BsH[128][40];
    __shared__ u16 BsL[128][40];

    const int tid  = threadIdx.x;
    const int bm   = blockIdx.y * 128;
    const int bn   = blockIdx.x * 128;
    const int wave = tid >> 6;
    const int lane = tid & 63;
    const int wm   = (wave >> 1) * 64;
    const int wn   = (wave & 1) * 64;
    const int lr   = lane & 15;
    const int quad = lane >> 4;

    const int sr = tid >> 1;
    const int sc = (tid & 1) * 16;

    f32x4 acc[4][4];
    #pragma unroll
    for (int i = 0; i < 4; i++)
        #pragma unroll
        for (int j = 0; j < 4; j++)
            acc[i][j] = (f32x4)(0.0f);

    for (int k0 = 0; k0 < Kp; k0 += 32) {
        // A: fp32 -> hi/lo (no k-mask; weight rows zero-padded handle k-pad)
        stage16(A + (long long)(bm + sr) * lda + k0 + sc, true, 0, 1 << 30,
                &AsH[sr][sc], &AsL[sr][sc]);
        // B: pre-split weights, straight copy (16 u16 per thread per array)
        {
            uint4 wh0 = make_uint4(0, 0, 0, 0), wh1 = make_uint4(0, 0, 0, 0);
            uint4 wl0 = make_uint4(0, 0, 0, 0), wl1 = make_uint4(0, 0, 0, 0);
            const int gn = bn + sr;
            if (gn < N) {
                const long long br = (long long)gn * ldb + k0 + sc;
                wh0 = *(const uint4*)(Bh + br);
                wh1 = *(const uint4*)(Bh + br + 8);
                wl0 = *(const uint4*)(Bl + br);
                wl1 = *(const uint4*)(Bl + br + 8);
            }
            *(uint4*)&BsH[sr][sc]     = wh0;
            *(uint4*)&BsH[sr][sc + 8] = wh1;
            *(uint4*)&BsL[sr][sc]     = wl0;
            *(uint4*)&BsL[sr][sc + 8] = wl1;
        }
        __syncthreads();

        bf16x8 fah[4], fal[4], fbh[4], fbl[4];
        #pragma unroll
        for (int i = 0; i < 4; i++) {
            fah[i] = *(const bf16x8*)&AsH[wm + i * 16 + lr][quad * 8];
            fal[i] = *(const bf16x8*)&AsL[wm + i * 16 + lr][quad * 8];
            fbh[i] = *(const bf16x8*)&BsH[wn + i * 16 + lr][quad * 8];
            fbl[i] = *(const bf16x8*)&BsL[wn + i * 16 + lr][quad * 8];
        }
        #pragma unroll
        for (int i = 0; i < 4; i++)
            #pragma unroll
            for (int j = 0; j < 4; j++) {
                acc[i][j] = __builtin_amdgcn_mfma_f32_16x16x32_bf16(fah[i], fbh[j], acc[i][j], 0, 0, 0);
                acc[i][j] = __builtin_amdgcn_mfma_f32_16x16x32_bf16(fah[i], fbl[j], acc[i][j], 0, 0, 0);
                acc[i][j] = __builtin_amdgcn_mfma_f32_16x16x32_bf16(fal[i], fbh[j], acc[i][j], 0, 0, 0);
            }
        __syncthreads();
    }

    // C/D layout: col = lane&15, row = quad*4 + r
    #pragma unroll
    for (int i = 0; i < 4; i++) {
        #pragma unroll
        for (int j = 0; j < 4; j++) {
            const int gn = bn + wn + j * 16 + lr;
            if (gn >= N) continue;
            #pragma unroll
            for (int r = 0; r < 4; r++) {
                const int gm = bm + wm + i * 16 + quad * 4 + r;
                float v = acc[i][j][r];
                if (flags & F_RELU) v = fmaxf(v, 0.f);
                if (C)  C[(long long)gm * ldc + gn] = v;
                if (CT) CT[(long long)(gm >> 7) * sCT + (long long)gn * 128 + (gm & 127)] = v;
            }
        }
    }
}

// ---------------------------------------------------------------------------
// Batched split-bf16 MFMA GEMM, NT, BOTH operands fp32 converted in staging:
//   C[bz][m][n] (+)= relu?( sum_k A[bz][m][k] * B[bz][n][k] ),  m in [0,128)
// K masked to Kvalid (both operands may carry garbage in [Kvalid, Kp)).
// Optional PT: transposed store PT[bz][n][m] (may alias B: each block writes
// only the B-rows it alone reads, after its final barrier).
// grid: x = ceil(N/128), z = batch.
// ---------------------------------------------------------------------------
__global__ __launch_bounds__(256) void gemm_mfma_bat(
    const float* __restrict__ A, const float* __restrict__ B,
    float* __restrict__ C, float* __restrict__ PT,
    int N, int Kvalid, int Kp, int lda, int ldb, int ldc,
    long long sA, long long sB, long long sC, long long sPT, int flags)
{
    __shared__ u16 AsH[128][40];
    __shared__ u16 AsL[128][40];
    __shared__ u16 BsH[128][40];
    __shared__ u16 BsL[128][40];

    const int bz = blockIdx.z;
    A += (long long)bz * sA;
    B += (long long)bz * sB;
    C += (long long)bz * sC;
    if (PT) PT += (long long)bz * sPT;

    const int tid  = threadIdx.x;
    const int bn   = blockIdx.x * 128;
    const int wave = tid >> 6;
    const int lane = tid & 63;
    const int wm   = (wave >> 1) * 64;
    const int wn   = (wave & 1) * 64;
    const int lr   = lane & 15;
    const int quad = lane >> 4;

    const int sr = tid >> 1;
    const int sc = (tid & 1) * 16;

    f32x4 acc[4][4];
    #pragma unroll
    for (int i = 0; i < 4; i++)
        #pragma unroll
        for (int j = 0; j < 4; j++)
            acc[i][j] = (f32x4)(0.0f);

    for (int k0 = 0; k0 < Kp; k0 += 32) {
        stage16(A + (long long)sr * lda + k0 + sc, true, k0 + sc, Kvalid,
                &AsH[sr][sc], &AsL[sr][sc]);
        const int gn = bn + sr;
        stage16(B + (long long)gn * ldb + k0 + sc, gn < N, k0 + sc, Kvalid,
                &BsH[sr][sc], &BsL[sr][sc]);
        __syncthreads();

        bf16x8 fah[4], fal[4], fbh[4], fbl[4];
        #pragma unroll
        for (int i = 0; i < 4; i++) {
            fah[i] = *(const bf16x8*)&AsH[wm + i * 16 + lr][quad * 8];
            fal[i] = *(const bf16x8*)&AsL[wm + i * 16 + lr][quad * 8];
            fbh[i] = *(const bf16x8*)&BsH[wn + i * 16 + lr][quad * 8];
            fbl[i] = *(const bf16x8*)&BsL[wn + i * 16 + lr][quad * 8];
        }
        #pragma unroll
        for (int i = 0; i < 4; i++)
            #pragma unroll
            for (int j = 0; j < 4; j++) {
                acc[i][j] = __builtin_amdgcn_mfma_f32_16x16x32_bf16(fah[i], fbh[j], acc[i][j], 0, 0, 0);
                acc[i][j] = __builtin_amdgcn_mfma_f32_16x16x32_bf16(fah[i], fbl[j], acc[i][j], 0, 0, 0);
                acc[i][j] = __builtin_amdgcn_mfma_f32_16x16x32_bf16(fal[i], fbh[j], acc[i][j], 0, 0, 0);
            }
        __syncthreads();
    }

    #pragma unroll
    for (int i = 0; i < 4; i++) {
        #pragma unroll
        for (int j = 0; j < 4; j++) {
            const int gn = bn + wn + j * 16 + lr;
            if (gn >= N) continue;
            #pragma unroll
            for (int r = 0; r < 4; r++) {
                const int gm = wm + i * 16 + quad * 4 + r;
                float v = acc[i][j][r];
                if (flags & F_ACCUM) v += C[(long long)gm * ldc + gn];
                if (flags & F_RELU)  v = fmaxf(v, 0.f);
                C[(long long)gm * ldc + gn] = v;
                if (PT) PT[(long long)gn * 128 + gm] = v;
            }
        }
    }
}

// weight [K][N] fp32 -> transposed hi/lo bf16 [N][Kp], zero-padded k in [K,Kp)
__global__ void convert_wt_kernel(const float* __restrict__ src, int K, int N,
                                  u16* __restrict__ H, u16* __restrict__ L, int Kp)
{
    const int n = blockIdx.y;
    const int k = blockIdx.x * 256 + threadIdx.x;
    if (k >= Kp) return;
    const float v = (k < K) ? src[(long long)k * N + n] : 0.f;
    const u16 h = f2bf(v);
    const long long di = (long long)n * Kp + k;
    H[di] = h;
    L[di] = f2bf(v - bf2f(h));
}

// sizes[side*256 + b] = count_nonzero(x_side[b, :])
__global__ void sizes_kernel(const int* __restrict__ x1, const int* __restrict__ x2,
                             int* __restrict__ sizes)
{
    const int b = blockIdx.x;
    const int side = blockIdx.y;
    const int* x = (side ? x2 : x1) + b * SEQ;
    const int nz = (x[threadIdx.x] != 0) ? 1 : 0;
    const unsigned long long bal = __ballot(nz);
    __shared__ int part[2];
    if ((threadIdx.x & 63) == 0) part[threadIdx.x >> 6] = __popcll(bal);
    __syncthreads();
    if (threadIdx.x == 0) sizes[side * BATCH + b] = part[0] + part[1];
}

// out[t, 0:300] = emb[x[t], :] / ||emb[x[t], :]||_2  (row stride ld)
__global__ void gather_norm_kernel(const int* __restrict__ x, const float* __restrict__ emb,
                                   float* __restrict__ out, int ld)
{
    const int t = blockIdx.x;
    const int lane = threadIdx.x;
    const int tok = x[t];
    const float* row = emb + (long long)tok * EDIM;
    float v[5];
    float ss = 0.f;
    #pragma unroll
    for (int i = 0; i < 5; i++) {
        const int c = lane + i * 64;
        const float f = (c < EDIM) ? row[c] : 0.f;
        v[i] = f;
        ss += f * f;
    }
    #pragma unroll
    for (int o = 32; o > 0; o >>= 1) ss += __shfl_xor(ss, o);
    const float inv = rsqrtf(fmaxf(ss, 1e-12f));
    float* orow = out + (long long)t * ld;
    #pragma unroll
    for (int i = 0; i < 5; i++) {
        const int c = lane + i * 64;
        if (c < EDIM) orow[c] = v[i] * inv;
    }
}

// Row softmax over last dim (len 128), optional distance bias (|i-j| >= 10).
__global__ void softmax_row_kernel(float* __restrict__ att, const float* __restrict__ bias_ptr,
                                   int use_bias)
{
    const int row = blockIdx.x;
    const int i = row & (SEQ - 1);
    const int lane = threadIdx.x;
    float* p = att + (long long)row * SEQ;
    float b0 = 0.f, b1 = 0.f;
    if (use_bias) {
        const float bias = bias_ptr[0];
        int d0 = i - lane;        d0 = d0 < 0 ? -d0 : d0;
        int d1 = i - (lane + 64); d1 = d1 < 0 ? -d1 : d1;
        b0 = (d0 >= 10) ? bias : 0.f;
        b1 = (d1 >= 10) ? bias : 0.f;
    }
    const float v0 = p[lane] + b0;
    const float v1 = p[lane + 64] + b1;
    float m = fmaxf(v0, v1);
    #pragma unroll
    for (int o = 32; o > 0; o >>= 1) m = fmaxf(m, __shfl_xor(m, o));
    const float e0 = __expf(v0 - m);
    const float e1 = __expf(v1 - m);
    float s = e0 + e1;
    #pragma unroll
    for (int o = 32; o > 0; o >>= 1) s += __shfl_xor(s, o);
    const float inv = 1.f / s;
    p[lane] = e0 * inv;
    p[lane + 64] = e1 * inv;
}

// Column softmax of sim (axis=1), written TRANSPOSED: smt[b,j,i]
__global__ void softmax_col_kernel(const float* __restrict__ sim, float* __restrict__ smt)
{
    const int cid = blockIdx.x;
    const int b = cid >> 7;
    const int j = cid & 127;
    const int lane = threadIdx.x;
    const float* p = sim + (long long)b * (SEQ * SEQ) + j;
    const float v0 = p[lane * SEQ];
    const float v1 = p[(lane + 64) * SEQ];
    float m = fmaxf(v0, v1);
    #pragma unroll
    for (int o = 32; o > 0; o >>= 1) m = fmaxf(m, __shfl_xor(m, o));
    const float e0 = __expf(v0 - m);
    const float e1 = __expf(v1 - m);
    float s = e0 + e1;
    #pragma unroll
    for (int o = 32; o > 0; o >>= 1) s += __shfl_xor(s, o);
    const float inv = 1.f / s;
    float* q = smt + (long long)b * (SEQ * SEQ) + (long long)j * SEQ;
    q[lane] = e0 * inv;
    q[lane + 64] = e1 * inv;
}

// Multiplicative mask: sim[b,i,j] = 0 where i >= size1[b] or j >= size2[b]
__global__ void mask_sim_kernel(float* __restrict__ sim, const int* __restrict__ sizes)
{
    const int idx = blockIdx.x * 256 + threadIdx.x;
    const int b = idx >> 14;
    const int i = (idx >> 7) & 127;
    const int j = idx & 127;
    if (i >= sizes[b] || j >= sizes[BATCH + b]) sim[idx] = 0.f;
}

// out[b,n] = sum_{s < sizes[b]} v[b,s,n], n in [0,400)
__global__ void pool_kernel(const float* __restrict__ v, const int* __restrict__ sizes,
                            float* __restrict__ out)
{
    const int b = blockIdx.x;
    const int sz = sizes[b];
    const float* p = v + (long long)b * SEQ * 400;
    for (int n = threadIdx.x; n < 400; n += blockDim.x) {
        float acc = 0.f;
        for (int s = 0; s < sz; s++) acc += p[s * 400 + n];
        out[b * 400 + n] = acc;
    }
}

// y[b,c] = relu(sum_k concat(v1s,v2s)[b,k] * w_agg[k,c]), K=800, C=3
__global__ void agg_kernel(const float* __restrict__ v1s, const float* __restrict__ v2s,
                           const float* __restrict__ w_agg, float* __restrict__ y)
{
    const int b = blockIdx.x;
    const int lane = threadIdx.x;
    float a0 = 0.f, a1 = 0.f, a2 = 0.f;
    for (int k = lane; k < 800; k += 64) {
        const float v = (k < 400) ? v1s[b * 400 + k] : v2s[b * 400 + k - 400];
        a0 = fmaf(v, w_agg[k * 3 + 0], a0);
        a1 = fmaf(v, w_agg[k * 3 + 1], a1);
        a2 = fmaf(v, w_agg[k * 3 + 2], a2);
    }
    #pragma unroll
    for (int o = 32; o > 0; o >>= 1) {
        a0 += __shfl_xor(a0, o);
        a1 += __shfl_xor(a1, o);
        a2 += __shfl_xor(a2, o);
    }
    if (lane == 0) {
        y[b * 3 + 0] = fmaxf(a0, 0.f);
        y[b * 3 + 1] = fmaxf(a1, 0.f);
        y[b * 3 + 2] = fmaxf(a2, 0.f);
    }
}

static inline void launch_flat(hipStream_t st, const float* A, const u16* Bh, const u16* Bl,
                               float* C, float* CT, int M, int N, int Kp,
                               int lda, int ldb, int ldc, long long sCT, int flags)
{
    dim3 grid((N + 127) / 128, M / 128);
    gemm_mfma_af32<<<grid, 256, 0, st>>>(A, Bh, Bl, C, CT, M, N, Kp, lda, ldb, ldc, sCT, flags);
}

static inline void launch_bat(hipStream_t st, const float* A, const float* B,
                              float* C, float* PT, int N, int Kvalid, int Kp,
                              int lda, int ldb, int ldc,
                              long long sA, long long sB, long long sC, long long sPT,
                              int flags)
{
    dim3 grid((N + 127) / 128, 1, BATCH);
    gemm_mfma_bat<<<grid, 256, 0, st>>>(A, B, C, PT, N, Kvalid, Kp, lda, ldb, ldc,
                                        sA, sB, sC, sPT, flags);
}

extern "C" void kernel_launch(void* const* d_in, const int* in_sizes, int n_in,
                              void* d_out, int out_size, void* d_ws, size_t ws_size,
                              hipStream_t stream)
{
    (void)in_sizes; (void)n_in; (void)out_size; (void)ws_size;
    const int*   x1         = (const int*)d_in[0];
    const int*   x2         = (const int*)d_in[1];
    const float* emb        = (const float*)d_in[2];
    const float* w_intra    = (const float*)d_in[3];
    const float* bias_intra = (const float*)d_in[4];
    const float* w_proj1    = (const float*)d_in[5];
    const float* w_proj2    = (const float*)d_in[6];
    const float* w_att      = (const float*)d_in[7];
    const float* w_cmp1     = (const float*)d_in[8];
    const float* w_cmp2     = (const float*)d_in[9];
    const float* w_agg      = (const float*)d_in[10];
    float* y  = (float*)d_out;
    float* ws = (float*)d_ws;

    // ---- workspace layout (floats); total 57,558,016 fl = 230.2 MB ----
    float* X1CAT = ws;                        // [32768,400]: x1p | beta
    float* X2CAT = X1CAT + 13107200;          // [32768,400]: x2p | alpha (FBUF alias)
    float* FBUF  = X2CAT;                     //   phase-A alias: intra f [32768,300]
    float* EF    = X2CAT + 13107200;          // 13,107,200 fl multi-use region
    float* E     = EF;                        //   phase A: e [32768,320]
    float* F1    = EF;                        //   phase B: f1 [32768,200]
    float* F2    = EF + 6553600;              //   phase B: f2 [32768,200]
    float* SMT   = EF;                        //   phase B (post-sim): smt [256,128,128]
    float* V     = EF;                        //   phase C: compare out [32768,400]
    float* T1    = EF + 13107200;             // [256,200,128]: side-0 GT -> x1p^T
    float* T2    = T1 + 6553600;              // [256,200,128]: side-1 GT -> x2p^T
    float* ATT   = T2 + 6553600;              // [256,128,128]: att / sim
    float* V1S   = ATT + 4194304;             // [256,400]
    float* V2S   = V1S + 102400;              // [256,400]
    int*   SIZES = (int*)(V2S + 102400);      // [2,256] + pad to 512 ints
    u16*   WIH   = (u16*)(V2S + 102400 + 512); // w_intra^T [300][320]
    u16*   WIL   = WIH + 96000;
    u16*   WPA1H = WIL + 96000;               // w_proj1[0:300]^T  [200][320]
    u16*   WPA1L = WPA1H + 64000;
    u16*   WPB1H = WPA1L + 64000;             // w_proj1[300:600]^T [200][320]
    u16*   WPB1L = WPB1H + 64000;
    u16*   WPA2H = WPB1L + 64000;
    u16*   WPA2L = WPA2H + 64000;
    u16*   WPB2H = WPA2L + 64000;
    u16*   WPB2L = WPB2H + 64000;
    u16*   WAH   = WPB2L + 64000;             // w_att^T  [200][224]
    u16*   WAL   = WAH + 44800;
    u16*   WC1H  = WAL + 44800;               // w_cmp1^T [400][416]
    u16*   WC1L  = WC1H + 166400;
    u16*   WC2H  = WC1L + 166400;
    u16*   WC2L  = WC2H + 166400;

    const long long sbSS = (long long)SEQ * SEQ;     // 16384
    const long long sbF  = (long long)SEQ * EDIM;    // 38400
    const long long sbP  = (long long)SEQ * PDIM;    // 25600
    const long long sbC  = (long long)SEQ * 400;     // 51200
    const long long sbT  = (long long)PDIM * SEQ;    // 25600

    sizes_kernel<<<dim3(BATCH, 2), 128, 0, stream>>>(x1, x2, SIZES);

    convert_wt_kernel<<<dim3(2, 300), 256, 0, stream>>>(w_intra, 300, 300, WIH, WIL, 320);
    convert_wt_kernel<<<dim3(2, 200), 256, 0, stream>>>(w_proj1, 300, 200, WPA1H, WPA1L, 320);
    convert_wt_kernel<<<dim3(2, 200), 256, 0, stream>>>(w_proj1 + 300 * 200, 300, 200, WPB1H, WPB1L, 320);
    convert_wt_kernel<<<dim3(2, 200), 256, 0, stream>>>(w_proj2, 300, 200, WPA2H, WPA2L, 320);
    convert_wt_kernel<<<dim3(2, 200), 256, 0, stream>>>(w_proj2 + 300 * 200, 300, 200, WPB2H, WPB2L, 320);
    convert_wt_kernel<<<dim3(1, 200), 256, 0, stream>>>(w_att,  200, 200, WAH,  WAL,  224);
    convert_wt_kernel<<<dim3(2, 400), 256, 0, stream>>>(w_cmp1, 400, 400, WC1H, WC1L, 416);
    convert_wt_kernel<<<dim3(2, 400), 256, 0, stream>>>(w_cmp2, 400, 400, WC2H, WC2L, 416);

    // -------- phase A: per-side intra attention + projection --------
    for (int side = 0; side < 2; side++) {
        const int* x = side ? x2 : x1;
        float* XCAT  = side ? X2CAT : X1CAT;
        float* T     = side ? T2 : T1;
        u16* WPAH = side ? WPA2H : WPA1H;  u16* WPAL = side ? WPA2L : WPA1L;
        u16* WPBH = side ? WPB2H : WPB1H;  u16* WPBL = side ? WPB2L : WPB1L;

        // e -> E [32768,320] cols 0:300 (pad cols: poison, killed by masks/zero-weights)
        gather_norm_kernel<<<BSTOK, 64, 0, stream>>>(x, emb, E, 320);
        // f = relu(e @ w_intra)  [flat MFMA]
        launch_flat(stream, E, WIH, WIL, FBUF, nullptr, BSTOK, EDIM, 320, 320, 320, EDIM, 0, F_RELU);
        // att[b] = f[b] f[b]^T  [batched MFMA, K=300 masked, A==B]
        launch_bat(stream, FBUF, FBUF, ATT, nullptr, SEQ, EDIM, 320, EDIM, EDIM, SEQ,
                   sbF, sbF, sbSS, 0, 0);
        softmax_row_kernel<<<BSTOK, 64, 0, stream>>>(ATT, bias_intra, 1);
        // GT[b] = (e @ wp_b)^T  [flat MFMA, transposed-only store]
        launch_flat(stream, E, WPBH, WPBL, nullptr, T, BSTOK, PDIM, 320, 320, 320, 0, sbT, 0);
        // XCAT[:,0:200] = e @ wp_a  (no relu yet)
        launch_flat(stream, E, WPAH, WPAL, XCAT, nullptr, BSTOK, PDIM, 320, 320, 320, 400, 0, 0);
        // XCAT[:,0:200] = relu(XCAT + sm @ G); also emit x_proj^T in-place over GT
        launch_bat(stream, ATT, T, XCAT, T, PDIM, SEQ, SEQ, SEQ, SEQ, 400,
                   sbSS, sbT, sbC, sbT, F_ACCUM | F_RELU);
    }

    // -------- phase B: cross attention --------
    float* SIM = ATT;

    // f1/f2 = relu(x_proj @ w_att)  [flat MFMA; A cols 200:224 garbage * 0]
    launch_flat(stream, X1CAT, WAH, WAL, F1, nullptr, BSTOK, PDIM, 224, 400, 224, PDIM, 0, F_RELU);
    launch_flat(stream, X2CAT, WAH, WAL, F2, nullptr, BSTOK, PDIM, 224, 400, 224, PDIM, 0, F_RELU);
    // sim[b] = f1[b] f2[b]^T  [batched MFMA, K=200 masked]
    launch_bat(stream, F1, F2, SIM, nullptr, SEQ, PDIM, 224, PDIM, PDIM, SEQ,
               sbP, sbP, sbSS, 0, 0);
    mask_sim_kernel<<<(BATCH * SEQ * SEQ) / 256, 256, 0, stream>>>(SIM, SIZES);
    softmax_col_kernel<<<BSTOK, 64, 0, stream>>>(SIM, SMT);   // SMT overlays F1 (dead)
    softmax_row_kernel<<<BSTOK, 64, 0, stream>>>(SIM, bias_intra, 0);
    // beta  = rowsm(sim) @ x2p  -> X1CAT cols 200:400   [B = x2p^T = T2]
    launch_bat(stream, SIM, T2, X1CAT + 200, nullptr, PDIM, SEQ, SEQ, SEQ, SEQ, 400,
               sbSS, sbT, sbC, 0, 0);
    // alpha = colsm(sim)^T @ x1p -> X2CAT cols 200:400  [A = SMT, B = x1p^T = T1]
    launch_bat(stream, SMT, T1, X2CAT + 200, nullptr, PDIM, SEQ, SEQ, SEQ, SEQ, 400,
               sbSS, sbT, sbC, 0, 0);

    // -------- phase C: compare + pool + aggregate --------
    // v = relu([xp|beta] @ w_cmp)  [flat MFMA; Kp=416: k-pad wraps, finite * 0]
    launch_flat(stream, X1CAT, WC1H, WC1L, V, nullptr, BSTOK, 400, 416, 400, 416, 400, 0, F_RELU);
    pool_kernel<<<BATCH, 256, 0, stream>>>(V, SIZES, V1S);
    launch_flat(stream, X2CAT, WC2H, WC2L, V, nullptr, BSTOK, 400, 416, 400, 416, 400, 0, F_RELU);
    pool_kernel<<<BATCH, 256, 0, stream>>>(V, SIZES + BATCH, V2S);

    agg_kernel<<<BATCH, 64, 0, stream>>>(V1S, V2S, w_agg, y);
}

// Round 6
// 795.556 us; speedup vs baseline: 2.2972x; 1.1733x over previous
//
#include <hip/hip_runtime.h>

#define BATCH 256
#define SEQ   128
#define EDIM  300
#define PDIM  200
#define BSTOK (BATCH * SEQ)

#define F_RELU  1
#define F_ACCUM 2

typedef unsigned short u16;
typedef __attribute__((ext_vector_type(8))) short bf16x8;
typedef __attribute__((ext_vector_type(4))) float f32x4;

__device__ __forceinline__ u16 f2bf(float x) {
    unsigned u = __float_as_uint(x);
    unsigned r = u + 0x7fffu + ((u >> 16) & 1u);
    return (u16)(r >> 16);
}
__device__ __forceinline__ float bf2f(u16 h) {
    return __uint_as_float(((unsigned)h) << 16);
}

// Load 16 fp32 (0 if !row_ok), zero k >= Kvalid, split hi(trunc)/lo(residual)
// bf16, write 2 x uint4 each. 256 thr x 16 elem = full 128x32 tile.
__device__ __forceinline__ void stage16(const float* __restrict__ src, bool row_ok,
                                        int kbase, int Kvalid, u16* dH, u16* dL)
{
    float va[16];
    if (row_ok) {
        #pragma unroll
        for (int i = 0; i < 4; i++) {
            const float4 v = *(const float4*)(src + i * 4);
            va[i * 4 + 0] = v.x; va[i * 4 + 1] = v.y;
            va[i * 4 + 2] = v.z; va[i * 4 + 3] = v.w;
        }
        #pragma unroll
        for (int i = 0; i < 16; i++)
            va[i] = (kbase + i < Kvalid) ? va[i] : 0.f;
    } else {
        #pragma unroll
        for (int i = 0; i < 16; i++) va[i] = 0.f;
    }
    unsigned hp[8], lp[8];
    #pragma unroll
    for (int i = 0; i < 8; i++) {
        const unsigned u0 = __float_as_uint(va[2 * i]);
        const unsigned u1 = __float_as_uint(va[2 * i + 1]);
        const unsigned h0 = u0 & 0xffff0000u;
        const unsigned h1 = u1 & 0xffff0000u;
        hp[i] = (u0 >> 16) | h1;
        const float r0 = va[2 * i]     - __uint_as_float(h0);
        const float r1 = va[2 * i + 1] - __uint_as_float(h1);
        lp[i] = (__float_as_uint(r0) >> 16) | (__float_as_uint(r1) & 0xffff0000u);
    }
    ((uint4*)dH)[0] = make_uint4(hp[0], hp[1], hp[2], hp[3]);
    ((uint4*)dH)[1] = make_uint4(hp[4], hp[5], hp[6], hp[7]);
    ((uint4*)dL)[0] = make_uint4(lp[0], lp[1], lp[2], lp[3]);
    ((uint4*)dL)[1] = make_uint4(lp[4], lp[5], lp[6], lp[7]);
}

// ---------------------------------------------------------------------------
// Flat split-bf16 MFMA GEMM vs pre-split transposed weights.
// Weight select per m-tile: bm >= Msplit -> (Bh2,Bl2).
// Outputs (all optional): C row-major; CT batch-transposed
// CT[gm>>7][gn][gm&127] (stride sCT); PO fused masked row-sum pool
// PO[bm>>7][gn] with rows masked to sizes[bm>>7] (tile == one batch).
// ---------------------------------------------------------------------------
__global__ __launch_bounds__(256) void gemm_flat(
    const float* __restrict__ A,
    const u16* __restrict__ Bh, const u16* __restrict__ Bl,
    const u16* __restrict__ Bh2, const u16* __restrict__ Bl2, int Msplit,
    float* __restrict__ C, float* __restrict__ CT, float* __restrict__ PO,
    const int* __restrict__ sizes,
    int M, int N, int Kp, int lda, int ldb, int ldc, long long sCT, int flags)
{
    __shared__ u16 AsH[128][40];
    __shared__ u16 AsL[128][40];
    __shared__ u16 BsH[128][40];
    __shared__ u16 BsL[128][40];

    const int tid  = threadIdx.x;
    const int bm   = blockIdx.y * 128;
    const int bn   = blockIdx.x * 128;
    const int wave = tid >> 6;
    const int lane = tid & 63;
    const int wm   = (wave >> 1) * 64;
    const int wn   = (wave & 1) * 64;
    const int lr   = lane & 15;
    const int quad = lane >> 4;

    if (bm >= Msplit) { Bh = Bh2; Bl = Bl2; }

    const int sr = tid >> 1;
    const int sc = (tid & 1) * 16;

    f32x4 acc[4][4];
    #pragma unroll
    for (int i = 0; i < 4; i++)
        #pragma unroll
        for (int j = 0; j < 4; j++)
            acc[i][j] = (f32x4)(0.0f);

    for (int k0 = 0; k0 < Kp; k0 += 32) {
        stage16(A + (long long)(bm + sr) * lda + k0 + sc, true, 0, 1 << 30,
                &AsH[sr][sc], &AsL[sr][sc]);
        {
            uint4 wh0 = make_uint4(0,0,0,0), wh1 = make_uint4(0,0,0,0);
            uint4 wl0 = make_uint4(0,0,0,0), wl1 = make_uint4(0,0,0,0);
            const int gn = bn + sr;
            if (gn < N) {
                const long long br = (long long)gn * ldb + k0 + sc;
                wh0 = *(const uint4*)(Bh + br);
                wh1 = *(const uint4*)(Bh + br + 8);
                wl0 = *(const uint4*)(Bl + br);
                wl1 = *(const uint4*)(Bl + br + 8);
            }
            *(uint4*)&BsH[sr][sc]     = wh0;
            *(uint4*)&BsH[sr][sc + 8] = wh1;
            *(uint4*)&BsL[sr][sc]     = wl0;
            *(uint4*)&BsL[sr][sc + 8] = wl1;
        }
        __syncthreads();

        bf16x8 fah[4], fal[4], fbh[4], fbl[4];
        #pragma unroll
        for (int i = 0; i < 4; i++) {
            fah[i] = *(const bf16x8*)&AsH[wm + i * 16 + lr][quad * 8];
            fal[i] = *(const bf16x8*)&AsL[wm + i * 16 + lr][quad * 8];
            fbh[i] = *(const bf16x8*)&BsH[wn + i * 16 + lr][quad * 8];
            fbl[i] = *(const bf16x8*)&BsL[wn + i * 16 + lr][quad * 8];
        }
        #pragma unroll
        for (int i = 0; i < 4; i++)
            #pragma unroll
            for (int j = 0; j < 4; j++) {
                acc[i][j] = __builtin_amdgcn_mfma_f32_16x16x32_bf16(fah[i], fbh[j], acc[i][j], 0, 0, 0);
                acc[i][j] = __builtin_amdgcn_mfma_f32_16x16x32_bf16(fah[i], fbl[j], acc[i][j], 0, 0, 0);
                acc[i][j] = __builtin_amdgcn_mfma_f32_16x16x32_bf16(fal[i], fbh[j], acc[i][j], 0, 0, 0);
            }
        __syncthreads();
    }

    // C/D: col = lane&15, row = quad*4 + r
    const int sz = PO ? sizes[bm >> 7] : 0;
    float ps[4] = {0.f, 0.f, 0.f, 0.f};
    #pragma unroll
    for (int j = 0; j < 4; j++) {
        const int gn = bn + wn + j * 16 + lr;
        const bool gok = gn < N;
        #pragma unroll
        for (int i = 0; i < 4; i++) {
            #pragma unroll
            for (int r = 0; r < 4; r++) {
                const int row = wm + i * 16 + quad * 4 + r;
                const int gm = bm + row;
                float v = acc[i][j][r];
                if (flags & F_RELU) v = fmaxf(v, 0.f);
                if (gok) {
                    if (C)  C[(long long)gm * ldc + gn] = v;
                    if (CT) CT[(long long)(gm >> 7) * sCT + (long long)gn * 128 + (gm & 127)] = v;
                }
                if (PO && row < sz) ps[j] += v;
            }
        }
    }
    if (PO) {
        // reduce across quads (lane bits 4,5), then across wm-wave-pairs via LDS
        #pragma unroll
        for (int j = 0; j < 4; j++) {
            ps[j] += __shfl_xor(ps[j], 16);
            ps[j] += __shfl_xor(ps[j], 32);
        }
        float* PS = (float*)AsH;   // staging LDS free after K-loop's final barrier
        if (wm == 0 && quad == 0) {
            #pragma unroll
            for (int j = 0; j < 4; j++) PS[wn + j * 16 + lr] = ps[j];
        }
        __syncthreads();
        if (wm == 64 && quad == 0) {
            #pragma unroll
            for (int j = 0; j < 4; j++) PS[wn + j * 16 + lr] += ps[j];
        }
        __syncthreads();
        if (tid < 128) {
            const int gn = bn + tid;
            if (gn < N) PO[(long long)(bm >> 7) * N + gn] = PS[tid];
        }
    }
}

// ---------------------------------------------------------------------------
// Batched split-bf16 MFMA GEMM, NT, both operands fp32->hi/lo in staging.
// MODE 0: plain (flags ACCUM/RELU; optional sizes mask [sim]; optional PT
//         transposed store (may alias B: block writes only rows it read)).
//         Optional (Aalt,Balt): batches bz>=256 use alt bases with bz-256.
// MODE 1: att — add dist-bias (|i-j|>=10), fused row softmax -> C (probs).
// grid: x = ceil(N/128), z = batch.
// ---------------------------------------------------------------------------
template <int MODE>
__global__ __launch_bounds__(256) void gemm_bat(
    const float* __restrict__ A, const float* __restrict__ Aalt,
    const float* __restrict__ B, const float* __restrict__ Balt,
    float* __restrict__ C, float* __restrict__ PT,
    int N, int Kvalid, int Kp, int lda, int ldb, int ldc,
    long long sA, long long sB, long long sC, long long sPT,
    int flags, const float* __restrict__ bias_ptr, const int* __restrict__ sizes,
    int same_ab)
{
    constexpr int SB = (MODE == 1) ? 65536 : 40960;
    __shared__ __align__(16) unsigned char smem[SB];
    u16 (*AsH)[40] = (u16(*)[40])(smem);
    u16 (*AsL)[40] = (u16(*)[40])(smem + 10240);
    u16 (*BsH)[40] = (u16(*)[40])(smem + 20480);
    u16 (*BsL)[40] = (u16(*)[40])(smem + 30720);

    const int bz = blockIdx.z;
    long long zb = bz;
    const float* Ause = A;
    const float* Buse = B;
    if (Aalt && bz >= BATCH) { Ause = Aalt; Buse = Balt; zb = bz - BATCH; }
    Ause += zb * sA;
    Buse += zb * sB;
    C += (long long)bz * sC;
    if (PT) PT += (long long)bz * sPT;

    const int tid  = threadIdx.x;
    const int bn   = blockIdx.x * 128;
    const int wave = tid >> 6;
    const int lane = tid & 63;
    const int wm   = (wave >> 1) * 64;
    const int wn   = (wave & 1) * 64;
    const int lr   = lane & 15;
    const int quad = lane >> 4;

    const int sr = tid >> 1;
    const int sc = (tid & 1) * 16;

    f32x4 acc[4][4];
    #pragma unroll
    for (int i = 0; i < 4; i++)
        #pragma unroll
        for (int j = 0; j < 4; j++)
            acc[i][j] = (f32x4)(0.0f);

    u16 (*fbH)[40] = same_ab ? AsH : BsH;
    u16 (*fbL)[40] = same_ab ? AsL : BsL;

    for (int k0 = 0; k0 < Kp; k0 += 32) {
        stage16(Ause + (long long)sr * lda + k0 + sc, true, k0 + sc, Kvalid,
                &AsH[sr][sc], &AsL[sr][sc]);
        if (!same_ab) {
            const int gn = bn + sr;
            stage16(Buse + (long long)gn * ldb + k0 + sc, gn < N, k0 + sc, Kvalid,
                    &BsH[sr][sc], &BsL[sr][sc]);
        }
        __syncthreads();

        bf16x8 fah[4], fal[4], fbh[4], fbl[4];
        #pragma unroll
        for (int i = 0; i < 4; i++) {
            fah[i] = *(const bf16x8*)&AsH[wm + i * 16 + lr][quad * 8];
            fal[i] = *(const bf16x8*)&AsL[wm + i * 16 + lr][quad * 8];
            fbh[i] = *(const bf16x8*)&fbH[wn + i * 16 + lr][quad * 8];
            fbl[i] = *(const bf16x8*)&fbL[wn + i * 16 + lr][quad * 8];
        }
        #pragma unroll
        for (int i = 0; i < 4; i++)
            #pragma unroll
            for (int j = 0; j < 4; j++) {
                acc[i][j] = __builtin_amdgcn_mfma_f32_16x16x32_bf16(fah[i], fbh[j], acc[i][j], 0, 0, 0);
                acc[i][j] = __builtin_amdgcn_mfma_f32_16x16x32_bf16(fah[i], fbl[j], acc[i][j], 0, 0, 0);
                acc[i][j] = __builtin_amdgcn_mfma_f32_16x16x32_bf16(fal[i], fbh[j], acc[i][j], 0, 0, 0);
            }
        __syncthreads();
    }

    if (MODE == 1) {
        // att: add distance bias, stage tile to LDS, fused row softmax -> C
        float* S = (float*)smem;   // 128x128 f32 = 64 KB (staging dead)
        const float bias = bias_ptr[0];
        #pragma unroll
        for (int i = 0; i < 4; i++) {
            #pragma unroll
            for (int j = 0; j < 4; j++) {
                const int col = wn + j * 16 + lr;
                #pragma unroll
                for (int r = 0; r < 4; r++) {
                    const int row = wm + i * 16 + quad * 4 + r;
                    int d = row - col; d = d < 0 ? -d : d;
                    S[row * 128 + col] = acc[i][j][r] + ((d >= 10) ? bias : 0.f);
                }
            }
        }
        __syncthreads();
        const int row = tid >> 1;
        const int half = (tid & 1) * 64;
        float mx = -1e30f;
        for (int c = 0; c < 64; c++) mx = fmaxf(mx, S[row * 128 + half + c]);
        mx = fmaxf(mx, __shfl_xor(mx, 1));
        float sum = 0.f;
        for (int c = 0; c < 64; c++) sum += __expf(S[row * 128 + half + c] - mx);
        sum += __shfl_xor(sum, 1);
        const float inv = 1.f / sum;
        for (int c = 0; c < 64; c++)
            C[(long long)row * ldc + half + c] = __expf(S[row * 128 + half + c] - mx) * inv;
    } else {
        const int s1 = sizes ? sizes[bz] : SEQ;
        const int s2 = sizes ? sizes[BATCH + bz] : SEQ;
        #pragma unroll
        for (int i = 0; i < 4; i++) {
            #pragma unroll
            for (int j = 0; j < 4; j++) {
                const int gn = bn + wn + j * 16 + lr;
                if (gn >= N) continue;
                #pragma unroll
                for (int r = 0; r < 4; r++) {
                    const int gm = wm + i * 16 + quad * 4 + r;
                    float v = acc[i][j][r];
                    if (sizes && (gm >= s1 || gn >= s2)) v = 0.f;
                    if (flags & F_ACCUM) v += C[(long long)gm * ldc + gn];
                    if (flags & F_RELU)  v = fmaxf(v, 0.f);
                    C[(long long)gm * ldc + gn] = v;
                    if (PT) PT[(long long)gn * 128 + gm] = v;
                }
            }
        }
    }
}

// One block per batch: load masked sim[b] (128x128) to LDS, then
// row softmax (axis 2) in-place to sim, col softmax (axis 1) transposed to smt.
__global__ __launch_bounds__(256) void softmax_both(float* __restrict__ sim,
                                                    float* __restrict__ smt)
{
    __shared__ float S[128 * 128];
    const int b = blockIdx.x;
    const int tid = threadIdx.x;
    float* sp = sim + (long long)b * (SEQ * SEQ);
    float* qp = smt + (long long)b * (SEQ * SEQ);
    #pragma unroll
    for (int it = 0; it < 16; it++) {
        const int i4 = it * 256 + tid;
        ((float4*)S)[i4] = ((const float4*)sp)[i4];
    }
    __syncthreads();
    const int idx = tid >> 1;
    const int half = (tid & 1) * 64;
    // row softmax -> sim
    {
        float mx = -1e30f;
        for (int c = 0; c < 64; c++) mx = fmaxf(mx, S[idx * 128 + half + c]);
        mx = fmaxf(mx, __shfl_xor(mx, 1));
        float sum = 0.f;
        for (int c = 0; c < 64; c++) sum += __expf(S[idx * 128 + half + c] - mx);
        sum += __shfl_xor(sum, 1);
        const float inv = 1.f / sum;
        for (int c = 0; c < 64; c++)
            sp[idx * 128 + half + c] = __expf(S[idx * 128 + half + c] - mx) * inv;
    }
    // col softmax -> smt transposed (smt[j][i] = softmax_i(sim[i][j]))
    {
        float mx = -1e30f;
        for (int r = 0; r < 64; r++) mx = fmaxf(mx, S[(half + r) * 128 + idx]);
        mx = fmaxf(mx, __shfl_xor(mx, 1));
        float sum = 0.f;
        for (int r = 0; r < 64; r++) sum += __expf(S[(half + r) * 128 + idx] - mx);
        sum += __shfl_xor(sum, 1);
        const float inv = 1.f / sum;
        for (int r = 0; r < 64; r++)
            qp[idx * 128 + half + r] = __expf(S[(half + r) * 128 + idx] - mx) * inv;
    }
}

// All weight transposes + hi/lo splits in one launch.
struct WEnt { const float* src; u16* H; u16* L; int K, N, Kp, rowStart; };
struct WTab { WEnt e[8]; };
__global__ void convert_all(WTab t)
{
    const int row = blockIdx.y;
    const int k = blockIdx.x * 256 + threadIdx.x;
    #pragma unroll
    for (int s = 0; s < 8; s++) {
        const WEnt w = t.e[s];
        if (row >= w.rowStart && row < w.rowStart + w.N) {
            const int n = row - w.rowStart;
            if (k < w.Kp) {
                const float v = (k < w.K) ? w.src[(long long)k * w.N + n] : 0.f;
                const u16 h = f2bf(v);
                w.H[(long long)n * w.Kp + k] = h;
                w.L[(long long)n * w.Kp + k] = f2bf(v - bf2f(h));
            }
            return;
        }
    }
}

__global__ void sizes_kernel(const int* __restrict__ x1, const int* __restrict__ x2,
                             int* __restrict__ sizes)
{
    const int b = blockIdx.x;
    const int side = blockIdx.y;
    const int* x = (side ? x2 : x1) + b * SEQ;
    const int nz = (x[threadIdx.x] != 0) ? 1 : 0;
    const unsigned long long bal = __ballot(nz);
    __shared__ int part[2];
    if ((threadIdx.x & 63) == 0) part[threadIdx.x >> 6] = __popcll(bal);
    __syncthreads();
    if (threadIdx.x == 0) sizes[side * BATCH + b] = part[0] + part[1];
}

__global__ void gather_norm_kernel(const int* __restrict__ x, const float* __restrict__ emb,
                                   float* __restrict__ out, int ld)
{
    const int t = blockIdx.x;
    const int lane = threadIdx.x;
    const int tok = x[t];
    const float* row = emb + (long long)tok * EDIM;
    float v[5];
    float ss = 0.f;
    #pragma unroll
    for (int i = 0; i < 5; i++) {
        const int c = lane + i * 64;
        const float f = (c < EDIM) ? row[c] : 0.f;
        v[i] = f;
        ss += f * f;
    }
    #pragma unroll
    for (int o = 32; o > 0; o >>= 1) ss += __shfl_xor(ss, o);
    const float inv = rsqrtf(fmaxf(ss, 1e-12f));
    float* orow = out + (long long)t * ld;
    #pragma unroll
    for (int i = 0; i < 5; i++) {
        const int c = lane + i * 64;
        if (c < EDIM) orow[c] = v[i] * inv;
    }
}

// y[b,c] = relu(sum_k concat(v1s,v2s)[b,k] * w_agg[k,c]), K=800, C=3
__global__ void agg_kernel(const float* __restrict__ v1s, const float* __restrict__ v2s,
                           const float* __restrict__ w_agg, float* __restrict__ y)
{
    const int b = blockIdx.x;
    const int lane = threadIdx.x;
    float a0 = 0.f, a1 = 0.f, a2 = 0.f;
    for (int k = lane; k < 800; k += 64) {
        const float v = (k < 400) ? v1s[b * 400 + k] : v2s[b * 400 + k - 400];
        a0 = fmaf(v, w_agg[k * 3 + 0], a0);
        a1 = fmaf(v, w_agg[k * 3 + 1], a1);
        a2 = fmaf(v, w_agg[k * 3 + 2], a2);
    }
    #pragma unroll
    for (int o = 32; o > 0; o >>= 1) {
        a0 += __shfl_xor(a0, o);
        a1 += __shfl_xor(a1, o);
        a2 += __shfl_xor(a2, o);
    }
    if (lane == 0) {
        y[b * 3 + 0] = fmaxf(a0, 0.f);
        y[b * 3 + 1] = fmaxf(a1, 0.f);
        y[b * 3 + 2] = fmaxf(a2, 0.f);
    }
}

static inline void launch_flat(hipStream_t st, const float* A,
                               const u16* Bh, const u16* Bl,
                               const u16* Bh2, const u16* Bl2, int Msplit,
                               float* C, float* CT, float* PO, const int* sizes,
                               int M, int N, int Kp, int lda, int ldb, int ldc,
                               long long sCT, int flags)
{
    dim3 grid((N + 127) / 128, M / 128);
    gemm_flat<<<grid, 256, 0, st>>>(A, Bh, Bl, Bh2, Bl2, Msplit, C, CT, PO, sizes,
                                    M, N, Kp, lda, ldb, ldc, sCT, flags);
}

extern "C" void kernel_launch(void* const* d_in, const int* in_sizes, int n_in,
                              void* d_out, int out_size, void* d_ws, size_t ws_size,
                              hipStream_t stream)
{
    (void)in_sizes; (void)n_in; (void)out_size; (void)ws_size;
    const int*   x1         = (const int*)d_in[0];
    const int*   x2         = (const int*)d_in[1];
    const float* emb        = (const float*)d_in[2];
    const float* w_intra    = (const float*)d_in[3];
    const float* bias_intra = (const float*)d_in[4];
    const float* w_proj1    = (const float*)d_in[5];
    const float* w_proj2    = (const float*)d_in[6];
    const float* w_att      = (const float*)d_in[7];
    const float* w_cmp1     = (const float*)d_in[8];
    const float* w_cmp2     = (const float*)d_in[9];
    const float* w_agg      = (const float*)d_in[10];
    float* y  = (float*)d_out;
    float* ws = (float*)d_ws;

    // ---- workspace (floats); total 57,558,016 fl = 230.2 MB ----
    float* X1CAT = ws;                        // [32768,400]: x1p | beta
    float* X2CAT = X1CAT + 13107200;          // [32768,400]: x2p | alpha
    float* FBUF  = X2CAT;                     //   phase-A alias: intra f [32768,300]
    float* EF    = X2CAT + 13107200;          // 13,107,200 fl multi-use
    float* E     = EF;                        //   phase A: e [32768,320]
    float* F1    = EF;                        //   phase B: f1 [32768,200]
    float* F2    = EF + 6553600;              //   phase B: f2 [32768,200] (contig after F1)
    float* SMT   = EF;                        //   phase B post-sim: [256,128,128]
    float* T     = EF + 13107200;             // [512,200,128]: T1 | T2
    float* T1    = T;
    float* T2    = T + 6553600;
    float* ATT   = T + 13107200;              // [256,128,128]: att probs / sim
    float* POOL  = ATT + 4194304;             // [512,400]: v1s | v2s pooled
    int*   SIZES = (int*)(POOL + 204800);     // [2,256] (+pad to 512)
    u16*   WIH   = (u16*)(SIZES + 512);       // w_intra^T [300][320]
    u16*   WIL   = WIH + 96000;
    u16*   WPA1H = WIL + 96000;               // w_proj1[0:300]^T  [200][320]
    u16*   WPA1L = WPA1H + 64000;
    u16*   WPB1H = WPA1L + 64000;             // w_proj1[300:600]^T [200][320]
    u16*   WPB1L = WPB1H + 64000;
    u16*   WPA2H = WPB1L + 64000;
    u16*   WPA2L = WPA2H + 64000;
    u16*   WPB2H = WPA2L + 64000;
    u16*   WPB2L = WPB2H + 64000;
    u16*   WAH   = WPB2L + 64000;             // w_att^T  [200][224]
    u16*   WAL   = WAH + 44800;
    u16*   WC1H  = WAL + 44800;               // w_cmp1^T [400][416]
    u16*   WC1L  = WC1H + 166400;
    u16*   WC2H  = WC1L + 166400;
    u16*   WC2L  = WC2H + 166400;

    const long long sbSS = (long long)SEQ * SEQ;     // 16384
    const long long sbF  = (long long)SEQ * EDIM;    // 38400
    const long long sbP  = (long long)SEQ * PDIM;    // 25600
    const long long sbC  = (long long)SEQ * 400;     // 51200
    const long long sbT  = (long long)PDIM * SEQ;    // 25600

    sizes_kernel<<<dim3(BATCH, 2), 128, 0, stream>>>(x1, x2, SIZES);

    // all weight converts in one launch (rows: cumulative over 8 segments)
    {
        WTab t;
        t.e[0] = { w_intra,             WIH,   WIL,   300, 300, 320, 0    };
        t.e[1] = { w_proj1,             WPA1H, WPA1L, 300, 200, 320, 300  };
        t.e[2] = { w_proj1 + 300 * 200, WPB1H, WPB1L, 300, 200, 320, 500  };
        t.e[3] = { w_proj2,             WPA2H, WPA2L, 300, 200, 320, 700  };
        t.e[4] = { w_proj2 + 300 * 200, WPB2H, WPB2L, 300, 200, 320, 900  };
        t.e[5] = { w_att,               WAH,   WAL,   200, 200, 224, 1100 };
        t.e[6] = { w_cmp1,              WC1H,  WC1L,  400, 400, 416, 1300 };
        t.e[7] = { w_cmp2,              WC2H,  WC2L,  400, 400, 416, 1700 };
        convert_all<<<dim3(2, 2100), 256, 0, stream>>>(t);
    }

    // -------- phase A: per-side intra attention + projection --------
    for (int side = 0; side < 2; side++) {
        const int* x = side ? x2 : x1;
        float* XCAT  = side ? X2CAT : X1CAT;
        float* Ts    = side ? T2 : T1;
        u16* WPAH = side ? WPA2H : WPA1H;  u16* WPAL = side ? WPA2L : WPA1L;
        u16* WPBH = side ? WPB2H : WPB1H;  u16* WPBL = side ? WPB2L : WPB1L;

        gather_norm_kernel<<<BSTOK, 64, 0, stream>>>(x, emb, E, 320);
        // f = relu(e @ w_intra)
        launch_flat(stream, E, WIH, WIL, WIH, WIL, 1 << 30, FBUF, nullptr, nullptr, nullptr,
                    BSTOK, EDIM, 320, 320, 320, EDIM, 0, F_RELU);
        // att probs = rowsoftmax(f f^T + dbias)   [fused epilogue, A==B symmetric]
        gemm_bat<1><<<dim3(1, 1, BATCH), 256, 0, stream>>>(
            FBUF, nullptr, FBUF, nullptr, ATT, nullptr,
            SEQ, EDIM, 320, EDIM, EDIM, SEQ, sbF, sbF, sbSS, 0,
            0, bias_intra, nullptr, 1);
        // GT[b] = (e @ wp_b)^T
        launch_flat(stream, E, WPBH, WPBL, WPBH, WPBL, 1 << 30, nullptr, Ts, nullptr, nullptr,
                    BSTOK, PDIM, 320, 320, 320, 0, sbT, 0);
        // XCAT[:,0:200] = e @ wp_a (no relu yet)
        launch_flat(stream, E, WPAH, WPAL, WPAH, WPAL, 1 << 30, XCAT, nullptr, nullptr, nullptr,
                    BSTOK, PDIM, 320, 320, 320, 400, 0, 0);
        // XCAT[:,0:200] = relu(XCAT + probs @ G); emit x_proj^T in-place over GT
        gemm_bat<0><<<dim3(2, 1, BATCH), 256, 0, stream>>>(
            ATT, nullptr, Ts, nullptr, XCAT, Ts,
            PDIM, SEQ, SEQ, SEQ, SEQ, 400, sbSS, sbT, sbC, sbT,
            F_ACCUM | F_RELU, nullptr, nullptr, 0);
    }

    // -------- phase B: cross attention --------
    float* SIM = ATT;

    // f1|f2 = relu(x_proj @ w_att)  [merged M=65536; A cols 200:224 garbage*0]
    launch_flat(stream, X1CAT, WAH, WAL, WAH, WAL, 1 << 30, F1, nullptr, nullptr, nullptr,
                2 * BSTOK, PDIM, 224, 400, 224, PDIM, 0, F_RELU);
    // sim[b] = mask(f1 f2^T)  [mask fused via sizes]
    gemm_bat<0><<<dim3(1, 1, BATCH), 256, 0, stream>>>(
        F1, nullptr, F2, nullptr, SIM, nullptr,
        SEQ, PDIM, 224, PDIM, PDIM, SEQ, sbP, sbP, sbSS, 0,
        0, nullptr, SIZES, 0);
    // row softmax in-place + col softmax transposed -> SMT (one pass)
    softmax_both<<<BATCH, 256, 0, stream>>>(SIM, SMT);
    // beta (bz<256): rowsm @ x2p^T -> X1CAT[:,200:400]
    // alpha (bz>=256): colsm^T @ x1p^T -> X2CAT[:,200:400]   [merged 512 batches]
    gemm_bat<0><<<dim3(2, 1, 2 * BATCH), 256, 0, stream>>>(
        SIM, SMT, T2, T1, X1CAT + 200, nullptr,
        PDIM, SEQ, SEQ, SEQ, SEQ, 400, sbSS, sbT, sbC, 0,
        0, nullptr, nullptr, 0);

    // -------- phase C: fused compare + masked pool, then aggregate --------
    launch_flat(stream, X1CAT, WC1H, WC1L, WC2H, WC2L, BSTOK,
                nullptr, nullptr, POOL, SIZES,
                2 * BSTOK, 400, 416, 400, 416, 400, 0, F_RELU);
    agg_kernel<<<BATCH, 64, 0, stream>>>(POOL, POOL + 102400, w_agg, y);
}

// Round 7
// 693.811 us; speedup vs baseline: 2.6341x; 1.1466x over previous
//
#include <hip/hip_runtime.h>

#define BATCH 256
#define SEQ   128
#define EDIM  300
#define PDIM  200
#define BSTOK (BATCH * SEQ)

#define F_RELU  1
#define F_ACCUM 2

typedef unsigned short u16;
typedef __attribute__((ext_vector_type(8))) short bf16x8;
typedef __attribute__((ext_vector_type(4))) float f32x4;

__device__ __forceinline__ u16 f2bf(float x) {
    unsigned u = __float_as_uint(x);
    unsigned r = u + 0x7fffu + ((u >> 16) & 1u);
    return (u16)(r >> 16);
}
__device__ __forceinline__ float bf2f(u16 h) {
    return __uint_as_float(((unsigned)h) << 16);
}

// split 16 fp32 -> hi(trunc)/lo(residual) bf16, store 2 x uint4 each.
__device__ __forceinline__ void split_store(const float* va, u16* dH, u16* dL)
{
    unsigned hp[8], lp[8];
    #pragma unroll
    for (int i = 0; i < 8; i++) {
        const unsigned u0 = __float_as_uint(va[2 * i]);
        const unsigned u1 = __float_as_uint(va[2 * i + 1]);
        const unsigned h0 = u0 & 0xffff0000u;
        const unsigned h1 = u1 & 0xffff0000u;
        hp[i] = (u0 >> 16) | h1;
        const float r0 = va[2 * i]     - __uint_as_float(h0);
        const float r1 = va[2 * i + 1] - __uint_as_float(h1);
        lp[i] = (__float_as_uint(r0) >> 16) | (__float_as_uint(r1) & 0xffff0000u);
    }
    ((uint4*)dH)[0] = make_uint4(hp[0], hp[1], hp[2], hp[3]);
    ((uint4*)dH)[1] = make_uint4(hp[4], hp[5], hp[6], hp[7]);
    ((uint4*)dL)[0] = make_uint4(lp[0], lp[1], lp[2], lp[3]);
    ((uint4*)dL)[1] = make_uint4(lp[4], lp[5], lp[6], lp[7]);
}

// Load 16 fp32 (0 if !row_ok), zero k >= Kvalid, split, store.
__device__ __forceinline__ void stage16(const float* __restrict__ src, bool row_ok,
                                        int kbase, int Kvalid, u16* dH, u16* dL)
{
    float va[16];
    if (row_ok) {
        #pragma unroll
        for (int i = 0; i < 4; i++) {
            const float4 v = *(const float4*)(src + i * 4);
            va[i * 4 + 0] = v.x; va[i * 4 + 1] = v.y;
            va[i * 4 + 2] = v.z; va[i * 4 + 3] = v.w;
        }
        #pragma unroll
        for (int i = 0; i < 16; i++)
            va[i] = (kbase + i < Kvalid) ? va[i] : 0.f;
    } else {
        #pragma unroll
        for (int i = 0; i < 16; i++) va[i] = 0.f;
    }
    split_store(va, dH, dL);
}

// Gathered-embedding staging: va = emb_row[kb..kb+15] * nrm, zero k >= 300.
// Boundary chunks use guarded scalar loads (no OOB past last emb row).
__device__ __forceinline__ void stage_gather(const float* __restrict__ erow, float nrm,
                                             int kb, u16* dH, u16* dL)
{
    float va[16];
    if (kb + 16 <= EDIM) {
        #pragma unroll
        for (int i = 0; i < 4; i++) {
            const float4 v = *(const float4*)(erow + kb + i * 4);
            va[i * 4 + 0] = v.x; va[i * 4 + 1] = v.y;
            va[i * 4 + 2] = v.z; va[i * 4 + 3] = v.w;
        }
    } else {
        #pragma unroll
        for (int i = 0; i < 16; i++)
            va[i] = (kb + i < EDIM) ? erow[kb + i] : 0.f;
    }
    #pragma unroll
    for (int i = 0; i < 16; i++) va[i] *= nrm;
    split_store(va, dH, dL);
}

#define MFMA3(ai, aj) \
    acc[ai][aj] = __builtin_amdgcn_mfma_f32_16x16x32_bf16(fah[ai], fbh[aj], acc[ai][aj], 0, 0, 0); \
    acc[ai][aj] = __builtin_amdgcn_mfma_f32_16x16x32_bf16(fah[ai], fbl[aj], acc[ai][aj], 0, 0, 0); \
    acc[ai][aj] = __builtin_amdgcn_mfma_f32_16x16x32_bf16(fal[ai], fbh[aj], acc[ai][aj], 0, 0, 0);

// ---------------------------------------------------------------------------
// Fused phase-A projection GEMM (per side):
//   A[32768][320] = emb[toks[r]] * norms[toks[r]]  (gathered in staging, k<300)
//   B = stacked weights [700][320] hi/lo: rows 0:200 wp_a | 200:400 wp_b | 400:700 w_intra
//   n <  200 -> XCAT[gm][n]          (no relu; xp accumulates later)
//   n in 200:400 -> T[gm>>7][n-200][gm&127]  (transposed, no relu)
//   n >= 400 -> F[gm][n-400] relu
// grid (6, 256), XCD-swizzled.
// ---------------------------------------------------------------------------
__global__ __launch_bounds__(256) void gemm_proj(
    const int* __restrict__ toks, const float* __restrict__ emb,
    const float* __restrict__ norms,
    const u16* __restrict__ Bh, const u16* __restrict__ Bl,
    float* __restrict__ XCAT, float* __restrict__ T, float* __restrict__ F)
{
    __shared__ u16 AsH[128][40];
    __shared__ u16 AsL[128][40];
    __shared__ u16 BsH[128][40];
    __shared__ u16 BsL[128][40];

    const int tid = threadIdx.x;
    const int id  = blockIdx.y * 6 + blockIdx.x;
    const int xcd = id & 7;
    const int s   = id >> 3;
    const int bm  = (xcd + 8 * (s / 6)) * 128;
    const int bn  = (s % 6) * 128;

    const int wave = tid >> 6;
    const int lane = tid & 63;
    const int wm   = (wave >> 1) * 64;
    const int wn   = (wave & 1) * 64;
    const int lr   = lane & 15;
    const int quad = lane >> 4;
    const int sr   = tid >> 1;
    const int sc   = (tid & 1) * 16;

    const int tok = toks[bm + sr];
    const float nrm = norms[tok];
    const float* erow = emb + (long long)tok * EDIM;

    f32x4 acc[4][4];
    #pragma unroll
    for (int i = 0; i < 4; i++)
        #pragma unroll
        for (int j = 0; j < 4; j++)
            acc[i][j] = (f32x4)(0.0f);

    for (int k0 = 0; k0 < 320; k0 += 32) {
        stage_gather(erow, nrm, k0 + sc, &AsH[sr][sc], &AsL[sr][sc]);
        {
            uint4 wh0 = make_uint4(0,0,0,0), wh1 = make_uint4(0,0,0,0);
            uint4 wl0 = make_uint4(0,0,0,0), wl1 = make_uint4(0,0,0,0);
            const int gn = bn + sr;
            if (gn < 700) {
                const long long br = (long long)gn * 320 + k0 + sc;
                wh0 = *(const uint4*)(Bh + br);
                wh1 = *(const uint4*)(Bh + br + 8);
                wl0 = *(const uint4*)(Bl + br);
                wl1 = *(const uint4*)(Bl + br + 8);
            }
            *(uint4*)&BsH[sr][sc]     = wh0;
            *(uint4*)&BsH[sr][sc + 8] = wh1;
            *(uint4*)&BsL[sr][sc]     = wl0;
            *(uint4*)&BsL[sr][sc + 8] = wl1;
        }
        __syncthreads();

        bf16x8 fah[4], fal[4], fbh[4], fbl[4];
        #pragma unroll
        for (int i = 0; i < 4; i++) {
            fah[i] = *(const bf16x8*)&AsH[wm + i * 16 + lr][quad * 8];
            fal[i] = *(const bf16x8*)&AsL[wm + i * 16 + lr][quad * 8];
            fbh[i] = *(const bf16x8*)&BsH[wn + i * 16 + lr][quad * 8];
            fbl[i] = *(const bf16x8*)&BsL[wn + i * 16 + lr][quad * 8];
        }
        #pragma unroll
        for (int i = 0; i < 4; i++)
            #pragma unroll
            for (int j = 0; j < 4; j++) { MFMA3(i, j) }
        __syncthreads();
    }

    #pragma unroll
    for (int i = 0; i < 4; i++) {
        #pragma unroll
        for (int j = 0; j < 4; j++) {
            const int gn = bn + wn + j * 16 + lr;
            if (gn >= 700) continue;
            #pragma unroll
            for (int r = 0; r < 4; r++) {
                const int gm = bm + wm + i * 16 + quad * 4 + r;
                const float v = acc[i][j][r];
                if (gn < 200)
                    XCAT[(long long)gm * 400 + gn] = v;
                else if (gn < 400)
                    T[(long long)(gm >> 7) * (PDIM * SEQ) + (long long)(gn - 200) * 128 + (gm & 127)] = v;
                else
                    F[(long long)gm * EDIM + (gn - 400)] = fmaxf(v, 0.f);
            }
        }
    }
}

// ---------------------------------------------------------------------------
// Flat split-bf16 MFMA GEMM vs pre-split transposed weights. XCD-swizzled
// when gridDim.y % 8 == 0. Weight select per m-tile: bm >= Msplit -> B2.
// Outputs: C row-major (optional) and/or PO fused masked row-sum pool
// PO[bm>>7][gn] (rows masked to sizes[bm>>7]; 128-row tile == one batch).
// ---------------------------------------------------------------------------
__global__ __launch_bounds__(256) void gemm_flat(
    const float* __restrict__ A,
    const u16* __restrict__ Bh, const u16* __restrict__ Bl,
    const u16* __restrict__ Bh2, const u16* __restrict__ Bl2, int Msplit,
    float* __restrict__ C, float* __restrict__ PO, const int* __restrict__ sizes,
    int M, int N, int Kp, int lda, int ldb, int ldc, int flags)
{
    __shared__ u16 AsH[128][40];
    __shared__ u16 AsL[128][40];
    __shared__ u16 BsH[128][40];
    __shared__ u16 BsL[128][40];

    const int tid = threadIdx.x;
    int bx = blockIdx.x, by = blockIdx.y;
    if ((gridDim.y & 7) == 0) {
        const int gx = gridDim.x;
        const int id = by * gx + bx;
        const int xcd = id & 7;
        const int s = id >> 3;
        by = xcd + 8 * (s / gx);
        bx = s % gx;
    }
    const int bm = by * 128;
    const int bn = bx * 128;

    const int wave = tid >> 6;
    const int lane = tid & 63;
    const int wm   = (wave >> 1) * 64;
    const int wn   = (wave & 1) * 64;
    const int lr   = lane & 15;
    const int quad = lane >> 4;
    const int sr   = tid >> 1;
    const int sc   = (tid & 1) * 16;

    if (bm >= Msplit) { Bh = Bh2; Bl = Bl2; }

    f32x4 acc[4][4];
    #pragma unroll
    for (int i = 0; i < 4; i++)
        #pragma unroll
        for (int j = 0; j < 4; j++)
            acc[i][j] = (f32x4)(0.0f);

    for (int k0 = 0; k0 < Kp; k0 += 32) {
        stage16(A + (long long)(bm + sr) * lda + k0 + sc, true, 0, 1 << 30,
                &AsH[sr][sc], &AsL[sr][sc]);
        {
            uint4 wh0 = make_uint4(0,0,0,0), wh1 = make_uint4(0,0,0,0);
            uint4 wl0 = make_uint4(0,0,0,0), wl1 = make_uint4(0,0,0,0);
            const int gn = bn + sr;
            if (gn < N) {
                const long long br = (long long)gn * ldb + k0 + sc;
                wh0 = *(const uint4*)(Bh + br);
                wh1 = *(const uint4*)(Bh + br + 8);
                wl0 = *(const uint4*)(Bl + br);
                wl1 = *(const uint4*)(Bl + br + 8);
            }
            *(uint4*)&BsH[sr][sc]     = wh0;
            *(uint4*)&BsH[sr][sc + 8] = wh1;
            *(uint4*)&BsL[sr][sc]     = wl0;
            *(uint4*)&BsL[sr][sc + 8] = wl1;
        }
        __syncthreads();

        bf16x8 fah[4], fal[4], fbh[4], fbl[4];
        #pragma unroll
        for (int i = 0; i < 4; i++) {
            fah[i] = *(const bf16x8*)&AsH[wm + i * 16 + lr][quad * 8];
            fal[i] = *(const bf16x8*)&AsL[wm + i * 16 + lr][quad * 8];
            fbh[i] = *(const bf16x8*)&BsH[wn + i * 16 + lr][quad * 8];
            fbl[i] = *(const bf16x8*)&BsL[wn + i * 16 + lr][quad * 8];
        }
        #pragma unroll
        for (int i = 0; i < 4; i++)
            #pragma unroll
            for (int j = 0; j < 4; j++) { MFMA3(i, j) }
        __syncthreads();
    }

    const int sz = PO ? sizes[bm >> 7] : 0;
    float ps[4] = {0.f, 0.f, 0.f, 0.f};
    #pragma unroll
    for (int j = 0; j < 4; j++) {
        const int gn = bn + wn + j * 16 + lr;
        const bool gok = gn < N;
        #pragma unroll
        for (int i = 0; i < 4; i++) {
            #pragma unroll
            for (int r = 0; r < 4; r++) {
                const int row = wm + i * 16 + quad * 4 + r;
                const int gm = bm + row;
                float v = acc[i][j][r];
                if (flags & F_RELU) v = fmaxf(v, 0.f);
                if (gok && C) C[(long long)gm * ldc + gn] = v;
                if (PO && row < sz) ps[j] += v;
            }
        }
    }
    if (PO) {
        #pragma unroll
        for (int j = 0; j < 4; j++) {
            ps[j] += __shfl_xor(ps[j], 16);
            ps[j] += __shfl_xor(ps[j], 32);
        }
        float* PS = (float*)AsH;
        if (wm == 0 && quad == 0) {
            #pragma unroll
            for (int j = 0; j < 4; j++) PS[wn + j * 16 + lr] = ps[j];
        }
        __syncthreads();
        if (wm == 64 && quad == 0) {
            #pragma unroll
            for (int j = 0; j < 4; j++) PS[wn + j * 16 + lr] += ps[j];
        }
        __syncthreads();
        if (tid < 128) {
            const int gn = bn + tid;
            if (gn < N) PO[(long long)(bm >> 7) * N + gn] = PS[tid];
        }
    }
}

// ---------------------------------------------------------------------------
// Batched split-bf16 MFMA GEMM, NT, both operands fp32->hi/lo in staging.
// MODE 0: plain (ACCUM/RELU; optional sizes mask; optional PT transposed
//         store, may alias B; (Aalt,Balt) for bz>=256 with bz-256).
// MODE 1: att — dist-bias (|i-j|>=10) + fused row softmax -> C (probs).
// ---------------------------------------------------------------------------
template <int MODE>
__global__ __launch_bounds__(256) void gemm_bat(
    const float* __restrict__ A, const float* __restrict__ Aalt,
    const float* __restrict__ B, const float* __restrict__ Balt,
    float* __restrict__ C, float* __restrict__ PT,
    int N, int Kvalid, int Kp, int lda, int ldb, int ldc,
    long long sA, long long sB, long long sC, long long sPT,
    int flags, const float* __restrict__ bias_ptr, const int* __restrict__ sizes,
    int same_ab)
{
    constexpr int SB = (MODE == 1) ? 65536 : 40960;
    __shared__ __align__(16) unsigned char smem[SB];
    u16 (*AsH)[40] = (u16(*)[40])(smem);
    u16 (*AsL)[40] = (u16(*)[40])(smem + 10240);
    u16 (*BsH)[40] = (u16(*)[40])(smem + 20480);
    u16 (*BsL)[40] = (u16(*)[40])(smem + 30720);

    const int bz = blockIdx.z;
    long long zb = bz;
    const float* Ause = A;
    const float* Buse = B;
    if (Aalt && bz >= BATCH) { Ause = Aalt; Buse = Balt; zb = bz - BATCH; }
    Ause += zb * sA;
    Buse += zb * sB;
    C += (long long)bz * sC;
    if (PT) PT += (long long)bz * sPT;

    const int tid  = threadIdx.x;
    const int bn   = blockIdx.x * 128;
    const int wave = tid >> 6;
    const int lane = tid & 63;
    const int wm   = (wave >> 1) * 64;
    const int wn   = (wave & 1) * 64;
    const int lr   = lane & 15;
    const int quad = lane >> 4;
    const int sr   = tid >> 1;
    const int sc   = (tid & 1) * 16;

    f32x4 acc[4][4];
    #pragma unroll
    for (int i = 0; i < 4; i++)
        #pragma unroll
        for (int j = 0; j < 4; j++)
            acc[i][j] = (f32x4)(0.0f);

    u16 (*fbH)[40] = same_ab ? AsH : BsH;
    u16 (*fbL)[40] = same_ab ? AsL : BsL;

    for (int k0 = 0; k0 < Kp; k0 += 32) {
        stage16(Ause + (long long)sr * lda + k0 + sc, true, k0 + sc, Kvalid,
                &AsH[sr][sc], &AsL[sr][sc]);
        if (!same_ab) {
            const int gn = bn + sr;
            stage16(Buse + (long long)gn * ldb + k0 + sc, gn < N, k0 + sc, Kvalid,
                    &BsH[sr][sc], &BsL[sr][sc]);
        }
        __syncthreads();

        bf16x8 fah[4], fal[4], fbh[4], fbl[4];
        #pragma unroll
        for (int i = 0; i < 4; i++) {
            fah[i] = *(const bf16x8*)&AsH[wm + i * 16 + lr][quad * 8];
            fal[i] = *(const bf16x8*)&AsL[wm + i * 16 + lr][quad * 8];
            fbh[i] = *(const bf16x8*)&fbH[wn + i * 16 + lr][quad * 8];
            fbl[i] = *(const bf16x8*)&fbL[wn + i * 16 + lr][quad * 8];
        }
        #pragma unroll
        for (int i = 0; i < 4; i++)
            #pragma unroll
            for (int j = 0; j < 4; j++) { MFMA3(i, j) }
        __syncthreads();
    }

    if (MODE == 1) {
        float* S = (float*)smem;   // 128x128 f32 (staging dead)
        const float bias = bias_ptr[0];
        #pragma unroll
        for (int i = 0; i < 4; i++) {
            #pragma unroll
            for (int j = 0; j < 4; j++) {
                const int col = wn + j * 16 + lr;
                #pragma unroll
                for (int r = 0; r < 4; r++) {
                    const int row = wm + i * 16 + quad * 4 + r;
                    int d = row - col; d = d < 0 ? -d : d;
                    S[row * 128 + col] = acc[i][j][r] + ((d >= 10) ? bias : 0.f);
                }
            }
        }
        __syncthreads();
        const int row = tid >> 1;
        const int half = (tid & 1) * 64;
        float mx = -1e30f;
        for (int c = 0; c < 64; c++) mx = fmaxf(mx, S[row * 128 + half + c]);
        mx = fmaxf(mx, __shfl_xor(mx, 1));
        float sum = 0.f;
        for (int c = 0; c < 64; c++) sum += __expf(S[row * 128 + half + c] - mx);
        sum += __shfl_xor(sum, 1);
        const float inv = 1.f / sum;
        for (int c = 0; c < 64; c++)
            C[(long long)row * ldc + half + c] = __expf(S[row * 128 + half + c] - mx) * inv;
    } else {
        const int s1 = sizes ? sizes[bz] : SEQ;
        const int s2 = sizes ? sizes[BATCH + bz] : SEQ;
        #pragma unroll
        for (int i = 0; i < 4; i++) {
            #pragma unroll
            for (int j = 0; j < 4; j++) {
                const int gn = bn + wn + j * 16 + lr;
                if (gn >= N) continue;
                #pragma unroll
                for (int r = 0; r < 4; r++) {
                    const int gm = wm + i * 16 + quad * 4 + r;
                    float v = acc[i][j][r];
                    if (sizes && (gm >= s1 || gn >= s2)) v = 0.f;
                    if (flags & F_ACCUM) v += C[(long long)gm * ldc + gn];
                    if (flags & F_RELU)  v = fmaxf(v, 0.f);
                    C[(long long)gm * ldc + gn] = v;
                    if (PT) PT[(long long)gn * 128 + gm] = v;
                }
            }
        }
    }
}

// One block per batch: sim tile to LDS, row softmax in-place, col softmax
// transposed -> smt.
__global__ __launch_bounds__(256) void softmax_both(float* __restrict__ sim,
                                                    float* __restrict__ smt)
{
    __shared__ float S[128 * 128];
    const int b = blockIdx.x;
    const int tid = threadIdx.x;
    float* sp = sim + (long long)b * (SEQ * SEQ);
    float* qp = smt + (long long)b * (SEQ * SEQ);
    #pragma unroll
    for (int it = 0; it < 16; it++) {
        const int i4 = it * 256 + tid;
        ((float4*)S)[i4] = ((const float4*)sp)[i4];
    }
    __syncthreads();
    const int idx = tid >> 1;
    const int half = (tid & 1) * 64;
    {
        float mx = -1e30f;
        for (int c = 0; c < 64; c++) mx = fmaxf(mx, S[idx * 128 + half + c]);
        mx = fmaxf(mx, __shfl_xor(mx, 1));
        float sum = 0.f;
        for (int c = 0; c < 64; c++) sum += __expf(S[idx * 128 + half + c] - mx);
        sum += __shfl_xor(sum, 1);
        const float inv = 1.f / sum;
        for (int c = 0; c < 64; c++)
            sp[idx * 128 + half + c] = __expf(S[idx * 128 + half + c] - mx) * inv;
    }
    {
        float mx = -1e30f;
        for (int r = 0; r < 64; r++) mx = fmaxf(mx, S[(half + r) * 128 + idx]);
        mx = fmaxf(mx, __shfl_xor(mx, 1));
        float sum = 0.f;
        for (int r = 0; r < 64; r++) sum += __expf(S[(half + r) * 128 + idx] - mx);
        sum += __shfl_xor(sum, 1);
        const float inv = 1.f / sum;
        for (int r = 0; r < 64; r++)
            qp[idx * 128 + half + r] = __expf(S[(half + r) * 128 + idx] - mx) * inv;
    }
}

// All weight transposes + hi/lo splits in one launch.
struct WEnt { const float* src; u16* H; u16* L; int K, N, Kp, rowStart; };
struct WTab { WEnt e[9]; };
__global__ void convert_all(WTab t)
{
    const int row = blockIdx.y;
    const int k = blockIdx.x * 256 + threadIdx.x;
    #pragma unroll
    for (int s = 0; s < 9; s++) {
        const WEnt w = t.e[s];
        if (row >= w.rowStart && row < w.rowStart + w.N) {
            const int n = row - w.rowStart;
            if (k < w.Kp) {
                const float v = (k < w.K) ? w.src[(long long)k * w.N + n] : 0.f;
                const u16 h = f2bf(v);
                w.H[(long long)n * w.Kp + k] = h;
                w.L[(long long)n * w.Kp + k] = f2bf(v - bf2f(h));
            }
            return;
        }
    }
}

// norms[r] = rsqrt(max(sum(emb[r]^2), 1e-12)), one wave per vocab row
__global__ void norms_kernel(const float* __restrict__ emb, float* __restrict__ norms)
{
    const int r = blockIdx.x;
    const int lane = threadIdx.x;
    const float* row = emb + (long long)r * EDIM;
    float ss = 0.f;
    #pragma unroll
    for (int i = 0; i < 5; i++) {
        const int c = lane + i * 64;
        const float f = (c < EDIM) ? row[c] : 0.f;
        ss += f * f;
    }
    #pragma unroll
    for (int o = 32; o > 0; o >>= 1) ss += __shfl_xor(ss, o);
    if (lane == 0) norms[r] = rsqrtf(fmaxf(ss, 1e-12f));
}

__global__ void sizes_kernel(const int* __restrict__ x1, const int* __restrict__ x2,
                             int* __restrict__ sizes)
{
    const int b = blockIdx.x;
    const int side = blockIdx.y;
    const int* x = (side ? x2 : x1) + b * SEQ;
    const int nz = (x[threadIdx.x] != 0) ? 1 : 0;
    const unsigned long long bal = __ballot(nz);
    __shared__ int part[2];
    if ((threadIdx.x & 63) == 0) part[threadIdx.x >> 6] = __popcll(bal);
    __syncthreads();
    if (threadIdx.x == 0) sizes[side * BATCH + b] = part[0] + part[1];
}

// y[b,c] = relu(sum_k concat(v1s,v2s)[b,k] * w_agg[k,c]), K=800, C=3
__global__ void agg_kernel(const float* __restrict__ v1s, const float* __restrict__ v2s,
                           const float* __restrict__ w_agg, float* __restrict__ y)
{
    const int b = blockIdx.x;
    const int lane = threadIdx.x;
    float a0 = 0.f, a1 = 0.f, a2 = 0.f;
    for (int k = lane; k < 800; k += 64) {
        const float v = (k < 400) ? v1s[b * 400 + k] : v2s[b * 400 + k - 400];
        a0 = fmaf(v, w_agg[k * 3 + 0], a0);
        a1 = fmaf(v, w_agg[k * 3 + 1], a1);
        a2 = fmaf(v, w_agg[k * 3 + 2], a2);
    }
    #pragma unroll
    for (int o = 32; o > 0; o >>= 1) {
        a0 += __shfl_xor(a0, o);
        a1 += __shfl_xor(a1, o);
        a2 += __shfl_xor(a2, o);
    }
    if (lane == 0) {
        y[b * 3 + 0] = fmaxf(a0, 0.f);
        y[b * 3 + 1] = fmaxf(a1, 0.f);
        y[b * 3 + 2] = fmaxf(a2, 0.f);
    }
}

extern "C" void kernel_launch(void* const* d_in, const int* in_sizes, int n_in,
                              void* d_out, int out_size, void* d_ws, size_t ws_size,
                              hipStream_t stream)
{
    (void)in_sizes; (void)n_in; (void)out_size; (void)ws_size;
    const int*   x1         = (const int*)d_in[0];
    const int*   x2         = (const int*)d_in[1];
    const float* emb        = (const float*)d_in[2];
    const float* w_intra    = (const float*)d_in[3];
    const float* bias_intra = (const float*)d_in[4];
    const float* w_proj1    = (const float*)d_in[5];
    const float* w_proj2    = (const float*)d_in[6];
    const float* w_att      = (const float*)d_in[7];
    const float* w_cmp1     = (const float*)d_in[8];
    const float* w_cmp2     = (const float*)d_in[9];
    const float* w_agg      = (const float*)d_in[10];
    float* y  = (float*)d_out;
    float* ws = (float*)d_ws;

    // ---- workspace (floats); total ~58.6M fl = 234.4 MB ----
    float* X1CAT = ws;                        // [32768,400]: x1p | beta
    float* X2CAT = X1CAT + 13107200;          // [32768,400]: x2p | alpha (contig)
    float* T     = X2CAT + 13107200;          // [512,200,128]: G^T -> x_proj^T (T1|T2)
    float* FBUF  = T + 13107200;              // [32768,300] intra f (phase A)
    float* ATT   = FBUF + 9830400;            // [512,128,128] probs (phase A)
    float* POOL  = ATT + 8388608;             // [512,400] pooled v1|v2
    int*   SIZES = (int*)(POOL + 204800);     // [2,256] + pad
    float* NORMS = (float*)(SIZES + 512);     // [32000] + pad
    u16*   W1H   = (u16*)(NORMS + 32768);     // side-1 stack [700][320]
    u16*   W1L   = W1H + 224000;
    u16*   W2H   = W1L + 224000;              // side-2 stack [700][320]
    u16*   W2L   = W2H + 224000;
    u16*   WAH   = W2L + 224000;              // w_att^T  [200][224]
    u16*   WAL   = WAH + 44800;
    u16*   WC1H  = WAL + 44800;               // w_cmp1^T [400][416]
    u16*   WC1L  = WC1H + 166400;
    u16*   WC2H  = WC1L + 166400;
    u16*   WC2L  = WC2H + 166400;

    // phase-B aliases over FBUF+ATT (18.2M contiguous, dead after xp)
    float* F12 = FBUF;                        // [65536,200] f1|f2
    float* F2  = FBUF + 6553600;
    float* SIM = FBUF + 13107200;             // [256,128,128] (inside ATT region)
    float* SMT = FBUF;                        // [256,128,128] (F12 dead)
    float* T1  = T;
    float* T2  = T + 6553600;

    const long long sbSS = (long long)SEQ * SEQ;     // 16384
    const long long sbF  = (long long)SEQ * EDIM;    // 38400
    const long long sbP  = (long long)SEQ * PDIM;    // 25600
    const long long sbC  = (long long)SEQ * 400;     // 51200
    const long long sbT  = (long long)PDIM * SEQ;    // 25600

    sizes_kernel<<<dim3(BATCH, 2), 128, 0, stream>>>(x1, x2, SIZES);
    norms_kernel<<<32000, 64, 0, stream>>>(emb, NORMS);

    {
        WTab t;
        t.e[0] = { w_proj1,             W1H,             W1L,             300, 200, 320, 0    };
        t.e[1] = { w_proj1 + 300 * 200, W1H + 200 * 320, W1L + 200 * 320, 300, 200, 320, 200  };
        t.e[2] = { w_intra,             W1H + 400 * 320, W1L + 400 * 320, 300, 300, 320, 400  };
        t.e[3] = { w_proj2,             W2H,             W2L,             300, 200, 320, 700  };
        t.e[4] = { w_proj2 + 300 * 200, W2H + 200 * 320, W2L + 200 * 320, 300, 200, 320, 900  };
        t.e[5] = { w_intra,             W2H + 400 * 320, W2L + 400 * 320, 300, 300, 320, 1100 };
        t.e[6] = { w_att,               WAH,             WAL,             200, 200, 224, 1400 };
        t.e[7] = { w_cmp1,              WC1H,            WC1L,            400, 400, 416, 1600 };
        t.e[8] = { w_cmp2,              WC2H,            WC2L,            400, 400, 416, 2000 };
        convert_all<<<dim3(2, 2400), 256, 0, stream>>>(t);
    }

    // -------- phase A --------
    for (int side = 0; side < 2; side++) {
        const int* x = side ? x2 : x1;
        float* XCAT  = side ? X2CAT : X1CAT;
        float* Ts    = side ? T2 : T1;
        u16* WH = side ? W2H : W1H;
        u16* WL = side ? W2L : W1L;

        // fused: XCAT[:,0:200]=e@wp_a, Ts=(e@wp_b)^T, FBUF=relu(e@w_intra)
        gemm_proj<<<dim3(6, 256), 256, 0, stream>>>(x, emb, NORMS, WH, WL, XCAT, Ts, FBUF);
        // probs = rowsoftmax(f f^T + dbias) -> ATT[side*256 ..]
        gemm_bat<1><<<dim3(1, 1, BATCH), 256, 0, stream>>>(
            FBUF, nullptr, FBUF, nullptr, ATT + (long long)side * BATCH * sbSS, nullptr,
            SEQ, EDIM, 320, EDIM, EDIM, SEQ, sbF, sbF, sbSS, 0,
            0, bias_intra, nullptr, 1);
    }
    // xp merged (512 batches): XCAT[:,0:200] = relu(XCAT + probs @ G); x_proj^T -> T
    gemm_bat<0><<<dim3(2, 1, 2 * BATCH), 256, 0, stream>>>(
        ATT, nullptr, T, nullptr, X1CAT, T,
        PDIM, SEQ, SEQ, SEQ, SEQ, 400, sbSS, sbT, sbC, sbT,
        F_ACCUM | F_RELU, nullptr, nullptr, 0);

    // -------- phase B --------
    // f1|f2 = relu(x_proj @ w_att)   [M=65536; A cols 200:224 garbage*0]
    gemm_flat<<<dim3(2, 512), 256, 0, stream>>>(
        X1CAT, WAH, WAL, WAH, WAL, 1 << 30, F12, nullptr, nullptr,
        2 * BSTOK, PDIM, 224, 400, 224, PDIM, F_RELU);
    // sim = mask(f1 f2^T)
    gemm_bat<0><<<dim3(1, 1, BATCH), 256, 0, stream>>>(
        F12, nullptr, F2, nullptr, SIM, nullptr,
        SEQ, PDIM, 224, PDIM, PDIM, SEQ, sbP, sbP, sbSS, 0,
        0, nullptr, SIZES, 0);
    softmax_both<<<BATCH, 256, 0, stream>>>(SIM, SMT);
    // beta (bz<256) / alpha (bz>=256) -> X1CAT/X2CAT cols 200:400
    gemm_bat<0><<<dim3(2, 1, 2 * BATCH), 256, 0, stream>>>(
        SIM, SMT, T2, T1, X1CAT + 200, nullptr,
        PDIM, SEQ, SEQ, SEQ, SEQ, 400, sbSS, sbT, sbC, 0,
        0, nullptr, nullptr, 0);

    // -------- phase C: fused compare + masked pool, aggregate --------
    gemm_flat<<<dim3(4, 512), 256, 0, stream>>>(
        X1CAT, WC1H, WC1L, WC2H, WC2L, BSTOK,
        nullptr, POOL, SIZES,
        2 * BSTOK, 400, 416, 400, 416, 400, F_RELU);
    agg_kernel<<<BATCH, 64, 0, stream>>>(POOL, POOL + 102400, w_agg, y);
}

// Round 8
// 611.596 us; speedup vs baseline: 2.9882x; 1.1344x over previous
//
#include <hip/hip_runtime.h>

#define BATCH 256
#define SEQ   128
#define EDIM  300
#define PDIM  200
#define BSTOK (BATCH * SEQ)

#define F_RELU  1
#define F_ACCUM 2

typedef unsigned short u16;
typedef __attribute__((ext_vector_type(8))) short bf16x8;
typedef __attribute__((ext_vector_type(4))) float f32x4;

__device__ __forceinline__ u16 f2bf(float x) {
    unsigned u = __float_as_uint(x);
    unsigned r = u + 0x7fffu + ((u >> 16) & 1u);
    return (u16)(r >> 16);
}
__device__ __forceinline__ float bf2f(u16 h) {
    return __uint_as_float(((unsigned)h) << 16);
}

// split 16 fp32 -> hi(trunc)/lo(residual) bf16, store 2 x uint4 each.
__device__ __forceinline__ void split_store(const float* va, u16* dH, u16* dL)
{
    unsigned hp[8], lp[8];
    #pragma unroll
    for (int i = 0; i < 8; i++) {
        const unsigned u0 = __float_as_uint(va[2 * i]);
        const unsigned u1 = __float_as_uint(va[2 * i + 1]);
        const unsigned h0 = u0 & 0xffff0000u;
        const unsigned h1 = u1 & 0xffff0000u;
        hp[i] = (u0 >> 16) | h1;
        const float r0 = va[2 * i]     - __uint_as_float(h0);
        const float r1 = va[2 * i + 1] - __uint_as_float(h1);
        lp[i] = (__float_as_uint(r0) >> 16) | (__float_as_uint(r1) & 0xffff0000u);
    }
    ((uint4*)dH)[0] = make_uint4(hp[0], hp[1], hp[2], hp[3]);
    ((uint4*)dH)[1] = make_uint4(hp[4], hp[5], hp[6], hp[7]);
    ((uint4*)dL)[0] = make_uint4(lp[0], lp[1], lp[2], lp[3]);
    ((uint4*)dL)[1] = make_uint4(lp[4], lp[5], lp[6], lp[7]);
}

__device__ __forceinline__ void stage16(const float* __restrict__ src, bool row_ok,
                                        int kbase, int Kvalid, u16* dH, u16* dL)
{
    float va[16];
    if (row_ok) {
        #pragma unroll
        for (int i = 0; i < 4; i++) {
            const float4 v = *(const float4*)(src + i * 4);
            va[i * 4 + 0] = v.x; va[i * 4 + 1] = v.y;
            va[i * 4 + 2] = v.z; va[i * 4 + 3] = v.w;
        }
        #pragma unroll
        for (int i = 0; i < 16; i++)
            va[i] = (kbase + i < Kvalid) ? va[i] : 0.f;
    } else {
        #pragma unroll
        for (int i = 0; i < 16; i++) va[i] = 0.f;
    }
    split_store(va, dH, dL);
}

// Gathered-embedding staging: va = emb_row[kb..kb+15] * nrm, zero k >= 300.
__device__ __forceinline__ void stage_gather(const float* __restrict__ erow, float nrm,
                                             int kb, u16* dH, u16* dL)
{
    float va[16];
    if (kb + 16 <= EDIM) {
        #pragma unroll
        for (int i = 0; i < 4; i++) {
            const float4 v = *(const float4*)(erow + kb + i * 4);
            va[i * 4 + 0] = v.x; va[i * 4 + 1] = v.y;
            va[i * 4 + 2] = v.z; va[i * 4 + 3] = v.w;
        }
    } else {
        #pragma unroll
        for (int i = 0; i < 16; i++)
            va[i] = (kb + i < EDIM) ? erow[kb + i] : 0.f;
    }
    #pragma unroll
    for (int i = 0; i < 16; i++) va[i] *= nrm;
    split_store(va, dH, dL);
}

#define MFMA3(ai, aj) \
    acc[ai][aj] = __builtin_amdgcn_mfma_f32_16x16x32_bf16(fah[ai], fbh[aj], acc[ai][aj], 0, 0, 0); \
    acc[ai][aj] = __builtin_amdgcn_mfma_f32_16x16x32_bf16(fah[ai], fbl[aj], acc[ai][aj], 0, 0, 0); \
    acc[ai][aj] = __builtin_amdgcn_mfma_f32_16x16x32_bf16(fal[ai], fbh[aj], acc[ai][aj], 0, 0, 0);

// Coalesced transposed store of the block's 128x128 tile: PT[gp][0:128] for
// gp = bn..bn+127 (guard gp < Nvalid), via LDS (stride 129 to spread banks).
// TR must be >= 64*129 floats (33 KB; staging LDS is free after final barrier).
__device__ __forceinline__ void store_transposed(
    float* __restrict__ PT, const f32x4 (*acc)[4], float* TR,
    int bn, int Nvalid, int wm, int wn, int lr, int quad, int tid, bool relu)
{
    #pragma unroll
    for (int h = 0; h < 2; h++) {
        __syncthreads();
        if ((wn >> 6) == h) {
            #pragma unroll
            for (int j = 0; j < 4; j++) {
                const int col = j * 16 + lr;      // 0..63 within half
                #pragma unroll
                for (int i = 0; i < 4; i++)
                    #pragma unroll
                    for (int r = 0; r < 4; r++) {
                        float v = acc[i][j][r];
                        if (relu) v = fmaxf(v, 0.f);
                        TR[col * 129 + wm + i * 16 + quad * 4 + r] = v;
                    }
            }
        }
        __syncthreads();
        const int row = tid >> 2;                 // 0..63
        const int gp = bn + h * 64 + row;
        if (gp < Nvalid) {
            float* dst = PT + (long long)gp * 128;
            for (int c = (tid & 3); c < 32; c += 4) {
                const int base = row * 129 + c * 4;
                *(float4*)(dst + c * 4) =
                    make_float4(TR[base], TR[base + 1], TR[base + 2], TR[base + 3]);
            }
        }
    }
}

// ---------------------------------------------------------------------------
// Phase-A projection GEMM (per side):
//   A[32768][320] = emb[toks[r]] * norms[toks[r]]  (gathered in staging)
//   B = stacked [556][320] hi/lo: rows 0:200 wp_b | 200:256 zero | 256:556 intra
//   tile bn < 256  -> T[gm>>7][gn][gm&127] (transposed coalesced, gn<200)
//   tile bn >= 256 -> F[gm][gn-256] relu (gn-256 < 300)
// grid (5, 256), XCD-swizzled.
// ---------------------------------------------------------------------------
__global__ __launch_bounds__(256) void gemm_proj(
    const int* __restrict__ toks, const float* __restrict__ emb,
    const float* __restrict__ norms,
    const u16* __restrict__ Bh, const u16* __restrict__ Bl,
    float* __restrict__ T, float* __restrict__ F)
{
    __shared__ __align__(16) unsigned char smem[40960];
    u16 (*AsH)[40] = (u16(*)[40])(smem);
    u16 (*AsL)[40] = (u16(*)[40])(smem + 10240);
    u16 (*BsH)[40] = (u16(*)[40])(smem + 20480);
    u16 (*BsL)[40] = (u16(*)[40])(smem + 30720);

    const int tid = threadIdx.x;
    const int id  = blockIdx.y * 5 + blockIdx.x;
    const int xcd = id & 7;
    const int s   = id >> 3;
    const int bm  = (xcd + 8 * (s / 5)) * 128;
    const int bn  = (s % 5) * 128;

    const int wave = tid >> 6;
    const int lane = tid & 63;
    const int wm   = (wave >> 1) * 64;
    const int wn   = (wave & 1) * 64;
    const int lr   = lane & 15;
    const int quad = lane >> 4;
    const int sr   = tid >> 1;
    const int sc   = (tid & 1) * 16;

    const int tok = toks[bm + sr];
    const float nrm = norms[tok];
    const float* erow = emb + (long long)tok * EDIM;

    f32x4 acc[4][4];
    #pragma unroll
    for (int i = 0; i < 4; i++)
        #pragma unroll
        for (int j = 0; j < 4; j++)
            acc[i][j] = (f32x4)(0.0f);

    for (int k0 = 0; k0 < 320; k0 += 32) {
        stage_gather(erow, nrm, k0 + sc, &AsH[sr][sc], &AsL[sr][sc]);
        {
            uint4 wh0 = make_uint4(0,0,0,0), wh1 = make_uint4(0,0,0,0);
            uint4 wl0 = make_uint4(0,0,0,0), wl1 = make_uint4(0,0,0,0);
            const int gn = bn + sr;
            if (gn < 556) {
                const long long br = (long long)gn * 320 + k0 + sc;
                wh0 = *(const uint4*)(Bh + br);
                wh1 = *(const uint4*)(Bh + br + 8);
                wl0 = *(const uint4*)(Bl + br);
                wl1 = *(const uint4*)(Bl + br + 8);
            }
            *(uint4*)&BsH[sr][sc]     = wh0;
            *(uint4*)&BsH[sr][sc + 8] = wh1;
            *(uint4*)&BsL[sr][sc]     = wl0;
            *(uint4*)&BsL[sr][sc + 8] = wl1;
        }
        __syncthreads();

        bf16x8 fah[4], fal[4], fbh[4], fbl[4];
        #pragma unroll
        for (int i = 0; i < 4; i++) {
            fah[i] = *(const bf16x8*)&AsH[wm + i * 16 + lr][quad * 8];
            fal[i] = *(const bf16x8*)&AsL[wm + i * 16 + lr][quad * 8];
            fbh[i] = *(const bf16x8*)&BsH[wn + i * 16 + lr][quad * 8];
            fbl[i] = *(const bf16x8*)&BsL[wn + i * 16 + lr][quad * 8];
        }
        #pragma unroll
        for (int i = 0; i < 4; i++)
            #pragma unroll
            for (int j = 0; j < 4; j++) { MFMA3(i, j) }
        __syncthreads();
    }

    if (bn < 256) {
        float* Tb = T + (long long)(bm >> 7) * (PDIM * SEQ);
        store_transposed(Tb, acc, (float*)smem, bn, PDIM, wm, wn, lr, quad, tid, false);
    } else {
        #pragma unroll
        for (int i = 0; i < 4; i++) {
            #pragma unroll
            for (int j = 0; j < 4; j++) {
                const int idx = bn + wn + j * 16 + lr - 256;
                if (idx >= EDIM) continue;
                #pragma unroll
                for (int r = 0; r < 4; r++) {
                    const int gm = bm + wm + i * 16 + quad * 4 + r;
                    F[(long long)gm * EDIM + idx] = fmaxf(acc[i][j][r], 0.f);
                }
            }
        }
    }
}

// ---------------------------------------------------------------------------
// Fused xp GEMM: acc = e @ wp_a (flat, K=320, gathered A) + probs @ G (batched,
// K=128); out = relu(acc) -> XCAT rows of batch (cols 0:200) + transposed
// in-place over T (G^T -> x_proj^T; block writes exactly the rows it read).
// grid (2, 1, 512): bz<256 side-1 (x1 toks), else side-2.
// ---------------------------------------------------------------------------
__global__ __launch_bounds__(256) void gemm_xp(
    const float* __restrict__ P, float* __restrict__ T,
    const int* __restrict__ x1, const int* __restrict__ x2,
    const float* __restrict__ emb, const float* __restrict__ norms,
    const u16* __restrict__ W1h, const u16* __restrict__ W1l,
    const u16* __restrict__ W2h, const u16* __restrict__ W2l,
    float* __restrict__ XCAT)
{
    __shared__ __align__(16) unsigned char smem[40960];
    u16 (*AsH)[40] = (u16(*)[40])(smem);
    u16 (*AsL)[40] = (u16(*)[40])(smem + 10240);
    u16 (*BsH)[40] = (u16(*)[40])(smem + 20480);
    u16 (*BsL)[40] = (u16(*)[40])(smem + 30720);

    const int tid = threadIdx.x;
    const int bz  = blockIdx.z;
    const int bn  = blockIdx.x * 128;

    const int wave = tid >> 6;
    const int lane = tid & 63;
    const int wm   = (wave >> 1) * 64;
    const int wn   = (wave & 1) * 64;
    const int lr   = lane & 15;
    const int quad = lane >> 4;
    const int sr   = tid >> 1;
    const int sc   = (tid & 1) * 16;

    const int* toks = (bz < BATCH) ? x1 + bz * SEQ : x2 + (bz - BATCH) * SEQ;
    const u16* Wh = (bz < BATCH) ? W1h : W2h;
    const u16* Wl = (bz < BATCH) ? W1l : W2l;
    const int tok = toks[sr];
    const float nrm = norms[tok];
    const float* erow = emb + (long long)tok * EDIM;
    const float* Pb = P + (long long)bz * (SEQ * SEQ);
    float* Tb = T + (long long)bz * (PDIM * SEQ);

    f32x4 acc[4][4];
    #pragma unroll
    for (int i = 0; i < 4; i++)
        #pragma unroll
        for (int j = 0; j < 4; j++)
            acc[i][j] = (f32x4)(0.0f);

    // flat term: e @ wp_a  (K=320)
    for (int k0 = 0; k0 < 320; k0 += 32) {
        stage_gather(erow, nrm, k0 + sc, &AsH[sr][sc], &AsL[sr][sc]);
        {
            uint4 wh0 = make_uint4(0,0,0,0), wh1 = make_uint4(0,0,0,0);
            uint4 wl0 = make_uint4(0,0,0,0), wl1 = make_uint4(0,0,0,0);
            const int gn = bn + sr;
            if (gn < PDIM) {
                const long long br = (long long)gn * 320 + k0 + sc;
                wh0 = *(const uint4*)(Wh + br);
                wh1 = *(const uint4*)(Wh + br + 8);
                wl0 = *(const uint4*)(Wl + br);
                wl1 = *(const uint4*)(Wl + br + 8);
            }
            *(uint4*)&BsH[sr][sc]     = wh0;
            *(uint4*)&BsH[sr][sc + 8] = wh1;
            *(uint4*)&BsL[sr][sc]     = wl0;
            *(uint4*)&BsL[sr][sc + 8] = wl1;
        }
        __syncthreads();

        bf16x8 fah[4], fal[4], fbh[4], fbl[4];
        #pragma unroll
        for (int i = 0; i < 4; i++) {
            fah[i] = *(const bf16x8*)&AsH[wm + i * 16 + lr][quad * 8];
            fal[i] = *(const bf16x8*)&AsL[wm + i * 16 + lr][quad * 8];
            fbh[i] = *(const bf16x8*)&BsH[wn + i * 16 + lr][quad * 8];
            fbl[i] = *(const bf16x8*)&BsL[wn + i * 16 + lr][quad * 8];
        }
        #pragma unroll
        for (int i = 0; i < 4; i++)
            #pragma unroll
            for (int j = 0; j < 4; j++) { MFMA3(i, j) }
        __syncthreads();
    }

    // batched term: probs @ G  (K=128, B = Tb rows, read-then-overwritten)
    for (int k0 = 0; k0 < 128; k0 += 32) {
        stage16(Pb + (long long)sr * 128 + k0 + sc, true, 0, 1 << 30,
                &AsH[sr][sc], &AsL[sr][sc]);
        const int gn = bn + sr;
        stage16(Tb + (long long)gn * 128 + k0 + sc, gn < PDIM, 0, 1 << 30,
                &BsH[sr][sc], &BsL[sr][sc]);
        __syncthreads();

        bf16x8 fah[4], fal[4], fbh[4], fbl[4];
        #pragma unroll
        for (int i = 0; i < 4; i++) {
            fah[i] = *(const bf16x8*)&AsH[wm + i * 16 + lr][quad * 8];
            fal[i] = *(const bf16x8*)&AsL[wm + i * 16 + lr][quad * 8];
            fbh[i] = *(const bf16x8*)&BsH[wn + i * 16 + lr][quad * 8];
            fbl[i] = *(const bf16x8*)&BsL[wn + i * 16 + lr][quad * 8];
        }
        #pragma unroll
        for (int i = 0; i < 4; i++)
            #pragma unroll
            for (int j = 0; j < 4; j++) { MFMA3(i, j) }
        __syncthreads();
    }

    // epilogue: relu -> XCAT (row-major) + x_proj^T in-place over Tb
    const long long rowbase = (long long)bz * SEQ;
    #pragma unroll
    for (int i = 0; i < 4; i++) {
        #pragma unroll
        for (int j = 0; j < 4; j++) {
            const int gn = bn + wn + j * 16 + lr;
            if (gn >= PDIM) continue;
            #pragma unroll
            for (int r = 0; r < 4; r++) {
                const int gm = wm + i * 16 + quad * 4 + r;
                XCAT[(rowbase + gm) * 400 + gn] = fmaxf(acc[i][j][r], 0.f);
            }
        }
    }
    store_transposed(Tb, acc, (float*)smem, bn, PDIM, wm, wn, lr, quad, tid, true);
}

// ---------------------------------------------------------------------------
// Flat split-bf16 MFMA GEMM vs pre-split transposed weights. XCD-swizzled
// when gridDim.y % 8 == 0. Weight select per m-tile: bm >= Msplit -> B2.
// Outputs: C row-major (optional) and/or PO fused masked row-sum pool.
// ---------------------------------------------------------------------------
__global__ __launch_bounds__(256) void gemm_flat(
    const float* __restrict__ A,
    const u16* __restrict__ Bh, const u16* __restrict__ Bl,
    const u16* __restrict__ Bh2, const u16* __restrict__ Bl2, int Msplit,
    float* __restrict__ C, float* __restrict__ PO, const int* __restrict__ sizes,
    int M, int N, int Kp, int lda, int ldb, int ldc, int flags)
{
    __shared__ u16 AsH[128][40];
    __shared__ u16 AsL[128][40];
    __shared__ u16 BsH[128][40];
    __shared__ u16 BsL[128][40];

    const int tid = threadIdx.x;
    int bx = blockIdx.x, by = blockIdx.y;
    if ((gridDim.y & 7) == 0) {
        const int gx = gridDim.x;
        const int id = by * gx + bx;
        const int xcd = id & 7;
        const int s = id >> 3;
        by = xcd + 8 * (s / gx);
        bx = s % gx;
    }
    const int bm = by * 128;
    const int bn = bx * 128;

    const int wave = tid >> 6;
    const int lane = tid & 63;
    const int wm   = (wave >> 1) * 64;
    const int wn   = (wave & 1) * 64;
    const int lr   = lane & 15;
    const int quad = lane >> 4;
    const int sr   = tid >> 1;
    const int sc   = (tid & 1) * 16;

    if (bm >= Msplit) { Bh = Bh2; Bl = Bl2; }

    f32x4 acc[4][4];
    #pragma unroll
    for (int i = 0; i < 4; i++)
        #pragma unroll
        for (int j = 0; j < 4; j++)
            acc[i][j] = (f32x4)(0.0f);

    for (int k0 = 0; k0 < Kp; k0 += 32) {
        stage16(A + (long long)(bm + sr) * lda + k0 + sc, true, 0, 1 << 30,
                &AsH[sr][sc], &AsL[sr][sc]);
        {
            uint4 wh0 = make_uint4(0,0,0,0), wh1 = make_uint4(0,0,0,0);
            uint4 wl0 = make_uint4(0,0,0,0), wl1 = make_uint4(0,0,0,0);
            const int gn = bn + sr;
            if (gn < N) {
                const long long br = (long long)gn * ldb + k0 + sc;
                wh0 = *(const uint4*)(Bh + br);
                wh1 = *(const uint4*)(Bh + br + 8);
                wl0 = *(const uint4*)(Bl + br);
                wl1 = *(const uint4*)(Bl + br + 8);
            }
            *(uint4*)&BsH[sr][sc]     = wh0;
            *(uint4*)&BsH[sr][sc + 8] = wh1;
            *(uint4*)&BsL[sr][sc]     = wl0;
            *(uint4*)&BsL[sr][sc + 8] = wl1;
        }
        __syncthreads();

        bf16x8 fah[4], fal[4], fbh[4], fbl[4];
        #pragma unroll
        for (int i = 0; i < 4; i++) {
            fah[i] = *(const bf16x8*)&AsH[wm + i * 16 + lr][quad * 8];
            fal[i] = *(const bf16x8*)&AsL[wm + i * 16 + lr][quad * 8];
            fbh[i] = *(const bf16x8*)&BsH[wn + i * 16 + lr][quad * 8];
            fbl[i] = *(const bf16x8*)&BsL[wn + i * 16 + lr][quad * 8];
        }
        #pragma unroll
        for (int i = 0; i < 4; i++)
            #pragma unroll
            for (int j = 0; j < 4; j++) { MFMA3(i, j) }
        __syncthreads();
    }

    const int sz = PO ? sizes[bm >> 7] : 0;
    float ps[4] = {0.f, 0.f, 0.f, 0.f};
    #pragma unroll
    for (int j = 0; j < 4; j++) {
        const int gn = bn + wn + j * 16 + lr;
        const bool gok = gn < N;
        #pragma unroll
        for (int i = 0; i < 4; i++) {
            #pragma unroll
            for (int r = 0; r < 4; r++) {
                const int row = wm + i * 16 + quad * 4 + r;
                const int gm = bm + row;
                float v = acc[i][j][r];
                if (flags & F_RELU) v = fmaxf(v, 0.f);
                if (gok && C) C[(long long)gm * ldc + gn] = v;
                if (PO && row < sz) ps[j] += v;
            }
        }
    }
    if (PO) {
        #pragma unroll
        for (int j = 0; j < 4; j++) {
            ps[j] += __shfl_xor(ps[j], 16);
            ps[j] += __shfl_xor(ps[j], 32);
        }
        float* PS = (float*)AsH;
        if (wm == 0 && quad == 0) {
            #pragma unroll
            for (int j = 0; j < 4; j++) PS[wn + j * 16 + lr] = ps[j];
        }
        __syncthreads();
        if (wm == 64 && quad == 0) {
            #pragma unroll
            for (int j = 0; j < 4; j++) PS[wn + j * 16 + lr] += ps[j];
        }
        __syncthreads();
        if (tid < 128) {
            const int gn = bn + tid;
            if (gn < N) PO[(long long)(bm >> 7) * N + gn] = PS[tid];
        }
    }
}

// ---------------------------------------------------------------------------
// Batched split-bf16 MFMA GEMM, NT, both operands fp32->hi/lo in staging.
// MODE 0: plain (ACCUM/RELU; optional sizes mask; optional PT transposed
//         store, may alias B; (Aalt,Balt) for bz>=256 with bz-256).
// MODE 1: att — dist-bias (|i-j|>=10) + fused row softmax -> C (probs).
// ---------------------------------------------------------------------------
template <int MODE>
__global__ __launch_bounds__(256) void gemm_bat(
    const float* __restrict__ A, const float* __restrict__ Aalt,
    const float* __restrict__ B, const float* __restrict__ Balt,
    float* __restrict__ C, float* __restrict__ PT,
    int N, int Kvalid, int Kp, int lda, int ldb, int ldc,
    long long sA, long long sB, long long sC, long long sPT,
    int flags, const float* __restrict__ bias_ptr, const int* __restrict__ sizes,
    int same_ab)
{
    constexpr int SB = (MODE == 1) ? 65536 : 40960;
    __shared__ __align__(16) unsigned char smem[SB];
    u16 (*AsH)[40] = (u16(*)[40])(smem);
    u16 (*AsL)[40] = (u16(*)[40])(smem + 10240);
    u16 (*BsH)[40] = (u16(*)[40])(smem + 20480);
    u16 (*BsL)[40] = (u16(*)[40])(smem + 30720);

    const int bz = blockIdx.z;
    long long zb = bz;
    const float* Ause = A;
    const float* Buse = B;
    if (Aalt && bz >= BATCH) { Ause = Aalt; Buse = Balt; zb = bz - BATCH; }
    Ause += zb * sA;
    Buse += zb * sB;
    C += (long long)bz * sC;
    if (PT) PT += (long long)bz * sPT;

    const int tid  = threadIdx.x;
    const int bn   = blockIdx.x * 128;
    const int wave = tid >> 6;
    const int lane = tid & 63;
    const int wm   = (wave >> 1) * 64;
    const int wn   = (wave & 1) * 64;
    const int lr   = lane & 15;
    const int quad = lane >> 4;
    const int sr   = tid >> 1;
    const int sc   = (tid & 1) * 16;

    f32x4 acc[4][4];
    #pragma unroll
    for (int i = 0; i < 4; i++)
        #pragma unroll
        for (int j = 0; j < 4; j++)
            acc[i][j] = (f32x4)(0.0f);

    u16 (*fbH)[40] = same_ab ? AsH : BsH;
    u16 (*fbL)[40] = same_ab ? AsL : BsL;

    for (int k0 = 0; k0 < Kp; k0 += 32) {
        stage16(Ause + (long long)sr * lda + k0 + sc, true, k0 + sc, Kvalid,
                &AsH[sr][sc], &AsL[sr][sc]);
        if (!same_ab) {
            const int gn = bn + sr;
            stage16(Buse + (long long)gn * ldb + k0 + sc, gn < N, k0 + sc, Kvalid,
                    &BsH[sr][sc], &BsL[sr][sc]);
        }
        __syncthreads();

        bf16x8 fah[4], fal[4], fbh[4], fbl[4];
        #pragma unroll
        for (int i = 0; i < 4; i++) {
            fah[i] = *(const bf16x8*)&AsH[wm + i * 16 + lr][quad * 8];
            fal[i] = *(const bf16x8*)&AsL[wm + i * 16 + lr][quad * 8];
            fbh[i] = *(const bf16x8*)&fbH[wn + i * 16 + lr][quad * 8];
            fbl[i] = *(const bf16x8*)&fbL[wn + i * 16 + lr][quad * 8];
        }
        #pragma unroll
        for (int i = 0; i < 4; i++)
            #pragma unroll
            for (int j = 0; j < 4; j++) { MFMA3(i, j) }
        __syncthreads();
    }

    if (MODE == 1) {
        float* S = (float*)smem;
        const float bias = bias_ptr[0];
        #pragma unroll
        for (int i = 0; i < 4; i++) {
            #pragma unroll
            for (int j = 0; j < 4; j++) {
                const int col = wn + j * 16 + lr;
                #pragma unroll
                for (int r = 0; r < 4; r++) {
                    const int row = wm + i * 16 + quad * 4 + r;
                    int d = row - col; d = d < 0 ? -d : d;
                    S[row * 128 + col] = acc[i][j][r] + ((d >= 10) ? bias : 0.f);
                }
            }
        }
        __syncthreads();
        const int row = tid >> 1;
        const int half = (tid & 1) * 64;
        float mx = -1e30f;
        for (int c = 0; c < 64; c++) mx = fmaxf(mx, S[row * 128 + half + c]);
        mx = fmaxf(mx, __shfl_xor(mx, 1));
        float sum = 0.f;
        for (int c = 0; c < 64; c++) sum += __expf(S[row * 128 + half + c] - mx);
        sum += __shfl_xor(sum, 1);
        const float inv = 1.f / sum;
        for (int c = 0; c < 64; c++)
            C[(long long)row * ldc + half + c] = __expf(S[row * 128 + half + c] - mx) * inv;
    } else {
        const int s1 = sizes ? sizes[bz] : SEQ;
        const int s2 = sizes ? sizes[BATCH + bz] : SEQ;
        #pragma unroll
        for (int i = 0; i < 4; i++) {
            #pragma unroll
            for (int j = 0; j < 4; j++) {
                const int gn = bn + wn + j * 16 + lr;
                if (gn >= N) continue;
                #pragma unroll
                for (int r = 0; r < 4; r++) {
                    const int gm = wm + i * 16 + quad * 4 + r;
                    float v = acc[i][j][r];
                    if (sizes && (gm >= s1 || gn >= s2)) v = 0.f;
                    if (flags & F_ACCUM) v += C[(long long)gm * ldc + gn];
                    if (flags & F_RELU)  v = fmaxf(v, 0.f);
                    C[(long long)gm * ldc + gn] = v;
                    if (PT) PT[(long long)gn * 128 + gm] = v;
                }
            }
        }
    }
}

// One block per batch: sim tile to LDS, row softmax in-place, col softmax
// transposed -> smt.
__global__ __launch_bounds__(256) void softmax_both(float* __restrict__ sim,
                                                    float* __restrict__ smt)
{
    __shared__ float S[128 * 128];
    const int b = blockIdx.x;
    const int tid = threadIdx.x;
    float* sp = sim + (long long)b * (SEQ * SEQ);
    float* qp = smt + (long long)b * (SEQ * SEQ);
    #pragma unroll
    for (int it = 0; it < 16; it++) {
        const int i4 = it * 256 + tid;
        ((float4*)S)[i4] = ((const float4*)sp)[i4];
    }
    __syncthreads();
    const int idx = tid >> 1;
    const int half = (tid & 1) * 64;
    {
        float mx = -1e30f;
        for (int c = 0; c < 64; c++) mx = fmaxf(mx, S[idx * 128 + half + c]);
        mx = fmaxf(mx, __shfl_xor(mx, 1));
        float sum = 0.f;
        for (int c = 0; c < 64; c++) sum += __expf(S[idx * 128 + half + c] - mx);
        sum += __shfl_xor(sum, 1);
        const float inv = 1.f / sum;
        for (int c = 0; c < 64; c++)
            sp[idx * 128 + half + c] = __expf(S[idx * 128 + half + c] - mx) * inv;
    }
    {
        float mx = -1e30f;
        for (int r = 0; r < 64; r++) mx = fmaxf(mx, S[(half + r) * 128 + idx]);
        mx = fmaxf(mx, __shfl_xor(mx, 1));
        float sum = 0.f;
        for (int r = 0; r < 64; r++) sum += __expf(S[(half + r) * 128 + idx] - mx);
        sum += __shfl_xor(sum, 1);
        const float inv = 1.f / sum;
        for (int r = 0; r < 64; r++)
            qp[idx * 128 + half + r] = __expf(S[(half + r) * 128 + idx] - mx) * inv;
    }
}

// All weight transposes + hi/lo splits in one launch.
struct WEnt { const float* src; u16* H; u16* L; int K, N, Kp, rowStart; };
struct WTab { WEnt e[11]; };
__global__ void convert_all(WTab t)
{
    const int row = blockIdx.y;
    const int k = blockIdx.x * 256 + threadIdx.x;
    #pragma unroll
    for (int s = 0; s < 11; s++) {
        const WEnt w = t.e[s];
        if (row >= w.rowStart && row < w.rowStart + w.N) {
            const int n = row - w.rowStart;
            if (k < w.Kp) {
                const float v = (k < w.K) ? w.src[(long long)k * w.N + n] : 0.f;
                const u16 h = f2bf(v);
                w.H[(long long)n * w.Kp + k] = h;
                w.L[(long long)n * w.Kp + k] = f2bf(v - bf2f(h));
            }
            return;
        }
    }
}

__global__ void norms_kernel(const float* __restrict__ emb, float* __restrict__ norms)
{
    const int r = blockIdx.x;
    const int lane = threadIdx.x;
    const float* row = emb + (long long)r * EDIM;
    float ss = 0.f;
    #pragma unroll
    for (int i = 0; i < 5; i++) {
        const int c = lane + i * 64;
        const float f = (c < EDIM) ? row[c] : 0.f;
        ss += f * f;
    }
    #pragma unroll
    for (int o = 32; o > 0; o >>= 1) ss += __shfl_xor(ss, o);
    if (lane == 0) norms[r] = rsqrtf(fmaxf(ss, 1e-12f));
}

__global__ void sizes_kernel(const int* __restrict__ x1, const int* __restrict__ x2,
                             int* __restrict__ sizes)
{
    const int b = blockIdx.x;
    const int side = blockIdx.y;
    const int* x = (side ? x2 : x1) + b * SEQ;
    const int nz = (x[threadIdx.x] != 0) ? 1 : 0;
    const unsigned long long bal = __ballot(nz);
    __shared__ int part[2];
    if ((threadIdx.x & 63) == 0) part[threadIdx.x >> 6] = __popcll(bal);
    __syncthreads();
    if (threadIdx.x == 0) sizes[side * BATCH + b] = part[0] + part[1];
}

__global__ void agg_kernel(const float* __restrict__ v1s, const float* __restrict__ v2s,
                           const float* __restrict__ w_agg, float* __restrict__ y)
{
    const int b = blockIdx.x;
    const int lane = threadIdx.x;
    float a0 = 0.f, a1 = 0.f, a2 = 0.f;
    for (int k = lane; k < 800; k += 64) {
        const float v = (k < 400) ? v1s[b * 400 + k] : v2s[b * 400 + k - 400];
        a0 = fmaf(v, w_agg[k * 3 + 0], a0);
        a1 = fmaf(v, w_agg[k * 3 + 1], a1);
        a2 = fmaf(v, w_agg[k * 3 + 2], a2);
    }
    #pragma unroll
    for (int o = 32; o > 0; o >>= 1) {
        a0 += __shfl_xor(a0, o);
        a1 += __shfl_xor(a1, o);
        a2 += __shfl_xor(a2, o);
    }
    if (lane == 0) {
        y[b * 3 + 0] = fmaxf(a0, 0.f);
        y[b * 3 + 1] = fmaxf(a1, 0.f);
        y[b * 3 + 2] = fmaxf(a2, 0.f);
    }
}

extern "C" void kernel_launch(void* const* d_in, const int* in_sizes, int n_in,
                              void* d_out, int out_size, void* d_ws, size_t ws_size,
                              hipStream_t stream)
{
    (void)in_sizes; (void)n_in; (void)out_size; (void)ws_size;
    const int*   x1         = (const int*)d_in[0];
    const int*   x2         = (const int*)d_in[1];
    const float* emb        = (const float*)d_in[2];
    const float* w_intra    = (const float*)d_in[3];
    const float* bias_intra = (const float*)d_in[4];
    const float* w_proj1    = (const float*)d_in[5];
    const float* w_proj2    = (const float*)d_in[6];
    const float* w_att      = (const float*)d_in[7];
    const float* w_cmp1     = (const float*)d_in[8];
    const float* w_cmp2     = (const float*)d_in[9];
    const float* w_agg      = (const float*)d_in[10];
    float* y  = (float*)d_out;
    float* ws = (float*)d_ws;

    // ---- workspace (floats); total ~58.64M fl = 234.6 MB ----
    float* X1CAT = ws;                        // [32768,400]: x1p | beta
    float* X2CAT = X1CAT + 13107200;          // [32768,400]: x2p | alpha (contig)
    float* T     = X2CAT + 13107200;          // [512,200,128]: G^T -> x_proj^T
    float* FBUF  = T + 13107200;              // [32768,300] intra f (phase A)
    float* ATT   = FBUF + 9830400;            // [512,128,128] probs
    float* POOL  = ATT + 8388608;             // [512,400] pooled v1|v2
    int*   SIZES = (int*)(POOL + 204800);     // [2,256] + pad
    float* NORMS = (float*)(SIZES + 512);     // [32000] + pad
    u16*   W1H   = (u16*)(NORMS + 32768);     // side-1 stack [556][320]: wp_b|z56|intra
    u16*   W1L   = W1H + 177920;
    u16*   W2H   = W1L + 177920;              // side-2 stack [556][320]
    u16*   W2L   = W2H + 177920;
    u16*   WAH   = W2L + 177920;              // w_att^T  [200][224]
    u16*   WAL   = WAH + 44800;
    u16*   WC1H  = WAL + 44800;               // w_cmp1^T [400][416]
    u16*   WC1L  = WC1H + 166400;
    u16*   WC2H  = WC1L + 166400;
    u16*   WC2L  = WC2H + 166400;
    u16*   WPA1H = WC2L + 166400;             // wp_a side1 [200][320]
    u16*   WPA1L = WPA1H + 64000;
    u16*   WPA2H = WPA1L + 64000;
    u16*   WPA2L = WPA2H + 64000;

    // phase-B aliases over FBUF+ATT-head (F12 dead before SMT written)
    float* F12 = FBUF;                        // [65536,200] f1|f2
    float* F2  = FBUF + 6553600;
    float* SIM = FBUF + 13107200;             // [256,128,128] (ATT tail, no F12 overlap)
    float* SMT = FBUF;                        // [256,128,128] (over F12 after dead)
    float* T1  = T;
    float* T2  = T + 6553600;

    const long long sbSS = (long long)SEQ * SEQ;     // 16384
    const long long sbF  = (long long)SEQ * EDIM;    // 38400
    const long long sbP  = (long long)SEQ * PDIM;    // 25600
    const long long sbC  = (long long)SEQ * 400;     // 51200
    const long long sbT  = (long long)PDIM * SEQ;    // 25600

    sizes_kernel<<<dim3(BATCH, 2), 128, 0, stream>>>(x1, x2, SIZES);
    norms_kernel<<<32000, 64, 0, stream>>>(emb, NORMS);

    {
        WTab t;
        t.e[0]  = { w_proj1 + 300 * 200, W1H,             W1L,             300, 200, 320, 0    };
        t.e[1]  = { w_intra,             W1H + 200 * 320, W1L + 200 * 320,   0,  56, 320, 200  };
        t.e[2]  = { w_intra,             W1H + 256 * 320, W1L + 256 * 320, 300, 300, 320, 256  };
        t.e[3]  = { w_proj2 + 300 * 200, W2H,             W2L,             300, 200, 320, 556  };
        t.e[4]  = { w_intra,             W2H + 200 * 320, W2L + 200 * 320,   0,  56, 320, 756  };
        t.e[5]  = { w_intra,             W2H + 256 * 320, W2L + 256 * 320, 300, 300, 320, 812  };
        t.e[6]  = { w_att,               WAH,             WAL,             200, 200, 224, 1112 };
        t.e[7]  = { w_cmp1,              WC1H,            WC1L,            400, 400, 416, 1312 };
        t.e[8]  = { w_cmp2,              WC2H,            WC2L,            400, 400, 416, 1712 };
        t.e[9]  = { w_proj1,             WPA1H,           WPA1L,           300, 200, 320, 2112 };
        t.e[10] = { w_proj2,             WPA2H,           WPA2L,           300, 200, 320, 2312 };
        convert_all<<<dim3(2, 2512), 256, 0, stream>>>(t);
    }

    // -------- phase A --------
    for (int side = 0; side < 2; side++) {
        const int* x = side ? x2 : x1;
        float* Ts    = side ? T2 : T1;
        u16* WH = side ? W2H : W1H;
        u16* WL = side ? W2L : W1L;

        // fused: Ts = (e@wp_b)^T (coalesced), FBUF = relu(e@w_intra)
        gemm_proj<<<dim3(5, 256), 256, 0, stream>>>(x, emb, NORMS, WH, WL, Ts, FBUF);
        // probs = rowsoftmax(f f^T + dbias) -> ATT[side*256 ..]
        gemm_bat<1><<<dim3(1, 1, BATCH), 256, 0, stream>>>(
            FBUF, nullptr, FBUF, nullptr, ATT + (long long)side * BATCH * sbSS, nullptr,
            SEQ, EDIM, 320, EDIM, EDIM, SEQ, sbF, sbF, sbSS, 0,
            0, bias_intra, nullptr, 1);
    }
    // fused xp: XCAT[:,0:200] = relu(e@wp_a + probs@G); x_proj^T in-place -> T
    gemm_xp<<<dim3(2, 1, 2 * BATCH), 256, 0, stream>>>(
        ATT, T, x1, x2, emb, NORMS, WPA1H, WPA1L, WPA2H, WPA2L, X1CAT);

    // -------- phase B --------
    // f1|f2 = relu(x_proj @ w_att)   [M=65536; A cols 200:224 garbage*0]
    gemm_flat<<<dim3(2, 512), 256, 0, stream>>>(
        X1CAT, WAH, WAL, WAH, WAL, 1 << 30, F12, nullptr, nullptr,
        2 * BSTOK, PDIM, 224, 400, 224, PDIM, F_RELU);
    // sim = mask(f1 f2^T)
    gemm_bat<0><<<dim3(1, 1, BATCH), 256, 0, stream>>>(
        F12, nullptr, F2, nullptr, SIM, nullptr,
        SEQ, PDIM, 224, PDIM, PDIM, SEQ, sbP, sbP, sbSS, 0,
        0, nullptr, SIZES, 0);
    softmax_both<<<BATCH, 256, 0, stream>>>(SIM, SMT);
    // beta (bz<256) / alpha (bz>=256) -> X1CAT/X2CAT cols 200:400
    gemm_bat<0><<<dim3(2, 1, 2 * BATCH), 256, 0, stream>>>(
        SIM, SMT, T2, T1, X1CAT + 200, nullptr,
        PDIM, SEQ, SEQ, SEQ, SEQ, 400, sbSS, sbT, sbC, 0,
        0, nullptr, nullptr, 0);

    // -------- phase C: fused compare + masked pool, aggregate --------
    gemm_flat<<<dim3(4, 512), 256, 0, stream>>>(
        X1CAT, WC1H, WC1L, WC2H, WC2L, BSTOK,
        nullptr, POOL, SIZES,
        2 * BSTOK, 400, 416, 400, 416, 400, F_RELU);
    agg_kernel<<<BATCH, 64, 0, stream>>>(POOL, POOL + 102400, w_agg, y);
}

// Round 9
// 563.246 us; speedup vs baseline: 3.2447x; 1.0858x over previous
//
#include <hip/hip_runtime.h>

#define BATCH 256
#define SEQ   128
#define EDIM  300
#define PDIM  200
#define BSTOK (BATCH * SEQ)

#define F_RELU  1
#define F_ACCUM 2

typedef unsigned short u16;
typedef __attribute__((ext_vector_type(8))) short bf16x8;
typedef __attribute__((ext_vector_type(4))) float f32x4;

__device__ __forceinline__ u16 f2bf(float x) {
    unsigned u = __float_as_uint(x);
    unsigned r = u + 0x7fffu + ((u >> 16) & 1u);
    return (u16)(r >> 16);
}
__device__ __forceinline__ float bf2f(u16 h) {
    return __uint_as_float(((unsigned)h) << 16);
}

// split 16 fp32 -> hi(trunc)/lo(residual) bf16, store 2 x uint4 each.
__device__ __forceinline__ void split_store(const float* va, u16* dH, u16* dL)
{
    unsigned hp[8], lp[8];
    #pragma unroll
    for (int i = 0; i < 8; i++) {
        const unsigned u0 = __float_as_uint(va[2 * i]);
        const unsigned u1 = __float_as_uint(va[2 * i + 1]);
        const unsigned h0 = u0 & 0xffff0000u;
        const unsigned h1 = u1 & 0xffff0000u;
        hp[i] = (u0 >> 16) | h1;
        const float r0 = va[2 * i]     - __uint_as_float(h0);
        const float r1 = va[2 * i + 1] - __uint_as_float(h1);
        lp[i] = (__float_as_uint(r0) >> 16) | (__float_as_uint(r1) & 0xffff0000u);
    }
    ((uint4*)dH)[0] = make_uint4(hp[0], hp[1], hp[2], hp[3]);
    ((uint4*)dH)[1] = make_uint4(hp[4], hp[5], hp[6], hp[7]);
    ((uint4*)dL)[0] = make_uint4(lp[0], lp[1], lp[2], lp[3]);
    ((uint4*)dL)[1] = make_uint4(lp[4], lp[5], lp[6], lp[7]);
}

__device__ __forceinline__ void stage16(const float* __restrict__ src, bool row_ok,
                                        int kbase, int Kvalid, u16* dH, u16* dL)
{
    float va[16];
    if (row_ok) {
        #pragma unroll
        for (int i = 0; i < 4; i++) {
            const float4 v = *(const float4*)(src + i * 4);
            va[i * 4 + 0] = v.x; va[i * 4 + 1] = v.y;
            va[i * 4 + 2] = v.z; va[i * 4 + 3] = v.w;
        }
        #pragma unroll
        for (int i = 0; i < 16; i++)
            va[i] = (kbase + i < Kvalid) ? va[i] : 0.f;
    } else {
        #pragma unroll
        for (int i = 0; i < 16; i++) va[i] = 0.f;
    }
    split_store(va, dH, dL);
}

// Gathered-embedding staging: va = emb_row[kb..kb+15] * nrm, zero k >= 300.
__device__ __forceinline__ void stage_gather(const float* __restrict__ erow, float nrm,
                                             int kb, u16* dH, u16* dL)
{
    float va[16];
    if (kb + 16 <= EDIM) {
        #pragma unroll
        for (int i = 0; i < 4; i++) {
            const float4 v = *(const float4*)(erow + kb + i * 4);
            va[i * 4 + 0] = v.x; va[i * 4 + 1] = v.y;
            va[i * 4 + 2] = v.z; va[i * 4 + 3] = v.w;
        }
    } else {
        #pragma unroll
        for (int i = 0; i < 16; i++)
            va[i] = (kb + i < EDIM) ? erow[kb + i] : 0.f;
    }
    #pragma unroll
    for (int i = 0; i < 16; i++) va[i] *= nrm;
    split_store(va, dH, dL);
}

#define MFMA3(ai, aj) \
    acc[ai][aj] = __builtin_amdgcn_mfma_f32_16x16x32_bf16(fah[ai], fbh[aj], acc[ai][aj], 0, 0, 0); \
    acc[ai][aj] = __builtin_amdgcn_mfma_f32_16x16x32_bf16(fah[ai], fbl[aj], acc[ai][aj], 0, 0, 0); \
    acc[ai][aj] = __builtin_amdgcn_mfma_f32_16x16x32_bf16(fal[ai], fbh[aj], acc[ai][aj], 0, 0, 0);

// Coalesced transposed store of the block's 128x128 tile via LDS (stride 129).
__device__ __forceinline__ void store_transposed(
    float* __restrict__ PT, const f32x4 (*acc)[4], float* TR,
    int bn, int Nvalid, int wm, int wn, int lr, int quad, int tid, bool relu)
{
    #pragma unroll
    for (int h = 0; h < 2; h++) {
        __syncthreads();
        if ((wn >> 6) == h) {
            #pragma unroll
            for (int j = 0; j < 4; j++) {
                const int col = j * 16 + lr;
                #pragma unroll
                for (int i = 0; i < 4; i++)
                    #pragma unroll
                    for (int r = 0; r < 4; r++) {
                        float v = acc[i][j][r];
                        if (relu) v = fmaxf(v, 0.f);
                        TR[col * 129 + wm + i * 16 + quad * 4 + r] = v;
                    }
            }
        }
        __syncthreads();
        const int row = tid >> 2;
        const int gp = bn + h * 64 + row;
        if (gp < Nvalid) {
            float* dst = PT + (long long)gp * 128;
            for (int c = (tid & 3); c < 32; c += 4) {
                const int base = row * 129 + c * 4;
                *(float4*)(dst + c * 4) =
                    make_float4(TR[base], TR[base + 1], TR[base + 2], TR[base + 3]);
            }
        }
    }
}

// ---------------------------------------------------------------------------
// Merged phase-A projection GEMM (both sides, grid (5, 512), XCD-swizzled):
//   m-tile mt in [0,512): side = mt >= 256; A row = l2norm-emb of that side's
//   token (gathered in staging).
//   B = per-side stack [556][320]: rows 0:200 wp_b | 200:256 zero | 256:556 intra
//   bn < 256  -> T[mt][gn][.] (transposed coalesced, gn < 200)
//   bn >= 256 -> Fside[row][gn-256] relu (gn-256 < 300)
// ---------------------------------------------------------------------------
__global__ __launch_bounds__(256) void gemm_proj(
    const int* __restrict__ x1, const int* __restrict__ x2,
    const float* __restrict__ emb, const float* __restrict__ norms,
    const u16* __restrict__ W1h, const u16* __restrict__ W1l,
    const u16* __restrict__ W2h, const u16* __restrict__ W2l,
    float* __restrict__ T, float* __restrict__ F0, float* __restrict__ F1)
{
    __shared__ __align__(16) unsigned char smem[40960];
    u16 (*AsH)[40] = (u16(*)[40])(smem);
    u16 (*AsL)[40] = (u16(*)[40])(smem + 10240);
    u16 (*BsH)[40] = (u16(*)[40])(smem + 20480);
    u16 (*BsL)[40] = (u16(*)[40])(smem + 30720);

    const int tid = threadIdx.x;
    const int id  = blockIdx.y * 5 + blockIdx.x;
    const int xcd = id & 7;
    const int s   = id >> 3;
    const int mt  = xcd + 8 * (s / 5);     // 0..511
    const int bm  = mt * 128;
    const int bn  = (s % 5) * 128;
    const bool side2 = mt >= 256;

    const u16* Bh = side2 ? W2h : W1h;
    const u16* Bl = side2 ? W2l : W1l;
    float* F = side2 ? F1 : F0;
    const int fm = side2 ? bm - 32768 : bm;
    const int* toks = (side2 ? x2 - 32768 : x1) + bm;

    const int wave = tid >> 6;
    const int lane = tid & 63;
    const int wm   = (wave >> 1) * 64;
    const int wn   = (wave & 1) * 64;
    const int lr   = lane & 15;
    const int quad = lane >> 4;
    const int sr   = tid >> 1;
    const int sc   = (tid & 1) * 16;

    const int tok = toks[sr];
    const float nrm = norms[tok];
    const float* erow = emb + (long long)tok * EDIM;

    f32x4 acc[4][4];
    #pragma unroll
    for (int i = 0; i < 4; i++)
        #pragma unroll
        for (int j = 0; j < 4; j++)
            acc[i][j] = (f32x4)(0.0f);

    for (int k0 = 0; k0 < 320; k0 += 32) {
        stage_gather(erow, nrm, k0 + sc, &AsH[sr][sc], &AsL[sr][sc]);
        {
            uint4 wh0 = make_uint4(0,0,0,0), wh1 = make_uint4(0,0,0,0);
            uint4 wl0 = make_uint4(0,0,0,0), wl1 = make_uint4(0,0,0,0);
            const int gn = bn + sr;
            if (gn < 556) {
                const long long br = (long long)gn * 320 + k0 + sc;
                wh0 = *(const uint4*)(Bh + br);
                wh1 = *(const uint4*)(Bh + br + 8);
                wl0 = *(const uint4*)(Bl + br);
                wl1 = *(const uint4*)(Bl + br + 8);
            }
            *(uint4*)&BsH[sr][sc]     = wh0;
            *(uint4*)&BsH[sr][sc + 8] = wh1;
            *(uint4*)&BsL[sr][sc]     = wl0;
            *(uint4*)&BsL[sr][sc + 8] = wl1;
        }
        __syncthreads();

        bf16x8 fah[4], fal[4], fbh[4], fbl[4];
        #pragma unroll
        for (int i = 0; i < 4; i++) {
            fah[i] = *(const bf16x8*)&AsH[wm + i * 16 + lr][quad * 8];
            fal[i] = *(const bf16x8*)&AsL[wm + i * 16 + lr][quad * 8];
            fbh[i] = *(const bf16x8*)&BsH[wn + i * 16 + lr][quad * 8];
            fbl[i] = *(const bf16x8*)&BsL[wn + i * 16 + lr][quad * 8];
        }
        #pragma unroll
        for (int i = 0; i < 4; i++)
            #pragma unroll
            for (int j = 0; j < 4; j++) { MFMA3(i, j) }
        __syncthreads();
    }

    if (bn < 256) {
        float* Tb = T + (long long)mt * (PDIM * SEQ);
        store_transposed(Tb, acc, (float*)smem, bn, PDIM, wm, wn, lr, quad, tid, false);
    } else {
        #pragma unroll
        for (int i = 0; i < 4; i++) {
            #pragma unroll
            for (int j = 0; j < 4; j++) {
                const int idx = bn + wn + j * 16 + lr - 256;
                if (idx >= EDIM) continue;
                #pragma unroll
                for (int r = 0; r < 4; r++) {
                    const int gm = fm + wm + i * 16 + quad * 4 + r;
                    F[(long long)gm * EDIM + idx] = fmaxf(acc[i][j][r], 0.f);
                }
            }
        }
    }
}

// ---------------------------------------------------------------------------
// Fused xp GEMM: acc = e @ wp_a (flat, K=320, gathered A) + probs @ G (batched,
// K=128); out = relu(acc) -> XCAT (cols 0:200) + transposed in-place over T.
// grid (2, 1, 512).
// ---------------------------------------------------------------------------
__global__ __launch_bounds__(256) void gemm_xp(
    const float* __restrict__ P, float* __restrict__ T,
    const int* __restrict__ x1, const int* __restrict__ x2,
    const float* __restrict__ emb, const float* __restrict__ norms,
    const u16* __restrict__ W1h, const u16* __restrict__ W1l,
    const u16* __restrict__ W2h, const u16* __restrict__ W2l,
    float* __restrict__ XCAT)
{
    __shared__ __align__(16) unsigned char smem[40960];
    u16 (*AsH)[40] = (u16(*)[40])(smem);
    u16 (*AsL)[40] = (u16(*)[40])(smem + 10240);
    u16 (*BsH)[40] = (u16(*)[40])(smem + 20480);
    u16 (*BsL)[40] = (u16(*)[40])(smem + 30720);

    const int tid = threadIdx.x;
    const int bz  = blockIdx.z;
    const int bn  = blockIdx.x * 128;

    const int wave = tid >> 6;
    const int lane = tid & 63;
    const int wm   = (wave >> 1) * 64;
    const int wn   = (wave & 1) * 64;
    const int lr   = lane & 15;
    const int quad = lane >> 4;
    const int sr   = tid >> 1;
    const int sc   = (tid & 1) * 16;

    const int* toks = (bz < BATCH) ? x1 + bz * SEQ : x2 + (bz - BATCH) * SEQ;
    const u16* Wh = (bz < BATCH) ? W1h : W2h;
    const u16* Wl = (bz < BATCH) ? W1l : W2l;
    const int tok = toks[sr];
    const float nrm = norms[tok];
    const float* erow = emb + (long long)tok * EDIM;
    const float* Pb = P + (long long)bz * (SEQ * SEQ);
    float* Tb = T + (long long)bz * (PDIM * SEQ);

    f32x4 acc[4][4];
    #pragma unroll
    for (int i = 0; i < 4; i++)
        #pragma unroll
        for (int j = 0; j < 4; j++)
            acc[i][j] = (f32x4)(0.0f);

    for (int k0 = 0; k0 < 320; k0 += 32) {
        stage_gather(erow, nrm, k0 + sc, &AsH[sr][sc], &AsL[sr][sc]);
        {
            uint4 wh0 = make_uint4(0,0,0,0), wh1 = make_uint4(0,0,0,0);
            uint4 wl0 = make_uint4(0,0,0,0), wl1 = make_uint4(0,0,0,0);
            const int gn = bn + sr;
            if (gn < PDIM) {
                const long long br = (long long)gn * 320 + k0 + sc;
                wh0 = *(const uint4*)(Wh + br);
                wh1 = *(const uint4*)(Wh + br + 8);
                wl0 = *(const uint4*)(Wl + br);
                wl1 = *(const uint4*)(Wl + br + 8);
            }
            *(uint4*)&BsH[sr][sc]     = wh0;
            *(uint4*)&BsH[sr][sc + 8] = wh1;
            *(uint4*)&BsL[sr][sc]     = wl0;
            *(uint4*)&BsL[sr][sc + 8] = wl1;
        }
        __syncthreads();

        bf16x8 fah[4], fal[4], fbh[4], fbl[4];
        #pragma unroll
        for (int i = 0; i < 4; i++) {
            fah[i] = *(const bf16x8*)&AsH[wm + i * 16 + lr][quad * 8];
            fal[i] = *(const bf16x8*)&AsL[wm + i * 16 + lr][quad * 8];
            fbh[i] = *(const bf16x8*)&BsH[wn + i * 16 + lr][quad * 8];
            fbl[i] = *(const bf16x8*)&BsL[wn + i * 16 + lr][quad * 8];
        }
        #pragma unroll
        for (int i = 0; i < 4; i++)
            #pragma unroll
            for (int j = 0; j < 4; j++) { MFMA3(i, j) }
        __syncthreads();
    }

    for (int k0 = 0; k0 < 128; k0 += 32) {
        stage16(Pb + (long long)sr * 128 + k0 + sc, true, 0, 1 << 30,
                &AsH[sr][sc], &AsL[sr][sc]);
        const int gn = bn + sr;
        stage16(Tb + (long long)gn * 128 + k0 + sc, gn < PDIM, 0, 1 << 30,
                &BsH[sr][sc], &BsL[sr][sc]);
        __syncthreads();

        bf16x8 fah[4], fal[4], fbh[4], fbl[4];
        #pragma unroll
        for (int i = 0; i < 4; i++) {
            fah[i] = *(const bf16x8*)&AsH[wm + i * 16 + lr][quad * 8];
            fal[i] = *(const bf16x8*)&AsL[wm + i * 16 + lr][quad * 8];
            fbh[i] = *(const bf16x8*)&BsH[wn + i * 16 + lr][quad * 8];
            fbl[i] = *(const bf16x8*)&BsL[wn + i * 16 + lr][quad * 8];
        }
        #pragma unroll
        for (int i = 0; i < 4; i++)
            #pragma unroll
            for (int j = 0; j < 4; j++) { MFMA3(i, j) }
        __syncthreads();
    }

    const long long rowbase = (long long)bz * SEQ;
    #pragma unroll
    for (int i = 0; i < 4; i++) {
        #pragma unroll
        for (int j = 0; j < 4; j++) {
            const int gn = bn + wn + j * 16 + lr;
            if (gn >= PDIM) continue;
            #pragma unroll
            for (int r = 0; r < 4; r++) {
                const int gm = wm + i * 16 + quad * 4 + r;
                XCAT[(rowbase + gm) * 400 + gn] = fmaxf(acc[i][j][r], 0.f);
            }
        }
    }
    store_transposed(Tb, acc, (float*)smem, bn, PDIM, wm, wn, lr, quad, tid, true);
}

// ---------------------------------------------------------------------------
// Flat split-bf16 MFMA GEMM vs pre-split transposed weights. XCD-swizzled
// when gridDim.y % 8 == 0. Weight select per m-tile: bm >= Msplit -> B2.
// Outputs: C row-major (optional) and/or PO fused masked row-sum pool.
// ---------------------------------------------------------------------------
__global__ __launch_bounds__(256) void gemm_flat(
    const float* __restrict__ A,
    const u16* __restrict__ Bh, const u16* __restrict__ Bl,
    const u16* __restrict__ Bh2, const u16* __restrict__ Bl2, int Msplit,
    float* __restrict__ C, float* __restrict__ PO, const int* __restrict__ sizes,
    int M, int N, int Kp, int lda, int ldb, int ldc, int flags)
{
    __shared__ u16 AsH[128][40];
    __shared__ u16 AsL[128][40];
    __shared__ u16 BsH[128][40];
    __shared__ u16 BsL[128][40];

    const int tid = threadIdx.x;
    int bx = blockIdx.x, by = blockIdx.y;
    if ((gridDim.y & 7) == 0) {
        const int gx = gridDim.x;
        const int id = by * gx + bx;
        const int xcd = id & 7;
        const int s = id >> 3;
        by = xcd + 8 * (s / gx);
        bx = s % gx;
    }
    const int bm = by * 128;
    const int bn = bx * 128;

    const int wave = tid >> 6;
    const int lane = tid & 63;
    const int wm   = (wave >> 1) * 64;
    const int wn   = (wave & 1) * 64;
    const int lr   = lane & 15;
    const int quad = lane >> 4;
    const int sr   = tid >> 1;
    const int sc   = (tid & 1) * 16;

    if (bm >= Msplit) { Bh = Bh2; Bl = Bl2; }

    f32x4 acc[4][4];
    #pragma unroll
    for (int i = 0; i < 4; i++)
        #pragma unroll
        for (int j = 0; j < 4; j++)
            acc[i][j] = (f32x4)(0.0f);

    for (int k0 = 0; k0 < Kp; k0 += 32) {
        stage16(A + (long long)(bm + sr) * lda + k0 + sc, true, 0, 1 << 30,
                &AsH[sr][sc], &AsL[sr][sc]);
        {
            uint4 wh0 = make_uint4(0,0,0,0), wh1 = make_uint4(0,0,0,0);
            uint4 wl0 = make_uint4(0,0,0,0), wl1 = make_uint4(0,0,0,0);
            const int gn = bn + sr;
            if (gn < N) {
                const long long br = (long long)gn * ldb + k0 + sc;
                wh0 = *(const uint4*)(Bh + br);
                wh1 = *(const uint4*)(Bh + br + 8);
                wl0 = *(const uint4*)(Bl + br);
                wl1 = *(const uint4*)(Bl + br + 8);
            }
            *(uint4*)&BsH[sr][sc]     = wh0;
            *(uint4*)&BsH[sr][sc + 8] = wh1;
            *(uint4*)&BsL[sr][sc]     = wl0;
            *(uint4*)&BsL[sr][sc + 8] = wl1;
        }
        __syncthreads();

        bf16x8 fah[4], fal[4], fbh[4], fbl[4];
        #pragma unroll
        for (int i = 0; i < 4; i++) {
            fah[i] = *(const bf16x8*)&AsH[wm + i * 16 + lr][quad * 8];
            fal[i] = *(const bf16x8*)&AsL[wm + i * 16 + lr][quad * 8];
            fbh[i] = *(const bf16x8*)&BsH[wn + i * 16 + lr][quad * 8];
            fbl[i] = *(const bf16x8*)&BsL[wn + i * 16 + lr][quad * 8];
        }
        #pragma unroll
        for (int i = 0; i < 4; i++)
            #pragma unroll
            for (int j = 0; j < 4; j++) { MFMA3(i, j) }
        __syncthreads();
    }

    const int sz = PO ? sizes[bm >> 7] : 0;
    float ps[4] = {0.f, 0.f, 0.f, 0.f};
    #pragma unroll
    for (int j = 0; j < 4; j++) {
        const int gn = bn + wn + j * 16 + lr;
        const bool gok = gn < N;
        #pragma unroll
        for (int i = 0; i < 4; i++) {
            #pragma unroll
            for (int r = 0; r < 4; r++) {
                const int row = wm + i * 16 + quad * 4 + r;
                const int gm = bm + row;
                float v = acc[i][j][r];
                if (flags & F_RELU) v = fmaxf(v, 0.f);
                if (gok && C) C[(long long)gm * ldc + gn] = v;
                if (PO && row < sz) ps[j] += v;
            }
        }
    }
    if (PO) {
        #pragma unroll
        for (int j = 0; j < 4; j++) {
            ps[j] += __shfl_xor(ps[j], 16);
            ps[j] += __shfl_xor(ps[j], 32);
        }
        float* PS = (float*)AsH;
        if (wm == 0 && quad == 0) {
            #pragma unroll
            for (int j = 0; j < 4; j++) PS[wn + j * 16 + lr] = ps[j];
        }
        __syncthreads();
        if (wm == 64 && quad == 0) {
            #pragma unroll
            for (int j = 0; j < 4; j++) PS[wn + j * 16 + lr] += ps[j];
        }
        __syncthreads();
        if (tid < 128) {
            const int gn = bn + tid;
            if (gn < N) PO[(long long)(bm >> 7) * N + gn] = PS[tid];
        }
    }
}

// ---------------------------------------------------------------------------
// Batched split-bf16 MFMA GEMM, NT, both operands fp32->hi/lo in staging.
// MODE 0: plain (ACCUM/RELU; optional sizes mask; optional PT transposed
//         store; (Aalt,Balt) for bz>=256 with bz-256).
// MODE 1: att — dist-bias (|i-j|>=10) + fused row softmax -> C (probs).
// MODE 2: sim — sizes mask + row softmax -> C + col softmax^T -> PT.
//         C/PT may alias the block's own A/B slots (block-local WAR only).
// ---------------------------------------------------------------------------
template <int MODE>
__global__ __launch_bounds__(256) void gemm_bat(
    const float* __restrict__ A, const float* __restrict__ Aalt,
    const float* __restrict__ B, const float* __restrict__ Balt,
    float* __restrict__ C, float* __restrict__ PT,
    int N, int Kvalid, int Kp, int lda, int ldb, int ldc,
    long long sA, long long sB, long long sC, long long sPT,
    int flags, const float* __restrict__ bias_ptr, const int* __restrict__ sizes,
    int same_ab)
{
    constexpr int SB = (MODE >= 1) ? 65536 : 40960;
    __shared__ __align__(16) unsigned char smem[SB];
    u16 (*AsH)[40] = (u16(*)[40])(smem);
    u16 (*AsL)[40] = (u16(*)[40])(smem + 10240);
    u16 (*BsH)[40] = (u16(*)[40])(smem + 20480);
    u16 (*BsL)[40] = (u16(*)[40])(smem + 30720);

    const int bz = blockIdx.z;
    long long zb = bz;
    const float* Ause = A;
    const float* Buse = B;
    if (Aalt && bz >= BATCH) { Ause = Aalt; Buse = Balt; zb = bz - BATCH; }
    Ause += zb * sA;
    Buse += zb * sB;
    C += (long long)bz * sC;
    if (PT) PT += (long long)bz * sPT;

    const int tid  = threadIdx.x;
    const int bn   = blockIdx.x * 128;
    const int wave = tid >> 6;
    const int lane = tid & 63;
    const int wm   = (wave >> 1) * 64;
    const int wn   = (wave & 1) * 64;
    const int lr   = lane & 15;
    const int quad = lane >> 4;
    const int sr   = tid >> 1;
    const int sc   = (tid & 1) * 16;

    f32x4 acc[4][4];
    #pragma unroll
    for (int i = 0; i < 4; i++)
        #pragma unroll
        for (int j = 0; j < 4; j++)
            acc[i][j] = (f32x4)(0.0f);

    u16 (*fbH)[40] = same_ab ? AsH : BsH;
    u16 (*fbL)[40] = same_ab ? AsL : BsL;

    for (int k0 = 0; k0 < Kp; k0 += 32) {
        stage16(Ause + (long long)sr * lda + k0 + sc, true, k0 + sc, Kvalid,
                &AsH[sr][sc], &AsL[sr][sc]);
        if (!same_ab) {
            const int gn = bn + sr;
            stage16(Buse + (long long)gn * ldb + k0 + sc, gn < N, k0 + sc, Kvalid,
                    &BsH[sr][sc], &BsL[sr][sc]);
        }
        __syncthreads();

        bf16x8 fah[4], fal[4], fbh[4], fbl[4];
        #pragma unroll
        for (int i = 0; i < 4; i++) {
            fah[i] = *(const bf16x8*)&AsH[wm + i * 16 + lr][quad * 8];
            fal[i] = *(const bf16x8*)&AsL[wm + i * 16 + lr][quad * 8];
            fbh[i] = *(const bf16x8*)&fbH[wn + i * 16 + lr][quad * 8];
            fbl[i] = *(const bf16x8*)&fbL[wn + i * 16 + lr][quad * 8];
        }
        #pragma unroll
        for (int i = 0; i < 4; i++)
            #pragma unroll
            for (int j = 0; j < 4; j++) { MFMA3(i, j) }
        __syncthreads();
    }

    if (MODE == 1) {
        float* S = (float*)smem;
        const float bias = bias_ptr[0];
        #pragma unroll
        for (int i = 0; i < 4; i++) {
            #pragma unroll
            for (int j = 0; j < 4; j++) {
                const int col = wn + j * 16 + lr;
                #pragma unroll
                for (int r = 0; r < 4; r++) {
                    const int row = wm + i * 16 + quad * 4 + r;
                    int d = row - col; d = d < 0 ? -d : d;
                    S[row * 128 + col] = acc[i][j][r] + ((d >= 10) ? bias : 0.f);
                }
            }
        }
        __syncthreads();
        const int row = tid >> 1;
        const int half = (tid & 1) * 64;
        float mx = -1e30f;
        for (int c = 0; c < 64; c++) mx = fmaxf(mx, S[row * 128 + half + c]);
        mx = fmaxf(mx, __shfl_xor(mx, 1));
        float sum = 0.f;
        for (int c = 0; c < 64; c++) sum += __expf(S[row * 128 + half + c] - mx);
        sum += __shfl_xor(sum, 1);
        const float inv = 1.f / sum;
        for (int c = 0; c < 64; c++)
            C[(long long)row * ldc + half + c] = __expf(S[row * 128 + half + c] - mx) * inv;
    } else if (MODE == 2) {
        float* S = (float*)smem;
        const int s1 = sizes[bz];
        const int s2 = sizes[BATCH + bz];
        #pragma unroll
        for (int i = 0; i < 4; i++) {
            #pragma unroll
            for (int j = 0; j < 4; j++) {
                const int col = wn + j * 16 + lr;
                #pragma unroll
                for (int r = 0; r < 4; r++) {
                    const int row = wm + i * 16 + quad * 4 + r;
                    float v = acc[i][j][r];
                    if (row >= s1 || col >= s2) v = 0.f;
                    S[row * 128 + col] = v;
                }
            }
        }
        __syncthreads();
        const int idx = tid >> 1;
        const int half = (tid & 1) * 64;
        {
            float mx = -1e30f;
            for (int c = 0; c < 64; c++) mx = fmaxf(mx, S[idx * 128 + half + c]);
            mx = fmaxf(mx, __shfl_xor(mx, 1));
            float sum = 0.f;
            for (int c = 0; c < 64; c++) sum += __expf(S[idx * 128 + half + c] - mx);
            sum += __shfl_xor(sum, 1);
            const float inv = 1.f / sum;
            for (int c = 0; c < 64; c++)
                C[(long long)idx * 128 + half + c] = __expf(S[idx * 128 + half + c] - mx) * inv;
        }
        {
            float mx = -1e30f;
            for (int r = 0; r < 64; r++) mx = fmaxf(mx, S[(half + r) * 128 + idx]);
            mx = fmaxf(mx, __shfl_xor(mx, 1));
            float sum = 0.f;
            for (int r = 0; r < 64; r++) sum += __expf(S[(half + r) * 128 + idx] - mx);
            sum += __shfl_xor(sum, 1);
            const float inv = 1.f / sum;
            for (int r = 0; r < 64; r++)
                PT[(long long)idx * 128 + half + r] = __expf(S[(half + r) * 128 + idx] - mx) * inv;
        }
    } else {
        const int s1 = sizes ? sizes[bz] : SEQ;
        const int s2 = sizes ? sizes[BATCH + bz] : SEQ;
        #pragma unroll
        for (int i = 0; i < 4; i++) {
            #pragma unroll
            for (int j = 0; j < 4; j++) {
                const int gn = bn + wn + j * 16 + lr;
                if (gn >= N) continue;
                #pragma unroll
                for (int r = 0; r < 4; r++) {
                    const int gm = wm + i * 16 + quad * 4 + r;
                    float v = acc[i][j][r];
                    if (sizes && (gm >= s1 || gn >= s2)) v = 0.f;
                    if (flags & F_ACCUM) v += C[(long long)gm * ldc + gn];
                    if (flags & F_RELU)  v = fmaxf(v, 0.f);
                    C[(long long)gm * ldc + gn] = v;
                    if (PT) PT[(long long)gn * 128 + gm] = v;
                }
            }
        }
    }
}

// All weight transposes + hi/lo splits in one launch.
struct WEnt { const float* src; u16* H; u16* L; int K, N, Kp, rowStart; };
struct WTab { WEnt e[11]; };
__global__ void convert_all(WTab t)
{
    const int row = blockIdx.y;
    const int k = blockIdx.x * 256 + threadIdx.x;
    #pragma unroll
    for (int s = 0; s < 11; s++) {
        const WEnt w = t.e[s];
        if (row >= w.rowStart && row < w.rowStart + w.N) {
            const int n = row - w.rowStart;
            if (k < w.Kp) {
                const float v = (k < w.K) ? w.src[(long long)k * w.N + n] : 0.f;
                const u16 h = f2bf(v);
                w.H[(long long)n * w.Kp + k] = h;
                w.L[(long long)n * w.Kp + k] = f2bf(v - bf2f(h));
            }
            return;
        }
    }
}

__global__ void norms_kernel(const float* __restrict__ emb, float* __restrict__ norms)
{
    const int r = blockIdx.x;
    const int lane = threadIdx.x;
    const float* row = emb + (long long)r * EDIM;
    float ss = 0.f;
    #pragma unroll
    for (int i = 0; i < 5; i++) {
        const int c = lane + i * 64;
        const float f = (c < EDIM) ? row[c] : 0.f;
        ss += f * f;
    }
    #pragma unroll
    for (int o = 32; o > 0; o >>= 1) ss += __shfl_xor(ss, o);
    if (lane == 0) norms[r] = rsqrtf(fmaxf(ss, 1e-12f));
}

__global__ void sizes_kernel(const int* __restrict__ x1, const int* __restrict__ x2,
                             int* __restrict__ sizes)
{
    const int b = blockIdx.x;
    const int side = blockIdx.y;
    const int* x = (side ? x2 : x1) + b * SEQ;
    const int nz = (x[threadIdx.x] != 0) ? 1 : 0;
    const unsigned long long bal = __ballot(nz);
    __shared__ int part[2];
    if ((threadIdx.x & 63) == 0) part[threadIdx.x >> 6] = __popcll(bal);
    __syncthreads();
    if (threadIdx.x == 0) sizes[side * BATCH + b] = part[0] + part[1];
}

__global__ void agg_kernel(const float* __restrict__ v1s, const float* __restrict__ v2s,
                           const float* __restrict__ w_agg, float* __restrict__ y)
{
    const int b = blockIdx.x;
    const int lane = threadIdx.x;
    float a0 = 0.f, a1 = 0.f, a2 = 0.f;
    for (int k = lane; k < 800; k += 64) {
        const float v = (k < 400) ? v1s[b * 400 + k] : v2s[b * 400 + k - 400];
        a0 = fmaf(v, w_agg[k * 3 + 0], a0);
        a1 = fmaf(v, w_agg[k * 3 + 1], a1);
        a2 = fmaf(v, w_agg[k * 3 + 2], a2);
    }
    #pragma unroll
    for (int o = 32; o > 0; o >>= 1) {
        a0 += __shfl_xor(a0, o);
        a1 += __shfl_xor(a1, o);
        a2 += __shfl_xor(a2, o);
    }
    if (lane == 0) {
        y[b * 3 + 0] = fmaxf(a0, 0.f);
        y[b * 3 + 1] = fmaxf(a1, 0.f);
        y[b * 3 + 2] = fmaxf(a2, 0.f);
    }
}

extern "C" void kernel_launch(void* const* d_in, const int* in_sizes, int n_in,
                              void* d_out, int out_size, void* d_ws, size_t ws_size,
                              hipStream_t stream)
{
    (void)in_sizes; (void)n_in; (void)out_size; (void)ws_size;
    const int*   x1         = (const int*)d_in[0];
    const int*   x2         = (const int*)d_in[1];
    const float* emb        = (const float*)d_in[2];
    const float* w_intra    = (const float*)d_in[3];
    const float* bias_intra = (const float*)d_in[4];
    const float* w_proj1    = (const float*)d_in[5];
    const float* w_proj2    = (const float*)d_in[6];
    const float* w_att      = (const float*)d_in[7];
    const float* w_cmp1     = (const float*)d_in[8];
    const float* w_cmp2     = (const float*)d_in[9];
    const float* w_agg      = (const float*)d_in[10];
    float* y  = (float*)d_out;
    float* ws = (float*)d_ws;

    // ---- workspace (floats); total ~58.64M fl = 234.6 MB ----
    float* X1CAT = ws;                        // [32768,400]: x1p | beta; phase A: F side-2
    float* X2CAT = X1CAT + 13107200;          // [32768,400]: x2p | alpha (contig)
    float* T     = X2CAT + 13107200;          // [512,200,128]: G^T -> x_proj^T
    float* FBUF  = T + 13107200;              // [32768,300] intra f side-1
    float* ATT   = FBUF + 9830400;            // [512,128,128] probs (dead after xp)
    float* POOL  = ATT + 8388608;             // [512,400] pooled v1|v2
    int*   SIZES = (int*)(POOL + 204800);     // [2,256] + pad
    float* NORMS = (float*)(SIZES + 512);     // [32000] + pad
    u16*   W1H   = (u16*)(NORMS + 32768);     // side-1 stack [556][320]: wp_b|z56|intra
    u16*   W1L   = W1H + 177920;
    u16*   W2H   = W1L + 177920;              // side-2 stack [556][320]
    u16*   W2L   = W2H + 177920;
    u16*   WAH   = W2L + 177920;              // w_att^T  [200][224]
    u16*   WAL   = WAH + 44800;
    u16*   WC1H  = WAL + 44800;               // w_cmp1^T [400][416]
    u16*   WC1L  = WC1H + 166400;
    u16*   WC2H  = WC1L + 166400;
    u16*   WC2L  = WC2H + 166400;
    u16*   WPA1H = WC2L + 166400;             // wp_a side1 [200][320]
    u16*   WPA1L = WPA1H + 64000;
    u16*   WPA2H = WPA1L + 64000;
    u16*   WPA2L = WPA2H + 64000;

    // phase-A alias: side-2 intra f lives in X1CAT region (dead until xp)
    float* F1X = X1CAT;                       // [32768,300]
    // phase-B aliases: F12 spans FBUF + head of ATT (probs dead by then)
    float* F12 = FBUF;                        // [65536,200] f1|f2
    float* F2  = FBUF + 6553600;
    // sim outputs alias the f slots they consumed (block-local WAR):
    float* SIMP = F2;                         // probs slot bz at F2  + bz*25600
    float* SMTP = F12;                        // probs^T slot bz at F12 + bz*25600
    float* T1  = T;
    float* T2  = T + 6553600;

    const long long sbSS = (long long)SEQ * SEQ;     // 16384
    const long long sbF  = (long long)SEQ * EDIM;    // 38400
    const long long sbFP = 25600;                    // f1/f2 slot stride (128*200)
    const long long sbC  = (long long)SEQ * 400;     // 51200
    const long long sbT  = (long long)PDIM * SEQ;    // 25600

    sizes_kernel<<<dim3(BATCH, 2), 128, 0, stream>>>(x1, x2, SIZES);
    norms_kernel<<<32000, 64, 0, stream>>>(emb, NORMS);

    {
        WTab t;
        t.e[0]  = { w_proj1 + 300 * 200, W1H,             W1L,             300, 200, 320, 0    };
        t.e[1]  = { w_intra,             W1H + 200 * 320, W1L + 200 * 320,   0,  56, 320, 200  };
        t.e[2]  = { w_intra,             W1H + 256 * 320, W1L + 256 * 320, 300, 300, 320, 256  };
        t.e[3]  = { w_proj2 + 300 * 200, W2H,             W2L,             300, 200, 320, 556  };
        t.e[4]  = { w_intra,             W2H + 200 * 320, W2L + 200 * 320,   0,  56, 320, 756  };
        t.e[5]  = { w_intra,             W2H + 256 * 320, W2L + 256 * 320, 300, 300, 320, 812  };
        t.e[6]  = { w_att,               WAH,             WAL,             200, 200, 224, 1112 };
        t.e[7]  = { w_cmp1,              WC1H,            WC1L,            400, 400, 416, 1312 };
        t.e[8]  = { w_cmp2,              WC2H,            WC2L,            400, 400, 416, 1712 };
        t.e[9]  = { w_proj1,             WPA1H,           WPA1L,           300, 200, 320, 2112 };
        t.e[10] = { w_proj2,             WPA2H,           WPA2L,           300, 200, 320, 2312 };
        convert_all<<<dim3(2, 2512), 256, 0, stream>>>(t);
    }

    // -------- phase A --------
    // merged proj (both sides): T[0:512] = (e@wp_b)^T; f side1 -> FBUF, side2 -> F1X
    gemm_proj<<<dim3(5, 512), 256, 0, stream>>>(
        x1, x2, emb, NORMS, W1H, W1L, W2H, W2L, T, FBUF, F1X);
    // merged att (512 batches): probs = rowsoftmax(f f^T + dbias) -> ATT
    gemm_bat<1><<<dim3(1, 1, 2 * BATCH), 256, 0, stream>>>(
        FBUF, F1X, FBUF, nullptr, ATT, nullptr,
        SEQ, EDIM, 320, EDIM, EDIM, SEQ, sbF, sbF, sbSS, 0,
        0, bias_intra, nullptr, 1);
    // fused xp: XCAT[:,0:200] = relu(e@wp_a + probs@G); x_proj^T in-place -> T
    gemm_xp<<<dim3(2, 1, 2 * BATCH), 256, 0, stream>>>(
        ATT, T, x1, x2, emb, NORMS, WPA1H, WPA1L, WPA2H, WPA2L, X1CAT);

    // -------- phase B --------
    // f1|f2 = relu(x_proj @ w_att)   [M=65536; A cols 200:224 garbage*0]
    gemm_flat<<<dim3(2, 512), 256, 0, stream>>>(
        X1CAT, WAH, WAL, WAH, WAL, 1 << 30, F12, nullptr, nullptr,
        2 * BSTOK, PDIM, 224, 400, 224, PDIM, F_RELU);
    // fused sim: mask(f1 f2^T) -> row softmax over f2 slot + col softmax^T over f1 slot
    gemm_bat<2><<<dim3(1, 1, BATCH), 256, 0, stream>>>(
        F12, nullptr, F2, nullptr, SIMP, SMTP,
        SEQ, PDIM, 224, PDIM, PDIM, SEQ, sbFP, sbFP, sbFP, sbFP,
        0, nullptr, SIZES, 0);
    // beta (bz<256): rowsm @ x2p^T; alpha (bz>=256): colsm^T @ x1p^T
    gemm_bat<0><<<dim3(2, 1, 2 * BATCH), 256, 0, stream>>>(
        SIMP, SMTP, T2, T1, X1CAT + 200, nullptr,
        PDIM, SEQ, SEQ, SEQ, SEQ, 400, sbFP, sbT, sbC, 0,
        0, nullptr, nullptr, 0);

    // -------- phase C: fused compare + masked pool, aggregate --------
    gemm_flat<<<dim3(4, 512), 256, 0, stream>>>(
        X1CAT, WC1H, WC1L, WC2H, WC2L, BSTOK,
        nullptr, POOL, SIZES,
        2 * BSTOK, 400, 416, 400, 416, 400, F_RELU);
    agg_kernel<<<BATCH, 64, 0, stream>>>(POOL, POOL + 102400, w_agg, y);
}

// Round 10
// 551.917 us; speedup vs baseline: 3.3113x; 1.0205x over previous
//
#include <hip/hip_runtime.h>

#define BATCH 256
#define SEQ   128
#define EDIM  300
#define PDIM  200
#define BSTOK (BATCH * SEQ)

#define F_RELU  1
#define F_ACCUM 2

typedef unsigned short u16;
typedef __attribute__((ext_vector_type(8))) short bf16x8;
typedef __attribute__((ext_vector_type(4))) float f32x4;

__device__ __forceinline__ u16 f2bf(float x) {
    unsigned u = __float_as_uint(x);
    unsigned r = u + 0x7fffu + ((u >> 16) & 1u);
    return (u16)(r >> 16);
}
__device__ __forceinline__ float bf2f(u16 h) {
    return __uint_as_float(((unsigned)h) << 16);
}

// split 16 fp32 -> hi(trunc)/lo(residual) bf16, store 2 x uint4 each.
__device__ __forceinline__ void split_store(const float* va, u16* dH, u16* dL)
{
    unsigned hp[8], lp[8];
    #pragma unroll
    for (int i = 0; i < 8; i++) {
        const unsigned u0 = __float_as_uint(va[2 * i]);
        const unsigned u1 = __float_as_uint(va[2 * i + 1]);
        const unsigned h0 = u0 & 0xffff0000u;
        const unsigned h1 = u1 & 0xffff0000u;
        hp[i] = (u0 >> 16) | h1;
        const float r0 = va[2 * i]     - __uint_as_float(h0);
        const float r1 = va[2 * i + 1] - __uint_as_float(h1);
        lp[i] = (__float_as_uint(r0) >> 16) | (__float_as_uint(r1) & 0xffff0000u);
    }
    ((uint4*)dH)[0] = make_uint4(hp[0], hp[1], hp[2], hp[3]);
    ((uint4*)dH)[1] = make_uint4(hp[4], hp[5], hp[6], hp[7]);
    ((uint4*)dL)[0] = make_uint4(lp[0], lp[1], lp[2], lp[3]);
    ((uint4*)dL)[1] = make_uint4(lp[4], lp[5], lp[6], lp[7]);
}

// RNE-rounded hi-only store (for 1-MFMA paths).
__device__ __forceinline__ void hi_store(const float* va, u16* dH)
{
    unsigned hp[8];
    #pragma unroll
    for (int i = 0; i < 8; i++)
        hp[i] = (unsigned)f2bf(va[2 * i]) | ((unsigned)f2bf(va[2 * i + 1]) << 16);
    ((uint4*)dH)[0] = make_uint4(hp[0], hp[1], hp[2], hp[3]);
    ((uint4*)dH)[1] = make_uint4(hp[4], hp[5], hp[6], hp[7]);
}

__device__ __forceinline__ void load16(float* va, const float* __restrict__ src,
                                       bool row_ok, int kbase, int Kvalid)
{
    if (row_ok) {
        #pragma unroll
        for (int i = 0; i < 4; i++) {
            const float4 v = *(const float4*)(src + i * 4);
            va[i * 4 + 0] = v.x; va[i * 4 + 1] = v.y;
            va[i * 4 + 2] = v.z; va[i * 4 + 3] = v.w;
        }
        #pragma unroll
        for (int i = 0; i < 16; i++)
            va[i] = (kbase + i < Kvalid) ? va[i] : 0.f;
    } else {
        #pragma unroll
        for (int i = 0; i < 16; i++) va[i] = 0.f;
    }
}

__device__ __forceinline__ void stage16(const float* __restrict__ src, bool row_ok,
                                        int kbase, int Kvalid, u16* dH, u16* dL)
{
    float va[16];
    load16(va, src, row_ok, kbase, Kvalid);
    split_store(va, dH, dL);
}

__device__ __forceinline__ void stage16_hi(const float* __restrict__ src, bool row_ok,
                                           int kbase, int Kvalid, u16* dH)
{
    float va[16];
    load16(va, src, row_ok, kbase, Kvalid);
    hi_store(va, dH);
}

// Gathered-embedding: va = emb_row[kb..kb+15] * nrm, zero k >= 300.
__device__ __forceinline__ void gather16(float* va, const float* __restrict__ erow,
                                         float nrm, int kb)
{
    if (kb + 16 <= EDIM) {
        #pragma unroll
        for (int i = 0; i < 4; i++) {
            const float4 v = *(const float4*)(erow + kb + i * 4);
            va[i * 4 + 0] = v.x; va[i * 4 + 1] = v.y;
            va[i * 4 + 2] = v.z; va[i * 4 + 3] = v.w;
        }
    } else {
        #pragma unroll
        for (int i = 0; i < 16; i++)
            va[i] = (kb + i < EDIM) ? erow[kb + i] : 0.f;
    }
    #pragma unroll
    for (int i = 0; i < 16; i++) va[i] *= nrm;
}

__device__ __forceinline__ void stage_gather(const float* __restrict__ erow, float nrm,
                                             int kb, u16* dH, u16* dL)
{
    float va[16];
    gather16(va, erow, nrm, kb);
    split_store(va, dH, dL);
}

__device__ __forceinline__ void stage_gather_hi(const float* __restrict__ erow, float nrm,
                                                int kb, u16* dH)
{
    float va[16];
    gather16(va, erow, nrm, kb);
    hi_store(va, dH);
}

#define MFMA3(ai, aj) \
    acc[ai][aj] = __builtin_amdgcn_mfma_f32_16x16x32_bf16(fah[ai], fbh[aj], acc[ai][aj], 0, 0, 0); \
    acc[ai][aj] = __builtin_amdgcn_mfma_f32_16x16x32_bf16(fah[ai], fbl[aj], acc[ai][aj], 0, 0, 0); \
    acc[ai][aj] = __builtin_amdgcn_mfma_f32_16x16x32_bf16(fal[ai], fbh[aj], acc[ai][aj], 0, 0, 0);

#define MFMA1(ai, aj) \
    acc[ai][aj] = __builtin_amdgcn_mfma_f32_16x16x32_bf16(fah[ai], fbh[aj], acc[ai][aj], 0, 0, 0);

// Coalesced transposed store of the block's 128x128 tile via LDS (stride 129).
__device__ __forceinline__ void store_transposed(
    float* __restrict__ PT, const f32x4 (*acc)[4], float* TR,
    int bn, int Nvalid, int wm, int wn, int lr, int quad, int tid, bool relu)
{
    #pragma unroll
    for (int h = 0; h < 2; h++) {
        __syncthreads();
        if ((wn >> 6) == h) {
            #pragma unroll
            for (int j = 0; j < 4; j++) {
                const int col = j * 16 + lr;
                #pragma unroll
                for (int i = 0; i < 4; i++)
                    #pragma unroll
                    for (int r = 0; r < 4; r++) {
                        float v = acc[i][j][r];
                        if (relu) v = fmaxf(v, 0.f);
                        TR[col * 129 + wm + i * 16 + quad * 4 + r] = v;
                    }
            }
        }
        __syncthreads();
        const int row = tid >> 2;
        const int gp = bn + h * 64 + row;
        if (gp < Nvalid) {
            float* dst = PT + (long long)gp * 128;
            for (int c = (tid & 3); c < 32; c += 4) {
                const int base = row * 129 + c * 4;
                *(float4*)(dst + c * 4) =
                    make_float4(TR[base], TR[base + 1], TR[base + 2], TR[base + 3]);
            }
        }
    }
}

// ---------------------------------------------------------------------------
// Merged phase-A projection GEMM (both sides, grid (5, 512), XCD-swizzled):
//   m-tile mt in [0,512): side = mt >= 256; A = gathered l2norm-emb rows.
//   B = per-side stack [556][320]: rows 0:200 wp_b | 200:256 zero | 256:556 intra
//   bn < 256  -> T[mt][gn][.] (transposed coalesced, 3-MFMA split: output-critical)
//   bn >= 256 -> Fside[row][gn-256] relu  (1-MFMA bf16: feeds att softmax only)
// ---------------------------------------------------------------------------
__global__ __launch_bounds__(256) void gemm_proj(
    const int* __restrict__ x1, const int* __restrict__ x2,
    const float* __restrict__ emb, const float* __restrict__ norms,
    const u16* __restrict__ W1h, const u16* __restrict__ W1l,
    const u16* __restrict__ W2h, const u16* __restrict__ W2l,
    float* __restrict__ T, float* __restrict__ F0, float* __restrict__ F1)
{
    __shared__ __align__(16) unsigned char smem[40960];
    u16 (*AsH)[40] = (u16(*)[40])(smem);
    u16 (*AsL)[40] = (u16(*)[40])(smem + 10240);
    u16 (*BsH)[40] = (u16(*)[40])(smem + 20480);
    u16 (*BsL)[40] = (u16(*)[40])(smem + 30720);

    const int tid = threadIdx.x;
    const int id  = blockIdx.y * 5 + blockIdx.x;
    const int xcd = id & 7;
    const int s   = id >> 3;
    const int mt  = xcd + 8 * (s / 5);
    const int bm  = mt * 128;
    const int bn  = (s % 5) * 128;
    const bool side2 = mt >= 256;
    const bool wb = bn < 256;          // block-uniform precision tier

    const u16* Bh = side2 ? W2h : W1h;
    const u16* Bl = side2 ? W2l : W1l;
    float* F = side2 ? F1 : F0;
    const int fm = side2 ? bm - 32768 : bm;
    const int* toks = (side2 ? x2 - 32768 : x1) + bm;

    const int wave = tid >> 6;
    const int lane = tid & 63;
    const int wm   = (wave >> 1) * 64;
    const int wn   = (wave & 1) * 64;
    const int lr   = lane & 15;
    const int quad = lane >> 4;
    const int sr   = tid >> 1;
    const int sc   = (tid & 1) * 16;

    const int tok = toks[sr];
    const float nrm = norms[tok];
    const float* erow = emb + (long long)tok * EDIM;

    f32x4 acc[4][4];
    #pragma unroll
    for (int i = 0; i < 4; i++)
        #pragma unroll
        for (int j = 0; j < 4; j++)
            acc[i][j] = (f32x4)(0.0f);

    for (int k0 = 0; k0 < 320; k0 += 32) {
        if (wb) stage_gather(erow, nrm, k0 + sc, &AsH[sr][sc], &AsL[sr][sc]);
        else    stage_gather_hi(erow, nrm, k0 + sc, &AsH[sr][sc]);
        {
            uint4 wh0 = make_uint4(0,0,0,0), wh1 = make_uint4(0,0,0,0);
            const int gn = bn + sr;
            const long long br = (long long)gn * 320 + k0 + sc;
            if (gn < 556) {
                wh0 = *(const uint4*)(Bh + br);
                wh1 = *(const uint4*)(Bh + br + 8);
            }
            *(uint4*)&BsH[sr][sc]     = wh0;
            *(uint4*)&BsH[sr][sc + 8] = wh1;
            if (wb) {
                uint4 wl0 = make_uint4(0,0,0,0), wl1 = make_uint4(0,0,0,0);
                if (gn < 556) {
                    wl0 = *(const uint4*)(Bl + br);
                    wl1 = *(const uint4*)(Bl + br + 8);
                }
                *(uint4*)&BsL[sr][sc]     = wl0;
                *(uint4*)&BsL[sr][sc + 8] = wl1;
            }
        }
        __syncthreads();

        bf16x8 fah[4], fal[4], fbh[4], fbl[4];
        #pragma unroll
        for (int i = 0; i < 4; i++) {
            fah[i] = *(const bf16x8*)&AsH[wm + i * 16 + lr][quad * 8];
            fbh[i] = *(const bf16x8*)&BsH[wn + i * 16 + lr][quad * 8];
        }
        if (wb) {
            #pragma unroll
            for (int i = 0; i < 4; i++) {
                fal[i] = *(const bf16x8*)&AsL[wm + i * 16 + lr][quad * 8];
                fbl[i] = *(const bf16x8*)&BsL[wn + i * 16 + lr][quad * 8];
            }
            #pragma unroll
            for (int i = 0; i < 4; i++)
                #pragma unroll
                for (int j = 0; j < 4; j++) { MFMA3(i, j) }
        } else {
            #pragma unroll
            for (int i = 0; i < 4; i++)
                #pragma unroll
                for (int j = 0; j < 4; j++) { MFMA1(i, j) }
        }
        __syncthreads();
    }

    if (wb) {
        float* Tb = T + (long long)mt * (PDIM * SEQ);
        store_transposed(Tb, acc, (float*)smem, bn, PDIM, wm, wn, lr, quad, tid, false);
    } else {
        #pragma unroll
        for (int i = 0; i < 4; i++) {
            #pragma unroll
            for (int j = 0; j < 4; j++) {
                const int idx = bn + wn + j * 16 + lr - 256;
                if (idx >= EDIM) continue;
                #pragma unroll
                for (int r = 0; r < 4; r++) {
                    const int gm = fm + wm + i * 16 + quad * 4 + r;
                    F[(long long)gm * EDIM + idx] = fmaxf(acc[i][j][r], 0.f);
                }
            }
        }
    }
}

// ---------------------------------------------------------------------------
// Fused xp GEMM (3-MFMA, output-critical): acc = e @ wp_a (K=320) +
// probs @ G (K=128); relu -> XCAT cols 0:200 + x_proj^T in-place over T.
// grid (2, 1, 512).
// ---------------------------------------------------------------------------
__global__ __launch_bounds__(256) void gemm_xp(
    const float* __restrict__ P, float* __restrict__ T,
    const int* __restrict__ x1, const int* __restrict__ x2,
    const float* __restrict__ emb, const float* __restrict__ norms,
    const u16* __restrict__ W1h, const u16* __restrict__ W1l,
    const u16* __restrict__ W2h, const u16* __restrict__ W2l,
    float* __restrict__ XCAT)
{
    __shared__ __align__(16) unsigned char smem[40960];
    u16 (*AsH)[40] = (u16(*)[40])(smem);
    u16 (*AsL)[40] = (u16(*)[40])(smem + 10240);
    u16 (*BsH)[40] = (u16(*)[40])(smem + 20480);
    u16 (*BsL)[40] = (u16(*)[40])(smem + 30720);

    const int tid = threadIdx.x;
    const int bz  = blockIdx.z;
    const int bn  = blockIdx.x * 128;

    const int wave = tid >> 6;
    const int lane = tid & 63;
    const int wm   = (wave >> 1) * 64;
    const int wn   = (wave & 1) * 64;
    const int lr   = lane & 15;
    const int quad = lane >> 4;
    const int sr   = tid >> 1;
    const int sc   = (tid & 1) * 16;

    const int* toks = (bz < BATCH) ? x1 + bz * SEQ : x2 + (bz - BATCH) * SEQ;
    const u16* Wh = (bz < BATCH) ? W1h : W2h;
    const u16* Wl = (bz < BATCH) ? W1l : W2l;
    const int tok = toks[sr];
    const float nrm = norms[tok];
    const float* erow = emb + (long long)tok * EDIM;
    const float* Pb = P + (long long)bz * (SEQ * SEQ);
    float* Tb = T + (long long)bz * (PDIM * SEQ);

    f32x4 acc[4][4];
    #pragma unroll
    for (int i = 0; i < 4; i++)
        #pragma unroll
        for (int j = 0; j < 4; j++)
            acc[i][j] = (f32x4)(0.0f);

    for (int k0 = 0; k0 < 320; k0 += 32) {
        stage_gather(erow, nrm, k0 + sc, &AsH[sr][sc], &AsL[sr][sc]);
        {
            uint4 wh0 = make_uint4(0,0,0,0), wh1 = make_uint4(0,0,0,0);
            uint4 wl0 = make_uint4(0,0,0,0), wl1 = make_uint4(0,0,0,0);
            const int gn = bn + sr;
            if (gn < PDIM) {
                const long long br = (long long)gn * 320 + k0 + sc;
                wh0 = *(const uint4*)(Wh + br);
                wh1 = *(const uint4*)(Wh + br + 8);
                wl0 = *(const uint4*)(Wl + br);
                wl1 = *(const uint4*)(Wl + br + 8);
            }
            *(uint4*)&BsH[sr][sc]     = wh0;
            *(uint4*)&BsH[sr][sc + 8] = wh1;
            *(uint4*)&BsL[sr][sc]     = wl0;
            *(uint4*)&BsL[sr][sc + 8] = wl1;
        }
        __syncthreads();

        bf16x8 fah[4], fal[4], fbh[4], fbl[4];
        #pragma unroll
        for (int i = 0; i < 4; i++) {
            fah[i] = *(const bf16x8*)&AsH[wm + i * 16 + lr][quad * 8];
            fal[i] = *(const bf16x8*)&AsL[wm + i * 16 + lr][quad * 8];
            fbh[i] = *(const bf16x8*)&BsH[wn + i * 16 + lr][quad * 8];
            fbl[i] = *(const bf16x8*)&BsL[wn + i * 16 + lr][quad * 8];
        }
        #pragma unroll
        for (int i = 0; i < 4; i++)
            #pragma unroll
            for (int j = 0; j < 4; j++) { MFMA3(i, j) }
        __syncthreads();
    }

    for (int k0 = 0; k0 < 128; k0 += 32) {
        stage16(Pb + (long long)sr * 128 + k0 + sc, true, 0, 1 << 30,
                &AsH[sr][sc], &AsL[sr][sc]);
        const int gn = bn + sr;
        stage16(Tb + (long long)gn * 128 + k0 + sc, gn < PDIM, 0, 1 << 30,
                &BsH[sr][sc], &BsL[sr][sc]);
        __syncthreads();

        bf16x8 fah[4], fal[4], fbh[4], fbl[4];
        #pragma unroll
        for (int i = 0; i < 4; i++) {
            fah[i] = *(const bf16x8*)&AsH[wm + i * 16 + lr][quad * 8];
            fal[i] = *(const bf16x8*)&AsL[wm + i * 16 + lr][quad * 8];
            fbh[i] = *(const bf16x8*)&BsH[wn + i * 16 + lr][quad * 8];
            fbl[i] = *(const bf16x8*)&BsL[wn + i * 16 + lr][quad * 8];
        }
        #pragma unroll
        for (int i = 0; i < 4; i++)
            #pragma unroll
            for (int j = 0; j < 4; j++) { MFMA3(i, j) }
        __syncthreads();
    }

    const long long rowbase = (long long)bz * SEQ;
    #pragma unroll
    for (int i = 0; i < 4; i++) {
        #pragma unroll
        for (int j = 0; j < 4; j++) {
            const int gn = bn + wn + j * 16 + lr;
            if (gn >= PDIM) continue;
            #pragma unroll
            for (int r = 0; r < 4; r++) {
                const int gm = wm + i * 16 + quad * 4 + r;
                XCAT[(rowbase + gm) * 400 + gn] = fmaxf(acc[i][j][r], 0.f);
            }
        }
    }
    store_transposed(Tb, acc, (float*)smem, bn, PDIM, wm, wn, lr, quad, tid, true);
}

// ---------------------------------------------------------------------------
// Flat split-bf16 MFMA GEMM vs pre-split transposed weights. NM = 3 (split)
// or 1 (plain bf16 RNE). XCD-swizzled when gridDim.y % 8 == 0.
// Weight select per m-tile: bm >= Msplit -> B2. Outputs: C and/or pooled PO.
// ---------------------------------------------------------------------------
template <int NM>
__global__ __launch_bounds__(256) void gemm_flat(
    const float* __restrict__ A,
    const u16* __restrict__ Bh, const u16* __restrict__ Bl,
    const u16* __restrict__ Bh2, const u16* __restrict__ Bl2, int Msplit,
    float* __restrict__ C, float* __restrict__ PO, const int* __restrict__ sizes,
    int M, int N, int Kp, int lda, int ldb, int ldc, int flags)
{
    __shared__ u16 AsH[128][40];
    __shared__ u16 AsL[128][40];
    __shared__ u16 BsH[128][40];
    __shared__ u16 BsL[128][40];

    const int tid = threadIdx.x;
    int bx = blockIdx.x, by = blockIdx.y;
    if ((gridDim.y & 7) == 0) {
        const int gx = gridDim.x;
        const int id = by * gx + bx;
        const int xcd = id & 7;
        const int s = id >> 3;
        by = xcd + 8 * (s / gx);
        bx = s % gx;
    }
    const int bm = by * 128;
    const int bn = bx * 128;

    const int wave = tid >> 6;
    const int lane = tid & 63;
    const int wm   = (wave >> 1) * 64;
    const int wn   = (wave & 1) * 64;
    const int lr   = lane & 15;
    const int quad = lane >> 4;
    const int sr   = tid >> 1;
    const int sc   = (tid & 1) * 16;

    if (bm >= Msplit) { Bh = Bh2; Bl = Bl2; }

    f32x4 acc[4][4];
    #pragma unroll
    for (int i = 0; i < 4; i++)
        #pragma unroll
        for (int j = 0; j < 4; j++)
            acc[i][j] = (f32x4)(0.0f);

    for (int k0 = 0; k0 < Kp; k0 += 32) {
        if constexpr (NM == 3)
            stage16(A + (long long)(bm + sr) * lda + k0 + sc, true, 0, 1 << 30,
                    &AsH[sr][sc], &AsL[sr][sc]);
        else
            stage16_hi(A + (long long)(bm + sr) * lda + k0 + sc, true, 0, 1 << 30,
                       &AsH[sr][sc]);
        {
            uint4 wh0 = make_uint4(0,0,0,0), wh1 = make_uint4(0,0,0,0);
            const int gn = bn + sr;
            const long long br = (long long)gn * ldb + k0 + sc;
            if (gn < N) {
                wh0 = *(const uint4*)(Bh + br);
                wh1 = *(const uint4*)(Bh + br + 8);
            }
            *(uint4*)&BsH[sr][sc]     = wh0;
            *(uint4*)&BsH[sr][sc + 8] = wh1;
            if constexpr (NM == 3) {
                uint4 wl0 = make_uint4(0,0,0,0), wl1 = make_uint4(0,0,0,0);
                if (gn < N) {
                    wl0 = *(const uint4*)(Bl + br);
                    wl1 = *(const uint4*)(Bl + br + 8);
                }
                *(uint4*)&BsL[sr][sc]     = wl0;
                *(uint4*)&BsL[sr][sc + 8] = wl1;
            }
        }
        __syncthreads();

        bf16x8 fah[4], fal[4], fbh[4], fbl[4];
        #pragma unroll
        for (int i = 0; i < 4; i++) {
            fah[i] = *(const bf16x8*)&AsH[wm + i * 16 + lr][quad * 8];
            fbh[i] = *(const bf16x8*)&BsH[wn + i * 16 + lr][quad * 8];
        }
        if constexpr (NM == 3) {
            #pragma unroll
            for (int i = 0; i < 4; i++) {
                fal[i] = *(const bf16x8*)&AsL[wm + i * 16 + lr][quad * 8];
                fbl[i] = *(const bf16x8*)&BsL[wn + i * 16 + lr][quad * 8];
            }
            #pragma unroll
            for (int i = 0; i < 4; i++)
                #pragma unroll
                for (int j = 0; j < 4; j++) { MFMA3(i, j) }
        } else {
            #pragma unroll
            for (int i = 0; i < 4; i++)
                #pragma unroll
                for (int j = 0; j < 4; j++) { MFMA1(i, j) }
        }
        __syncthreads();
    }

    const int sz = PO ? sizes[bm >> 7] : 0;
    float ps[4] = {0.f, 0.f, 0.f, 0.f};
    #pragma unroll
    for (int j = 0; j < 4; j++) {
        const int gn = bn + wn + j * 16 + lr;
        const bool gok = gn < N;
        #pragma unroll
        for (int i = 0; i < 4; i++) {
            #pragma unroll
            for (int r = 0; r < 4; r++) {
                const int row = wm + i * 16 + quad * 4 + r;
                const int gm = bm + row;
                float v = acc[i][j][r];
                if (flags & F_RELU) v = fmaxf(v, 0.f);
                if (gok && C) C[(long long)gm * ldc + gn] = v;
                if (PO && row < sz) ps[j] += v;
            }
        }
    }
    if (PO) {
        #pragma unroll
        for (int j = 0; j < 4; j++) {
            ps[j] += __shfl_xor(ps[j], 16);
            ps[j] += __shfl_xor(ps[j], 32);
        }
        float* PS = (float*)AsH;
        if (wm == 0 && quad == 0) {
            #pragma unroll
            for (int j = 0; j < 4; j++) PS[wn + j * 16 + lr] = ps[j];
        }
        __syncthreads();
        if (wm == 64 && quad == 0) {
            #pragma unroll
            for (int j = 0; j < 4; j++) PS[wn + j * 16 + lr] += ps[j];
        }
        __syncthreads();
        if (tid < 128) {
            const int gn = bn + tid;
            if (gn < N) PO[(long long)(bm >> 7) * N + gn] = PS[tid];
        }
    }
}

// ---------------------------------------------------------------------------
// Batched MFMA GEMM, NT, operands fp32 converted in staging.
// MODE 0 (3-MFMA split): plain; ACCUM/RELU; optional sizes mask; optional PT
//         transposed store; (Aalt,Balt) for bz>=256 with bz-256.
// MODE 1 (1-MFMA bf16): att — dist-bias + fused row softmax -> C (probs).
// MODE 2 (1-MFMA bf16): sim — mask + row softmax -> C + col softmax^T -> PT.
//         C/PT may alias the block's own A/B slots (block-local WAR only).
// ---------------------------------------------------------------------------
template <int MODE>
__global__ __launch_bounds__(256) void gemm_bat(
    const float* __restrict__ A, const float* __restrict__ Aalt,
    const float* __restrict__ B, const float* __restrict__ Balt,
    float* __restrict__ C, float* __restrict__ PT,
    int N, int Kvalid, int Kp, int lda, int ldb, int ldc,
    long long sA, long long sB, long long sC, long long sPT,
    int flags, const float* __restrict__ bias_ptr, const int* __restrict__ sizes,
    int same_ab)
{
    constexpr int NM = (MODE == 0) ? 3 : 1;
    constexpr int SB = (MODE >= 1) ? 65536 : 40960;
    __shared__ __align__(16) unsigned char smem[SB];
    u16 (*AsH)[40] = (u16(*)[40])(smem);
    u16 (*AsL)[40] = (u16(*)[40])(smem + 10240);
    u16 (*BsH)[40] = (u16(*)[40])(smem + 20480);
    u16 (*BsL)[40] = (u16(*)[40])(smem + 30720);

    const int bz = blockIdx.z;
    long long zb = bz;
    const float* Ause = A;
    const float* Buse = B;
    if (Aalt && bz >= BATCH) { Ause = Aalt; Buse = Balt; zb = bz - BATCH; }
    Ause += zb * sA;
    Buse += zb * sB;
    C += (long long)bz * sC;
    if (PT) PT += (long long)bz * sPT;

    const int tid  = threadIdx.x;
    const int bn   = blockIdx.x * 128;
    const int wave = tid >> 6;
    const int lane = tid & 63;
    const int wm   = (wave >> 1) * 64;
    const int wn   = (wave & 1) * 64;
    const int lr   = lane & 15;
    const int quad = lane >> 4;
    const int sr   = tid >> 1;
    const int sc   = (tid & 1) * 16;

    f32x4 acc[4][4];
    #pragma unroll
    for (int i = 0; i < 4; i++)
        #pragma unroll
        for (int j = 0; j < 4; j++)
            acc[i][j] = (f32x4)(0.0f);

    u16 (*fbH)[40] = same_ab ? AsH : BsH;
    u16 (*fbL)[40] = same_ab ? AsL : BsL;

    for (int k0 = 0; k0 < Kp; k0 += 32) {
        if constexpr (NM == 3)
            stage16(Ause + (long long)sr * lda + k0 + sc, true, k0 + sc, Kvalid,
                    &AsH[sr][sc], &AsL[sr][sc]);
        else
            stage16_hi(Ause + (long long)sr * lda + k0 + sc, true, k0 + sc, Kvalid,
                       &AsH[sr][sc]);
        if (!same_ab) {
            const int gn = bn + sr;
            if constexpr (NM == 3)
                stage16(Buse + (long long)gn * ldb + k0 + sc, gn < N, k0 + sc, Kvalid,
                        &BsH[sr][sc], &BsL[sr][sc]);
            else
                stage16_hi(Buse + (long long)gn * ldb + k0 + sc, gn < N, k0 + sc, Kvalid,
                           &BsH[sr][sc]);
        }
        __syncthreads();

        bf16x8 fah[4], fal[4], fbh[4], fbl[4];
        #pragma unroll
        for (int i = 0; i < 4; i++) {
            fah[i] = *(const bf16x8*)&AsH[wm + i * 16 + lr][quad * 8];
            fbh[i] = *(const bf16x8*)&fbH[wn + i * 16 + lr][quad * 8];
        }
        if constexpr (NM == 3) {
            #pragma unroll
            for (int i = 0; i < 4; i++) {
                fal[i] = *(const bf16x8*)&AsL[wm + i * 16 + lr][quad * 8];
                fbl[i] = *(const bf16x8*)&fbL[wn + i * 16 + lr][quad * 8];
            }
            #pragma unroll
            for (int i = 0; i < 4; i++)
                #pragma unroll
                for (int j = 0; j < 4; j++) { MFMA3(i, j) }
        } else {
            #pragma unroll
            for (int i = 0; i < 4; i++)
                #pragma unroll
                for (int j = 0; j < 4; j++) { MFMA1(i, j) }
        }
        __syncthreads();
    }

    if (MODE == 1) {
        float* S = (float*)smem;
        const float bias = bias_ptr[0];
        #pragma unroll
        for (int i = 0; i < 4; i++) {
            #pragma unroll
            for (int j = 0; j < 4; j++) {
                const int col = wn + j * 16 + lr;
                #pragma unroll
                for (int r = 0; r < 4; r++) {
                    const int row = wm + i * 16 + quad * 4 + r;
                    int d = row - col; d = d < 0 ? -d : d;
                    S[row * 128 + col] = acc[i][j][r] + ((d >= 10) ? bias : 0.f);
                }
            }
        }
        __syncthreads();
        const int row = tid >> 1;
        const int half = (tid & 1) * 64;
        float mx = -1e30f;
        for (int c = 0; c < 64; c++) mx = fmaxf(mx, S[row * 128 + half + c]);
        mx = fmaxf(mx, __shfl_xor(mx, 1));
        float sum = 0.f;
        for (int c = 0; c < 64; c++) sum += __expf(S[row * 128 + half + c] - mx);
        sum += __shfl_xor(sum, 1);
        const float inv = 1.f / sum;
        for (int c = 0; c < 64; c++)
            C[(long long)row * ldc + half + c] = __expf(S[row * 128 + half + c] - mx) * inv;
    } else if (MODE == 2) {
        float* S = (float*)smem;
        const int s1 = sizes[bz];
        const int s2 = sizes[BATCH + bz];
        #pragma unroll
        for (int i = 0; i < 4; i++) {
            #pragma unroll
            for (int j = 0; j < 4; j++) {
                const int col = wn + j * 16 + lr;
                #pragma unroll
                for (int r = 0; r < 4; r++) {
                    const int row = wm + i * 16 + quad * 4 + r;
                    float v = acc[i][j][r];
                    if (row >= s1 || col >= s2) v = 0.f;
                    S[row * 128 + col] = v;
                }
            }
        }
        __syncthreads();
        const int idx = tid >> 1;
        const int half = (tid & 1) * 64;
        {
            float mx = -1e30f;
            for (int c = 0; c < 64; c++) mx = fmaxf(mx, S[idx * 128 + half + c]);
            mx = fmaxf(mx, __shfl_xor(mx, 1));
            float sum = 0.f;
            for (int c = 0; c < 64; c++) sum += __expf(S[idx * 128 + half + c] - mx);
            sum += __shfl_xor(sum, 1);
            const float inv = 1.f / sum;
            for (int c = 0; c < 64; c++)
                C[(long long)idx * 128 + half + c] = __expf(S[idx * 128 + half + c] - mx) * inv;
        }
        {
            float mx = -1e30f;
            for (int r = 0; r < 64; r++) mx = fmaxf(mx, S[(half + r) * 128 + idx]);
            mx = fmaxf(mx, __shfl_xor(mx, 1));
            float sum = 0.f;
            for (int r = 0; r < 64; r++) sum += __expf(S[(half + r) * 128 + idx] - mx);
            sum += __shfl_xor(sum, 1);
            const float inv = 1.f / sum;
            for (int r = 0; r < 64; r++)
                PT[(long long)idx * 128 + half + r] = __expf(S[(half + r) * 128 + idx] - mx) * inv;
        }
    } else {
        const int s1 = sizes ? sizes[bz] : SEQ;
        const int s2 = sizes ? sizes[BATCH + bz] : SEQ;
        #pragma unroll
        for (int i = 0; i < 4; i++) {
            #pragma unroll
            for (int j = 0; j < 4; j++) {
                const int gn = bn + wn + j * 16 + lr;
                if (gn >= N) continue;
                #pragma unroll
                for (int r = 0; r < 4; r++) {
                    const int gm = wm + i * 16 + quad * 4 + r;
                    float v = acc[i][j][r];
                    if (sizes && (gm >= s1 || gn >= s2)) v = 0.f;
                    if (flags & F_ACCUM) v += C[(long long)gm * ldc + gn];
                    if (flags & F_RELU)  v = fmaxf(v, 0.f);
                    C[(long long)gm * ldc + gn] = v;
                    if (PT) PT[(long long)gn * 128 + gm] = v;
                }
            }
        }
    }
}

// All weight transposes + hi/lo splits in one launch.
struct WEnt { const float* src; u16* H; u16* L; int K, N, Kp, rowStart; };
struct WTab { WEnt e[11]; };
__global__ void convert_all(WTab t)
{
    const int row = blockIdx.y;
    const int k = blockIdx.x * 256 + threadIdx.x;
    #pragma unroll
    for (int s = 0; s < 11; s++) {
        const WEnt w = t.e[s];
        if (row >= w.rowStart && row < w.rowStart + w.N) {
            const int n = row - w.rowStart;
            if (k < w.Kp) {
                const float v = (k < w.K) ? w.src[(long long)k * w.N + n] : 0.f;
                const u16 h = f2bf(v);
                w.H[(long long)n * w.Kp + k] = h;
                w.L[(long long)n * w.Kp + k] = f2bf(v - bf2f(h));
            }
            return;
        }
    }
}

__global__ void norms_kernel(const float* __restrict__ emb, float* __restrict__ norms)
{
    const int r = blockIdx.x;
    const int lane = threadIdx.x;
    const float* row = emb + (long long)r * EDIM;
    float ss = 0.f;
    #pragma unroll
    for (int i = 0; i < 5; i++) {
        const int c = lane + i * 64;
        const float f = (c < EDIM) ? row[c] : 0.f;
        ss += f * f;
    }
    #pragma unroll
    for (int o = 32; o > 0; o >>= 1) ss += __shfl_xor(ss, o);
    if (lane == 0) norms[r] = rsqrtf(fmaxf(ss, 1e-12f));
}

__global__ void sizes_kernel(const int* __restrict__ x1, const int* __restrict__ x2,
                             int* __restrict__ sizes)
{
    const int b = blockIdx.x;
    const int side = blockIdx.y;
    const int* x = (side ? x2 : x1) + b * SEQ;
    const int nz = (x[threadIdx.x] != 0) ? 1 : 0;
    const unsigned long long bal = __ballot(nz);
    __shared__ int part[2];
    if ((threadIdx.x & 63) == 0) part[threadIdx.x >> 6] = __popcll(bal);
    __syncthreads();
    if (threadIdx.x == 0) sizes[side * BATCH + b] = part[0] + part[1];
}

__global__ void agg_kernel(const float* __restrict__ v1s, const float* __restrict__ v2s,
                           const float* __restrict__ w_agg, float* __restrict__ y)
{
    const int b = blockIdx.x;
    const int lane = threadIdx.x;
    float a0 = 0.f, a1 = 0.f, a2 = 0.f;
    for (int k = lane; k < 800; k += 64) {
        const float v = (k < 400) ? v1s[b * 400 + k] : v2s[b * 400 + k - 400];
        a0 = fmaf(v, w_agg[k * 3 + 0], a0);
        a1 = fmaf(v, w_agg[k * 3 + 1], a1);
        a2 = fmaf(v, w_agg[k * 3 + 2], a2);
    }
    #pragma unroll
    for (int o = 32; o > 0; o >>= 1) {
        a0 += __shfl_xor(a0, o);
        a1 += __shfl_xor(a1, o);
        a2 += __shfl_xor(a2, o);
    }
    if (lane == 0) {
        y[b * 3 + 0] = fmaxf(a0, 0.f);
        y[b * 3 + 1] = fmaxf(a1, 0.f);
        y[b * 3 + 2] = fmaxf(a2, 0.f);
    }
}

extern "C" void kernel_launch(void* const* d_in, const int* in_sizes, int n_in,
                              void* d_out, int out_size, void* d_ws, size_t ws_size,
                              hipStream_t stream)
{
    (void)in_sizes; (void)n_in; (void)out_size; (void)ws_size;
    const int*   x1         = (const int*)d_in[0];
    const int*   x2         = (const int*)d_in[1];
    const float* emb        = (const float*)d_in[2];
    const float* w_intra    = (const float*)d_in[3];
    const float* bias_intra = (const float*)d_in[4];
    const float* w_proj1    = (const float*)d_in[5];
    const float* w_proj2    = (const float*)d_in[6];
    const float* w_att      = (const float*)d_in[7];
    const float* w_cmp1     = (const float*)d_in[8];
    const float* w_cmp2     = (const float*)d_in[9];
    const float* w_agg      = (const float*)d_in[10];
    float* y  = (float*)d_out;
    float* ws = (float*)d_ws;

    // ---- workspace (floats); total ~58.64M fl = 234.6 MB ----
    float* X1CAT = ws;                        // [32768,400]: x1p | beta; phase A: F side-2
    float* X2CAT = X1CAT + 13107200;          // [32768,400]: x2p | alpha (contig)
    float* T     = X2CAT + 13107200;          // [512,200,128]: G^T -> x_proj^T
    float* FBUF  = T + 13107200;              // [32768,300] intra f side-1
    float* ATT   = FBUF + 9830400;            // [512,128,128] probs (dead after xp)
    float* POOL  = ATT + 8388608;             // [512,400] pooled v1|v2
    int*   SIZES = (int*)(POOL + 204800);     // [2,256] + pad
    float* NORMS = (float*)(SIZES + 512);     // [32000] + pad
    u16*   W1H   = (u16*)(NORMS + 32768);     // side-1 stack [556][320]: wp_b|z56|intra
    u16*   W1L   = W1H + 177920;
    u16*   W2H   = W1L + 177920;              // side-2 stack [556][320]
    u16*   W2L   = W2H + 177920;
    u16*   WAH   = W2L + 177920;              // w_att^T  [200][224]
    u16*   WAL   = WAH + 44800;
    u16*   WC1H  = WAL + 44800;               // w_cmp1^T [400][416]
    u16*   WC1L  = WC1H + 166400;
    u16*   WC2H  = WC1L + 166400;
    u16*   WC2L  = WC2H + 166400;
    u16*   WPA1H = WC2L + 166400;             // wp_a side1 [200][320]
    u16*   WPA1L = WPA1H + 64000;
    u16*   WPA2H = WPA1L + 64000;
    u16*   WPA2L = WPA2H + 64000;

    // phase-A alias: side-2 intra f lives in X1CAT region (dead until xp)
    float* F1X = X1CAT;                       // [32768,300]
    // phase-B aliases: F12 spans FBUF + head of ATT (probs dead by then)
    float* F12 = FBUF;                        // [65536,200] f1|f2
    float* F2  = FBUF + 6553600;
    // sim outputs alias the f slots they consumed (block-local WAR):
    float* SIMP = F2;                         // probs slot bz at F2  + bz*25600
    float* SMTP = F12;                        // probs^T slot bz at F12 + bz*25600
    float* T1  = T;
    float* T2  = T + 6553600;

    const long long sbSS = (long long)SEQ * SEQ;     // 16384
    const long long sbF  = (long long)SEQ * EDIM;    // 38400
    const long long sbFP = 25600;                    // f1/f2 slot stride (128*200)
    const long long sbC  = (long long)SEQ * 400;     // 51200
    const long long sbT  = (long long)PDIM * SEQ;    // 25600

    sizes_kernel<<<dim3(BATCH, 2), 128, 0, stream>>>(x1, x2, SIZES);
    norms_kernel<<<32000, 64, 0, stream>>>(emb, NORMS);

    {
        WTab t;
        t.e[0]  = { w_proj1 + 300 * 200, W1H,             W1L,             300, 200, 320, 0    };
        t.e[1]  = { w_intra,             W1H + 200 * 320, W1L + 200 * 320,   0,  56, 320, 200  };
        t.e[2]  = { w_intra,             W1H + 256 * 320, W1L + 256 * 320, 300, 300, 320, 256  };
        t.e[3]  = { w_proj2 + 300 * 200, W2H,             W2L,             300, 200, 320, 556  };
        t.e[4]  = { w_intra,             W2H + 200 * 320, W2L + 200 * 320,   0,  56, 320, 756  };
        t.e[5]  = { w_intra,             W2H + 256 * 320, W2L + 256 * 320, 300, 300, 320, 812  };
        t.e[6]  = { w_att,               WAH,             WAL,             200, 200, 224, 1112 };
        t.e[7]  = { w_cmp1,              WC1H,            WC1L,            400, 400, 416, 1312 };
        t.e[8]  = { w_cmp2,              WC2H,            WC2L,            400, 400, 416, 1712 };
        t.e[9]  = { w_proj1,             WPA1H,           WPA1L,           300, 200, 320, 2112 };
        t.e[10] = { w_proj2,             WPA2H,           WPA2L,           300, 200, 320, 2312 };
        convert_all<<<dim3(2, 2512), 256, 0, stream>>>(t);
    }

    // -------- phase A --------
    // merged proj (both sides): T[0:512] = (e@wp_b)^T; f side1 -> FBUF, side2 -> F1X
    gemm_proj<<<dim3(5, 512), 256, 0, stream>>>(
        x1, x2, emb, NORMS, W1H, W1L, W2H, W2L, T, FBUF, F1X);
    // merged att (512 batches, 1-MFMA): probs = rowsoftmax(f f^T + dbias) -> ATT
    gemm_bat<1><<<dim3(1, 1, 2 * BATCH), 256, 0, stream>>>(
        FBUF, F1X, FBUF, nullptr, ATT, nullptr,
        SEQ, EDIM, 320, EDIM, EDIM, SEQ, sbF, sbF, sbSS, 0,
        0, bias_intra, nullptr, 1);
    // fused xp (3-MFMA): XCAT[:,0:200] = relu(e@wp_a + probs@G); x_proj^T -> T
    gemm_xp<<<dim3(2, 1, 2 * BATCH), 256, 0, stream>>>(
        ATT, T, x1, x2, emb, NORMS, WPA1H, WPA1L, WPA2H, WPA2L, X1CAT);

    // -------- phase B --------
    // f1|f2 = relu(x_proj @ w_att)  [1-MFMA; A cols 200:224 garbage*0]
    gemm_flat<1><<<dim3(2, 512), 256, 0, stream>>>(
        X1CAT, WAH, WAL, WAH, WAL, 1 << 30, F12, nullptr, nullptr,
        2 * BSTOK, PDIM, 224, 400, 224, PDIM, F_RELU);
    // fused sim (1-MFMA): mask(f1 f2^T) -> rowsm over f2 slot + colsm^T over f1 slot
    gemm_bat<2><<<dim3(1, 1, BATCH), 256, 0, stream>>>(
        F12, nullptr, F2, nullptr, SIMP, SMTP,
        SEQ, PDIM, 224, PDIM, PDIM, SEQ, sbFP, sbFP, sbFP, sbFP,
        0, nullptr, SIZES, 0);
    // beta (bz<256) / alpha (bz>=256) -> X1CAT/X2CAT cols 200:400  [3-MFMA]
    gemm_bat<0><<<dim3(2, 1, 2 * BATCH), 256, 0, stream>>>(
        SIMP, SMTP, T2, T1, X1CAT + 200, nullptr,
        PDIM, SEQ, SEQ, SEQ, SEQ, 400, sbFP, sbT, sbC, 0,
        0, nullptr, nullptr, 0);

    // -------- phase C: fused compare + masked pool, aggregate [3-MFMA] --------
    gemm_flat<3><<<dim3(4, 512), 256, 0, stream>>>(
        X1CAT, WC1H, WC1L, WC2H, WC2L, BSTOK,
        nullptr, POOL, SIZES,
        2 * BSTOK, 400, 416, 400, 416, 400, F_RELU);
    agg_kernel<<<BATCH, 64, 0, stream>>>(POOL, POOL + 102400, w_agg, y);
}